// Round 1
// baseline (2784.398 us; speedup 1.0000x reference)
//
#include <hip/hip_runtime.h>

#define BB 2
#define NN 16384
#define MM 4096
#define KK 16
#define CQ 64
#define GEOC 18
#define EPSV 1e-5

// ---------------- transpose lr points/values (with |b|^2 precomputed) ----------------
__global__ __launch_bounds__(256) void tlr_k(const float* __restrict__ xyz,
    const float* __restrict__ val, float* __restrict__ xyzT, float* __restrict__ valT)
{
#pragma clang fp contract(off)
  int i = blockIdx.x * 256 + threadIdx.x;  // B*M
  int b = i / MM, m = i % MM;
  float x = xyz[(b * 3 + 0) * MM + m];
  float y = xyz[(b * 3 + 1) * MM + m];
  float z = xyz[(b * 3 + 2) * MM + m];
  float sb = (x * x + y * y) + z * z;      // exact numpy order: (x2+y2)+z2
  ((float4*)xyzT)[i] = make_float4(x, y, z, sb);
  float v0 = val[((size_t)b * 6 + 0) * MM + m];
  float v1 = val[((size_t)b * 6 + 1) * MM + m];
  float v2 = val[((size_t)b * 6 + 2) * MM + m];
  float v3 = val[((size_t)b * 6 + 3) * MM + m];
  float v4 = val[((size_t)b * 6 + 4) * MM + m];
  float v5 = val[((size_t)b * 6 + 5) * MM + m];
  ((float4*)valT)[2 * i]     = make_float4(v0, v1, v2, v3);
  ((float4*)valT)[2 * i + 1] = make_float4(v4, v5, 0.f, 0.f);
}

// ---------------- generic 1x1 conv; optional fused BN+ReLU on input ----------------
template<int CIN, int COUT, bool TOUT, bool TW>
__global__ __launch_bounds__(256) void conv_k(const float* __restrict__ x,
    const float* __restrict__ W, const float* __restrict__ bias,
    const float* __restrict__ AB, float* __restrict__ y, int L)
{
  int i = blockIdx.x * 256 + threadIdx.x;  // exact grid over B*L
  int b = i / L, n = i % L;
  const float* xp = x + (size_t)b * CIN * L + n;
  float xr[CIN];
#pragma unroll
  for (int c = 0; c < CIN; c++) {
    float v = xp[(size_t)c * L];
    if (AB) v = fmaxf(fmaf(v, AB[c], AB[CIN + c]), 0.f);
    xr[c] = v;
  }
  for (int o = 0; o < COUT; o++) {
    float acc = bias ? bias[o] : 0.f;
#pragma unroll
    for (int c = 0; c < CIN; c++)
      acc = fmaf(TW ? W[(size_t)c * COUT + o] : W[(size_t)o * CIN + c], xr[c], acc);
    if (TOUT) y[((size_t)b * L + n) * COUT + o] = acc;
    else      y[((size_t)b * COUT + o) * L + n] = acc;
  }
}

// ---------------- per-channel BN stats -> fused (A,B): y = relu(x*A + B) ----------------
template<int C>
__global__ __launch_bounds__(256) void stats_k(const float* __restrict__ t, int L,
    const float* __restrict__ g, const float* __restrict__ bt, float* __restrict__ AB)
{
  int c = blockIdx.x;
  double s = 0.0, ss = 0.0;
  for (int b = 0; b < BB; b++) {
    const float* p = t + ((size_t)b * C + c) * L;
    for (int i = threadIdx.x; i < L; i += 256) { double v = p[i]; s += v; ss += v * v; }
  }
  for (int o = 32; o >= 1; o >>= 1) { s += __shfl_down(s, o); ss += __shfl_down(ss, o); }
  __shared__ double sh[8];
  int w = threadIdx.x >> 6;
  if ((threadIdx.x & 63) == 0) { sh[2 * w] = s; sh[2 * w + 1] = ss; }
  __syncthreads();
  if (threadIdx.x == 0) {
    for (int j = 1; j < 4; j++) { s += sh[2 * j]; ss += sh[2 * j + 1]; }
    double n = (double)BB * L;
    double mean = s / n, var = ss / n - mean * mean;
    double A = (double)g[c] / sqrt(var + EPSV);
    AB[c] = (float)A;
    AB[C + c] = (float)((double)bt[c] - mean * A);
  }
}

// ---------------- FiLM: glr = relu(bn(t2))*(1+scale)+shift ----------------
__global__ __launch_bounds__(256) void film_k(const float* __restrict__ t2,
    const float* __restrict__ AB, const float* __restrict__ val,
    const float* __restrict__ scw, const float* __restrict__ scb,
    const float* __restrict__ shw, const float* __restrict__ shb,
    float* __restrict__ gout)
{
  int i = blockIdx.x * 256 + threadIdx.x;  // B*64*M
  int b = i / (CQ * MM);
  int c = (i / MM) % CQ;
  int m = i % MM;
  float gv = fmaxf(fmaf(t2[i], AB[c], AB[CQ + c]), 0.f);
  float sc = scb[c], sh = shb[c];
#pragma unroll
  for (int j = 0; j < 6; j++) {
    float v = val[((size_t)b * 6 + j) * MM + m];
    sc = fmaf(scw[c * 6 + j], v, sc);
    sh = fmaf(shw[c * 6 + j], v, sh);
  }
  gout[i] = fmaf(gv, 1.f + sc, sh);
}

// ---------------- boundary head output ----------------
__global__ __launch_bounds__(256) void bdy_k(const float* __restrict__ tb,
    const float* __restrict__ AB, const float* __restrict__ w2,
    const float* __restrict__ b2, float* __restrict__ out2)
{
  int i = blockIdx.x * 256 + threadIdx.x;  // B*N
  int b = i / NN, n = i % NN;
  float acc = b2[0];
#pragma unroll
  for (int c = 0; c < 32; c++) {
    float v = tb[((size_t)b * 32 + c) * NN + n];
    v = fmaxf(fmaf(v, AB[c], AB[32 + c]), 0.f);
    acc = fmaf(w2[c], v, acc);
  }
  out2[i] = 1.f / (1.f + expf(-acc));
}

// ---------------- kNN: per-query top-16 by squared distance (numpy-exact fp32) ----------------
__global__ __launch_bounds__(64) void knn_k(const float* __restrict__ xyz_hr,
    const float* __restrict__ xyzT, int* __restrict__ idx_out)
{
#pragma clang fp contract(off)
  const int nb = NN / 64;
  int b = blockIdx.x / nb;
  int n = (blockIdx.x % nb) * 64 + threadIdx.x;
  float ax = xyz_hr[(b * 3 + 0) * NN + n];
  float ay = xyz_hr[(b * 3 + 1) * NN + n];
  float az = xyz_hr[(b * 3 + 2) * NN + n];
  float sa = (ax * ax + ay * ay) + az * az;
  const float4* __restrict__ P = ((const float4*)xyzT) + (size_t)b * MM;
  float dv[16]; int di[16];
#pragma unroll
  for (int j = 0; j < 16; j++) { dv[j] = 3.4e38f; di[j] = 0; }
  float cm = 3.4e38f; int cpos = 0;
  auto ins = [&](float d, int m) {
#pragma unroll
    for (int j = 0; j < 16; j++) if (j == cpos) { dv[j] = d; di[j] = m; }
    cm = dv[0]; cpos = 0; int cmi = di[0];
#pragma unroll
    for (int j = 1; j < 16; j++) {
      bool gsel = (dv[j] > cm) || ((dv[j] == cm) && (di[j] > cmi));
      if (gsel) { cm = dv[j]; cmi = di[j]; cpos = j; }
    }
  };
  for (int m0 = 0; m0 < MM; m0 += 4) {
    float4 p0 = P[m0], p1 = P[m0 + 1], p2 = P[m0 + 2], p3 = P[m0 + 3];
    float d0 = (sa + p0.w) - 2.0f * ((ax * p0.x + ay * p0.y) + az * p0.z);
    float d1 = (sa + p1.w) - 2.0f * ((ax * p1.x + ay * p1.y) + az * p1.z);
    float d2 = (sa + p2.w) - 2.0f * ((ax * p2.x + ay * p2.y) + az * p2.z);
    float d3 = (sa + p3.w) - 2.0f * ((ax * p3.x + ay * p3.y) + az * p3.z);
    float mn = fminf(fminf(d0, d1), fminf(d2, d3));
    if (mn < cm) {
      if (d0 < cm) ins(d0, m0);
      if (d1 < cm) ins(d1, m0 + 1);
      if (d2 < cm) ins(d2, m0 + 2);
      if (d3 < cm) ins(d3, m0 + 3);
    }
  }
  size_t base = ((size_t)b * NN + n) * KK;
#pragma unroll
  for (int j = 0; j < 16; j++) idx_out[base + j] = di[j];
}

// ---------------- rel_pos first/second moments (BN2d stats via linearity) ----------------
__global__ __launch_bounds__(256) void mom_k(const float* __restrict__ xyz_hr,
    const float* __restrict__ xyzT, const int* __restrict__ idxb, double* __restrict__ mom)
{
  float a0=0,a1=0,a2=0,a3=0,a4=0,a5=0,a6=0,a7=0,a8=0;
  const size_t total = (size_t)BB * NN * KK;
  for (size_t i = (size_t)blockIdx.x * 256 + threadIdx.x; i < total; i += (size_t)gridDim.x * 256) {
    int b = (int)(i / ((size_t)NN * KK));
    int n = (int)((i / KK) % NN);
    int id = idxb[i];
    float ax = xyz_hr[(b * 3 + 0) * NN + n];
    float ay = xyz_hr[(b * 3 + 1) * NN + n];
    float az = xyz_hr[(b * 3 + 2) * NN + n];
    float4 p = ((const float4*)xyzT)[(size_t)b * MM + id];
    float rx = ax - p.x, ry = ay - p.y, rz = az - p.z;
    a0 += rx; a1 += ry; a2 += rz;
    a3 += rx * rx; a4 += ry * ry; a5 += rz * rz;
    a6 += rx * ry; a7 += rx * rz; a8 += ry * rz;
  }
  double d[9] = {a0,a1,a2,a3,a4,a5,a6,a7,a8};
#pragma unroll
  for (int j = 0; j < 9; j++)
    for (int o = 32; o >= 1; o >>= 1) d[j] += __shfl_down(d[j], o);
  __shared__ double sh[4][9];
  int w = threadIdx.x >> 6, l = threadIdx.x & 63;
  if (l == 0) { for (int j = 0; j < 9; j++) sh[w][j] = d[j]; }
  __syncthreads();
  if (threadIdx.x == 0) {
    for (int wv = 1; wv < 4; wv++) for (int j = 0; j < 9; j++) d[j] += sh[wv][j];
    for (int j = 0; j < 9; j++) atomicAdd(&mom[j], d[j]);
  }
}

__global__ void bn2fin_k(const double* __restrict__ mom, const float* __restrict__ w1,
    const float* __restrict__ b1, const float* __restrict__ g,
    const float* __restrict__ bt, float* __restrict__ AB)
{
  int c = threadIdx.x;
  if (c >= CQ) return;
  double cnt = (double)BB * NN * KK;
  double mx = mom[0]/cnt, my = mom[1]/cnt, mz = mom[2]/cnt;
  double cxx = mom[3]/cnt - mx*mx, cyy = mom[4]/cnt - my*my, czz = mom[5]/cnt - mz*mz;
  double cxy = mom[6]/cnt - mx*my, cxz = mom[7]/cnt - mx*mz, cyz = mom[8]/cnt - my*mz;
  double wx = w1[c*3], wy = w1[c*3+1], wz = w1[c*3+2];
  double mean = wx*mx + wy*my + wz*mz + (double)b1[c];
  double var = wx*wx*cxx + wy*wy*cyy + wz*wz*czz + 2.0*(wx*wy*cxy + wx*wz*cxz + wy*wz*cyz);
  double A = (double)g[c] / sqrt(var + EPSV);
  AB[c] = (float)A;
  AB[CQ + c] = (float)((double)bt[c] - mean * A);
}

// ---------------- fused pos-enc + attention + output ----------------
__global__ __launch_bounds__(256) void attn_k(
    const float* __restrict__ Q, const float* __restrict__ Qp,
    const float* __restrict__ KfT, const int* __restrict__ idxb,
    const float* __restrict__ xyzT, const float* __restrict__ valT,
    const float* __restrict__ xyz_hr, const float* __restrict__ AB,
    const float* __restrict__ w1, const float* __restrict__ b1,
    const float* __restrict__ b2, float* __restrict__ out)
{
  __shared__ float q_s[CQ * 16], qp_s[CQ * 16];
  const int ngrp = NN / 16;
  int b = blockIdx.x / ngrp;
  int n0 = (blockIdx.x % ngrp) * 16;
  for (int t = threadIdx.x; t < CQ * 16; t += 256) {
    int c = t >> 4, j = t & 15;
    q_s[t]  = Q [((size_t)b * CQ + c) * NN + n0 + j];
    qp_s[t] = Qp[((size_t)b * CQ + c) * NN + n0 + j];
  }
  __syncthreads();
  int q = threadIdx.x >> 4, k = threadIdx.x & 15;
  int n = n0 + q;
  int id = idxb[((size_t)b * NN + n) * KK + k];
  float ax = xyz_hr[(b * 3 + 0) * NN + n];
  float ay = xyz_hr[(b * 3 + 1) * NN + n];
  float az = xyz_hr[(b * 3 + 2) * NN + n];
  float4 pl = ((const float4*)xyzT)[(size_t)b * MM + id];
  float rx = ax - pl.x, ry = ay - pl.y, rz = az - pl.z;
  const float4* kg = (const float4*)(KfT + ((size_t)b * MM + id) * CQ);
  float s = 0.f;
#pragma unroll
  for (int c4 = 0; c4 < CQ / 4; c4++) {
    float4 g4 = kg[c4];
    float ga[4] = {g4.x, g4.y, g4.z, g4.w};
#pragma unroll
    for (int u = 0; u < 4; u++) {
      int c = 4 * c4 + u;
      float t0 = fmaf(w1[c * 3 + 0], rx, fmaf(w1[c * 3 + 1], ry, w1[c * 3 + 2] * rz)) + b1[c];
      float pe = fmaxf(fmaf(t0, AB[c], AB[CQ + c]), 0.f);
      s = fmaf(q_s[c * 16 + q], ga[u] + b2[c], s);
      s = fmaf(qp_s[c * 16 + q], pe, s);
    }
  }
  s *= 0.125f;  // /sqrt(64)
  float mx = s;
#pragma unroll
  for (int o = 8; o >= 1; o >>= 1) mx = fmaxf(mx, __shfl_xor(mx, o, 16));
  float p = expf(s - mx);
  float sum = p;
#pragma unroll
  for (int o = 8; o >= 1; o >>= 1) sum += __shfl_xor(sum, o, 16);
  float attn = p / sum;
  const float4* vt = (const float4*)(valT + ((size_t)b * MM + id) * 8);
  float4 va = vt[0], vb = vt[1];
  float oc[6] = {attn*va.x, attn*va.y, attn*va.z, attn*va.w, attn*vb.x, attn*vb.y};
#pragma unroll
  for (int c = 0; c < 6; c++) {
    float a = oc[c];
#pragma unroll
    for (int o = 8; o >= 1; o >>= 1) a += __shfl_xor(a, o, 16);
    oc[c] = a;
  }
  if (k == 0) {
#pragma unroll
    for (int c = 0; c < 6; c++) out[((size_t)b * 6 + c) * NN + n] = oc[c];
  }
}

extern "C" void kernel_launch(void* const* d_in, const int* in_sizes, int n_in,
                              void* d_out, int out_size, void* d_ws, size_t ws_size,
                              hipStream_t stream)
{
  const float* xyz_hr = (const float*)d_in[0];
  const float* xyz_lr = (const float*)d_in[1];
  const float* val_lr = (const float*)d_in[2];
  const float* feat_hr= (const float*)d_in[3];
  const float* feat_lr= (const float*)d_in[4];
  const float* ge_w1 = (const float*)d_in[5];
  const float* ge_b1 = (const float*)d_in[6];
  const float* ge_g1 = (const float*)d_in[7];
  const float* ge_bt1= (const float*)d_in[8];
  const float* ge_w2 = (const float*)d_in[9];
  const float* ge_b2 = (const float*)d_in[10];
  const float* ge_g2 = (const float*)d_in[11];
  const float* ge_bt2= (const float*)d_in[12];
  const float* sc_w = (const float*)d_in[13];
  const float* sc_b = (const float*)d_in[14];
  const float* sh_w = (const float*)d_in[15];
  const float* sh_b = (const float*)d_in[16];
  const float* q_w  = (const float*)d_in[17];
  const float* q_b  = (const float*)d_in[18];
  const float* k_w  = (const float*)d_in[19];
  const float* k_b  = (const float*)d_in[20];
  const float* bh_w1= (const float*)d_in[21];
  const float* bh_b1= (const float*)d_in[22];
  const float* bh_g = (const float*)d_in[23];
  const float* bh_bt= (const float*)d_in[24];
  const float* bh_w2= (const float*)d_in[25];
  const float* bh_b2= (const float*)d_in[26];
  const float* rp_w1= (const float*)d_in[27];
  const float* rp_b1= (const float*)d_in[28];
  const float* rp_g = (const float*)d_in[29];
  const float* rp_bt= (const float*)d_in[30];
  const float* rp_w2= (const float*)d_in[31];
  const float* rp_b2= (const float*)d_in[32];
  float* out = (float*)d_out;

  double* mom = (double*)d_ws;
  float* base = (float*)((char*)d_ws + 128);
  float* AB1h = base;          // 128
  float* AB2h = base + 128;    // 128
  float* AB1l = base + 256;    // 128
  float* AB2l = base + 384;    // 128
  float* ABb  = base + 512;    // 64
  float* AB2d = base + 576;    // 128
  float* big  = base + 768;
  float* t1_hr = big;                      // 2*64*16384
  float* t2_hr = t1_hr + 2097152;
  float* Qb    = t2_hr + 2097152;
  float* Qp    = Qb    + 2097152;
  float* t1_lr = Qp    + 2097152;          // 2*64*4096
  float* t2_lr = t1_lr + 524288;
  float* glr   = t2_lr + 524288;
  float* KfT   = glr   + 524288;           // [B,M,64]
  float* tb    = KfT   + 524288;           // 2*32*16384
  float* xyzT  = tb    + 1048576;          // [B,M,4]
  float* valT  = xyzT  + 32768;            // [B,M,8]
  int*   idxb  = (int*)(valT + 65536);     // 2*16384*16

  hipMemsetAsync(mom, 0, 9 * sizeof(double), stream);

  tlr_k<<<32, 256, 0, stream>>>(xyz_lr, val_lr, xyzT, valT);

  conv_k<GEOC, CQ, false, false><<<128, 256, 0, stream>>>(feat_hr, ge_w1, ge_b1, nullptr, t1_hr, NN);
  conv_k<GEOC, CQ, false, false><<<32,  256, 0, stream>>>(feat_lr, ge_w1, ge_b1, nullptr, t1_lr, MM);
  stats_k<CQ><<<64, 256, 0, stream>>>(t1_hr, NN, ge_g1, ge_bt1, AB1h);
  stats_k<CQ><<<64, 256, 0, stream>>>(t1_lr, MM, ge_g1, ge_bt1, AB1l);
  conv_k<CQ, CQ, false, false><<<128, 256, 0, stream>>>(t1_hr, ge_w2, ge_b2, AB1h, t2_hr, NN);
  conv_k<CQ, CQ, false, false><<<32,  256, 0, stream>>>(t1_lr, ge_w2, ge_b2, AB1l, t2_lr, MM);
  stats_k<CQ><<<64, 256, 0, stream>>>(t2_hr, NN, ge_g2, ge_bt2, AB2h);
  stats_k<CQ><<<64, 256, 0, stream>>>(t2_lr, MM, ge_g2, ge_bt2, AB2l);

  film_k<<<2048, 256, 0, stream>>>(t2_lr, AB2l, val_lr, sc_w, sc_b, sh_w, sh_b, glr);
  conv_k<CQ, CQ, true, false><<<32, 256, 0, stream>>>(glr, k_w, k_b, nullptr, KfT, MM);

  conv_k<CQ, 32, false, false><<<128, 256, 0, stream>>>(t2_hr, bh_w1, bh_b1, AB2h, tb, NN);
  stats_k<32><<<32, 256, 0, stream>>>(tb, NN, bh_g, bh_bt, ABb);
  bdy_k<<<128, 256, 0, stream>>>(tb, ABb, bh_w2, bh_b2, out + (size_t)BB * 6 * NN);

  conv_k<CQ, CQ, false, false><<<128, 256, 0, stream>>>(t2_hr, q_w, q_b, AB2h, Qb, NN);
  conv_k<CQ, CQ, false, true><<<128, 256, 0, stream>>>(Qb, rp_w2, nullptr, nullptr, Qp, NN);

  knn_k<<<512, 64, 0, stream>>>(xyz_hr, xyzT, idxb);
  mom_k<<<512, 256, 0, stream>>>(xyz_hr, xyzT, idxb, mom);
  bn2fin_k<<<1, 64, 0, stream>>>(mom, rp_w1, rp_b1, rp_g, rp_bt, AB2d);

  attn_k<<<2048, 256, 0, stream>>>(Qb, Qp, KfT, idxb, xyzT, valT, xyz_hr, AB2d,
                                   rp_w1, rp_b1, rp_b2, out);
}

// Round 3
// 1452.753 us; speedup vs baseline: 1.9166x; 1.9166x over previous
//
#include <hip/hip_runtime.h>

#define BB 2
#define NN 16384
#define MM 4096
#define KK 16
#define CQ 64
#define GEOC 18
#define EPSV 1e-5
#define SPL 8   // M-split per query for kNN

// ---------------- transpose lr points/values (with |b|^2 precomputed) ----------------
__global__ __launch_bounds__(256) void tlr_k(const float* __restrict__ xyz,
    const float* __restrict__ val, float* __restrict__ xyzT, float* __restrict__ valT)
{
#pragma clang fp contract(off)
  int i = blockIdx.x * 256 + threadIdx.x;  // B*M
  int b = i / MM, m = i % MM;
  float x = xyz[(b * 3 + 0) * MM + m];
  float y = xyz[(b * 3 + 1) * MM + m];
  float z = xyz[(b * 3 + 2) * MM + m];
  float sb = (x * x + y * y) + z * z;      // exact numpy order: (x2+y2)+z2
  ((float4*)xyzT)[i] = make_float4(x, y, z, sb);
  float v0 = val[((size_t)b * 6 + 0) * MM + m];
  float v1 = val[((size_t)b * 6 + 1) * MM + m];
  float v2 = val[((size_t)b * 6 + 2) * MM + m];
  float v3 = val[((size_t)b * 6 + 3) * MM + m];
  float v4 = val[((size_t)b * 6 + 4) * MM + m];
  float v5 = val[((size_t)b * 6 + 5) * MM + m];
  ((float4*)valT)[2 * i]     = make_float4(v0, v1, v2, v3);
  ((float4*)valT)[2 * i + 1] = make_float4(v4, v5, 0.f, 0.f);
}

// ---------------- generic 1x1 conv; optional fused BN+ReLU on input ----------------
template<int CIN, int COUT, bool TOUT, bool TW>
__global__ __launch_bounds__(256) void conv_k(const float* __restrict__ x,
    const float* __restrict__ W, const float* __restrict__ bias,
    const float* __restrict__ AB, float* __restrict__ y, int L)
{
  int i = blockIdx.x * 256 + threadIdx.x;  // exact grid over B*L
  int b = i / L, n = i % L;
  const float* xp = x + (size_t)b * CIN * L + n;
  float xr[CIN];
#pragma unroll
  for (int c = 0; c < CIN; c++) {
    float v = xp[(size_t)c * L];
    if (AB) v = fmaxf(fmaf(v, AB[c], AB[CIN + c]), 0.f);
    xr[c] = v;
  }
  for (int o = 0; o < COUT; o++) {
    float acc = bias ? bias[o] : 0.f;
#pragma unroll
    for (int c = 0; c < CIN; c++)
      acc = fmaf(TW ? W[(size_t)c * COUT + o] : W[(size_t)o * CIN + c], xr[c], acc);
    if (TOUT) y[((size_t)b * L + n) * COUT + o] = acc;
    else      y[((size_t)b * COUT + o) * L + n] = acc;
  }
}

// ---------------- per-channel BN stats -> fused (A,B): y = relu(x*A + B) ----------------
template<int C>
__global__ __launch_bounds__(256) void stats_k(const float* __restrict__ t, int L,
    const float* __restrict__ g, const float* __restrict__ bt, float* __restrict__ AB)
{
  int c = blockIdx.x;
  double s = 0.0, ss = 0.0;
  for (int b = 0; b < BB; b++) {
    const float* p = t + ((size_t)b * C + c) * L;
    for (int i = threadIdx.x; i < L; i += 256) { double v = p[i]; s += v; ss += v * v; }
  }
  for (int o = 32; o >= 1; o >>= 1) { s += __shfl_down(s, o); ss += __shfl_down(ss, o); }
  __shared__ double sh[8];
  int w = threadIdx.x >> 6;
  if ((threadIdx.x & 63) == 0) { sh[2 * w] = s; sh[2 * w + 1] = ss; }
  __syncthreads();
  if (threadIdx.x == 0) {
    for (int j = 1; j < 4; j++) { s += sh[2 * j]; ss += sh[2 * j + 1]; }
    double n = (double)BB * L;
    double mean = s / n, var = ss / n - mean * mean;
    double A = (double)g[c] / sqrt(var + EPSV);
    AB[c] = (float)A;
    AB[C + c] = (float)((double)bt[c] - mean * A);
  }
}

// ---------------- FiLM: glr = relu(bn(t2))*(1+scale)+shift ----------------
__global__ __launch_bounds__(256) void film_k(const float* __restrict__ t2,
    const float* __restrict__ AB, const float* __restrict__ val,
    const float* __restrict__ scw, const float* __restrict__ scb,
    const float* __restrict__ shw, const float* __restrict__ shb,
    float* __restrict__ gout)
{
  int i = blockIdx.x * 256 + threadIdx.x;  // B*64*M
  int b = i / (CQ * MM);
  int c = (i / MM) % CQ;
  int m = i % MM;
  float gv = fmaxf(fmaf(t2[i], AB[c], AB[CQ + c]), 0.f);
  float sc = scb[c], sh = shb[c];
#pragma unroll
  for (int j = 0; j < 6; j++) {
    float v = val[((size_t)b * 6 + j) * MM + m];
    sc = fmaf(scw[c * 6 + j], v, sc);
    sh = fmaf(shw[c * 6 + j], v, sh);
  }
  gout[i] = fmaf(gv, 1.f + sc, sh);
}

// ---------------- boundary head output ----------------
__global__ __launch_bounds__(256) void bdy_k(const float* __restrict__ tb,
    const float* __restrict__ AB, const float* __restrict__ w2,
    const float* __restrict__ b2, float* __restrict__ out2)
{
  int i = blockIdx.x * 256 + threadIdx.x;  // B*N
  int b = i / NN, n = i % NN;
  float acc = b2[0];
#pragma unroll
  for (int c = 0; c < 32; c++) {
    float v = tb[((size_t)b * 32 + c) * NN + n];
    v = fmaxf(fmaf(v, AB[c], AB[32 + c]), 0.f);
    acc = fmaf(w2[c], v, acc);
  }
  out2[i] = 1.f / (1.f + expf(-acc));
}

// ---------------- kNN phase A: per-(query, residue-class) top-16 ----------------
// thread t of SPL-group scans m = s, s+SPL, s+2*SPL, ... (indices increasing ->
// strict < gate preserves numpy top_k stable-tie set semantics within chunk)
__global__ __launch_bounds__(256) void knnA_k(const float* __restrict__ xyz_hr,
    const float* __restrict__ xyzT, float2* __restrict__ part)
{
#pragma clang fp contract(off)
  int tid = blockIdx.x * 256 + threadIdx.x;  // B*N*SPL
  int s = tid & (SPL - 1);
  int qi = tid / SPL;                        // b*NN + n
  int b = qi / NN, n = qi % NN;
  float ax = xyz_hr[(b * 3 + 0) * NN + n];
  float ay = xyz_hr[(b * 3 + 1) * NN + n];
  float az = xyz_hr[(b * 3 + 2) * NN + n];
  float sa = (ax * ax + ay * ay) + az * az;
  const float4* __restrict__ Ps = ((const float4*)xyzT) + (size_t)b * MM + s;
  float dv[16]; int di[16];
#pragma unroll
  for (int j = 0; j < 16; j++) { dv[j] = 3.4e38f; di[j] = 0; }
  float cm = 3.4e38f; int cpos = 0;
  auto ins = [&](float d, int m) {
#pragma unroll
    for (int j = 0; j < 16; j++) if (j == cpos) { dv[j] = d; di[j] = m; }
    cm = dv[0]; cpos = 0; int cmi = di[0];
#pragma unroll
    for (int j = 1; j < 16; j++) {
      bool gsel = (dv[j] > cm) || ((dv[j] == cm) && (di[j] > cmi));
      if (gsel) { cm = dv[j]; cmi = di[j]; cpos = j; }
    }
  };
  const int C = MM / SPL;  // 512 candidates per thread
  for (int j = 0; j < C; j += 4) {
    float4 p0 = Ps[(j + 0) * SPL];
    float4 p1 = Ps[(j + 1) * SPL];
    float4 p2 = Ps[(j + 2) * SPL];
    float4 p3 = Ps[(j + 3) * SPL];
    float d0 = (sa + p0.w) - 2.0f * ((ax * p0.x + ay * p0.y) + az * p0.z);
    float d1 = (sa + p1.w) - 2.0f * ((ax * p1.x + ay * p1.y) + az * p1.z);
    float d2 = (sa + p2.w) - 2.0f * ((ax * p2.x + ay * p2.y) + az * p2.z);
    float d3 = (sa + p3.w) - 2.0f * ((ax * p3.x + ay * p3.y) + az * p3.z);
    float mn = fminf(fminf(d0, d1), fminf(d2, d3));
    if (mn < cm) {
      if (d0 < cm) ins(d0, s + (j + 0) * SPL);
      if (d1 < cm) ins(d1, s + (j + 1) * SPL);
      if (d2 < cm) ins(d2, s + (j + 2) * SPL);
      if (d3 < cm) ins(d3, s + (j + 3) * SPL);
    }
  }
  float2* op = part + (size_t)qi * (SPL * 16) + s * 16;
#pragma unroll
  for (int j = 0; j < 16; j++) op[j] = make_float2(dv[j], __int_as_float(di[j]));
}

// ---------------- kNN phase B: merge SPL*16 candidates, full (d,idx) lexicographic ----------------
__global__ __launch_bounds__(256) void knnB_k(const float2* __restrict__ part,
    int* __restrict__ idx_out)
{
  int qi = blockIdx.x * 256 + threadIdx.x;  // B*N
  const float4* __restrict__ p = (const float4*)(part + (size_t)qi * (SPL * 16));
  float dv[16]; int di[16];
#pragma unroll
  for (int j = 0; j < 16; j++) { dv[j] = 3.4e38f; di[j] = 0; }
  float cm = 3.4e38f; int cmi = 0; int cpos = 0;
  auto ins = [&](float d, int m) {
#pragma unroll
    for (int j = 0; j < 16; j++) if (j == cpos) { dv[j] = d; di[j] = m; }
    cm = dv[0]; cmi = di[0]; cpos = 0;
#pragma unroll
    for (int j = 1; j < 16; j++) {
      bool gsel = (dv[j] > cm) || ((dv[j] == cm) && (di[j] > cmi));
      if (gsel) { cm = dv[j]; cmi = di[j]; cpos = j; }
    }
  };
  for (int j = 0; j < SPL * 16 / 2; j++) {
    float4 two = p[j];
    float d0 = two.x; int m0 = __float_as_int(two.y);
    float d1 = two.z; int m1 = __float_as_int(two.w);
    if ((d0 < cm) || ((d0 == cm) && (m0 < cmi))) ins(d0, m0);
    if ((d1 < cm) || ((d1 == cm) && (m1 < cmi))) ins(d1, m1);
  }
  size_t base = (size_t)qi * KK;
#pragma unroll
  for (int j = 0; j < 16; j++) idx_out[base + j] = di[j];
}

// ---------------- rel_pos first/second moments (BN2d stats via linearity) ----------------
__global__ __launch_bounds__(256) void mom_k(const float* __restrict__ xyz_hr,
    const float* __restrict__ xyzT, const int* __restrict__ idxb, double* __restrict__ mom)
{
  float a0=0,a1=0,a2=0,a3=0,a4=0,a5=0,a6=0,a7=0,a8=0;
  const size_t total = (size_t)BB * NN * KK;
  for (size_t i = (size_t)blockIdx.x * 256 + threadIdx.x; i < total; i += (size_t)gridDim.x * 256) {
    int b = (int)(i / ((size_t)NN * KK));
    int n = (int)((i / KK) % NN);
    int id = idxb[i];
    float ax = xyz_hr[(b * 3 + 0) * NN + n];
    float ay = xyz_hr[(b * 3 + 1) * NN + n];
    float az = xyz_hr[(b * 3 + 2) * NN + n];
    float4 p = ((const float4*)xyzT)[(size_t)b * MM + id];
    float rx = ax - p.x, ry = ay - p.y, rz = az - p.z;
    a0 += rx; a1 += ry; a2 += rz;
    a3 += rx * rx; a4 += ry * ry; a5 += rz * rz;
    a6 += rx * ry; a7 += rx * rz; a8 += ry * rz;
  }
  double d[9] = {a0,a1,a2,a3,a4,a5,a6,a7,a8};
#pragma unroll
  for (int j = 0; j < 9; j++)
    for (int o = 32; o >= 1; o >>= 1) d[j] += __shfl_down(d[j], o);
  __shared__ double sh[4][9];
  int w = threadIdx.x >> 6, l = threadIdx.x & 63;
  if (l == 0) { for (int j = 0; j < 9; j++) sh[w][j] = d[j]; }
  __syncthreads();
  if (threadIdx.x == 0) {
    for (int wv = 1; wv < 4; wv++) for (int j = 0; j < 9; j++) d[j] += sh[wv][j];
    for (int j = 0; j < 9; j++) atomicAdd(&mom[j], d[j]);
  }
}

__global__ void bn2fin_k(const double* __restrict__ mom, const float* __restrict__ w1,
    const float* __restrict__ b1, const float* __restrict__ g,
    const float* __restrict__ bt, float* __restrict__ AB)
{
  int c = threadIdx.x;
  if (c >= CQ) return;
  double cnt = (double)BB * NN * KK;
  double mx = mom[0]/cnt, my = mom[1]/cnt, mz = mom[2]/cnt;
  double cxx = mom[3]/cnt - mx*mx, cyy = mom[4]/cnt - my*my, czz = mom[5]/cnt - mz*mz;
  double cxy = mom[6]/cnt - mx*my, cxz = mom[7]/cnt - mx*mz, cyz = mom[8]/cnt - my*mz;
  double wx = w1[c*3], wy = w1[c*3+1], wz = w1[c*3+2];
  double mean = wx*mx + wy*my + wz*mz + (double)b1[c];
  double var = wx*wx*cxx + wy*wy*cyy + wz*wz*czz + 2.0*(wx*wy*cxy + wx*wz*cxz + wy*wz*cyz);
  double A = (double)g[c] / sqrt(var + EPSV);
  AB[c] = (float)A;
  AB[CQ + c] = (float)((double)bt[c] - mean * A);
}

// ---------------- fused pos-enc + attention + output ----------------
__global__ __launch_bounds__(256) void attn_k(
    const float* __restrict__ Q, const float* __restrict__ Qp,
    const float* __restrict__ KfT, const int* __restrict__ idxb,
    const float* __restrict__ xyzT, const float* __restrict__ valT,
    const float* __restrict__ xyz_hr, const float* __restrict__ AB,
    const float* __restrict__ w1, const float* __restrict__ b1,
    const float* __restrict__ b2, float* __restrict__ out)
{
  __shared__ float q_s[CQ * 16], qp_s[CQ * 16];
  const int ngrp = NN / 16;
  int b = blockIdx.x / ngrp;
  int n0 = (blockIdx.x % ngrp) * 16;
  for (int t = threadIdx.x; t < CQ * 16; t += 256) {
    int c = t >> 4, j = t & 15;
    q_s[t]  = Q [((size_t)b * CQ + c) * NN + n0 + j];
    qp_s[t] = Qp[((size_t)b * CQ + c) * NN + n0 + j];
  }
  __syncthreads();
  int q = threadIdx.x >> 4, k = threadIdx.x & 15;
  int n = n0 + q;
  int id = idxb[((size_t)b * NN + n) * KK + k];
  float ax = xyz_hr[(b * 3 + 0) * NN + n];
  float ay = xyz_hr[(b * 3 + 1) * NN + n];
  float az = xyz_hr[(b * 3 + 2) * NN + n];
  float4 pl = ((const float4*)xyzT)[(size_t)b * MM + id];
  float rx = ax - pl.x, ry = ay - pl.y, rz = az - pl.z;
  const float4* kg = (const float4*)(KfT + ((size_t)b * MM + id) * CQ);
  float s = 0.f;
#pragma unroll
  for (int c4 = 0; c4 < CQ / 4; c4++) {
    float4 g4 = kg[c4];
    float ga[4] = {g4.x, g4.y, g4.z, g4.w};
#pragma unroll
    for (int u = 0; u < 4; u++) {
      int c = 4 * c4 + u;
      float t0 = fmaf(w1[c * 3 + 0], rx, fmaf(w1[c * 3 + 1], ry, w1[c * 3 + 2] * rz)) + b1[c];
      float pe = fmaxf(fmaf(t0, AB[c], AB[CQ + c]), 0.f);
      s = fmaf(q_s[c * 16 + q], ga[u] + b2[c], s);
      s = fmaf(qp_s[c * 16 + q], pe, s);
    }
  }
  s *= 0.125f;  // /sqrt(64)
  float mx = s;
#pragma unroll
  for (int o = 8; o >= 1; o >>= 1) mx = fmaxf(mx, __shfl_xor(mx, o, 16));
  float p = expf(s - mx);
  float sum = p;
#pragma unroll
  for (int o = 8; o >= 1; o >>= 1) sum += __shfl_xor(sum, o, 16);
  float attn = p / sum;
  const float4* vt = (const float4*)(valT + ((size_t)b * MM + id) * 8);
  float4 va = vt[0], vb = vt[1];
  float oc[6] = {attn*va.x, attn*va.y, attn*va.z, attn*va.w, attn*vb.x, attn*vb.y};
#pragma unroll
  for (int c = 0; c < 6; c++) {
    float a = oc[c];
#pragma unroll
    for (int o = 8; o >= 1; o >>= 1) a += __shfl_xor(a, o, 16);
    oc[c] = a;
  }
  if (k == 0) {
#pragma unroll
    for (int c = 0; c < 6; c++) out[((size_t)b * 6 + c) * NN + n] = oc[c];
  }
}

extern "C" void kernel_launch(void* const* d_in, const int* in_sizes, int n_in,
                              void* d_out, int out_size, void* d_ws, size_t ws_size,
                              hipStream_t stream)
{
  const float* xyz_hr = (const float*)d_in[0];
  const float* xyz_lr = (const float*)d_in[1];
  const float* val_lr = (const float*)d_in[2];
  const float* feat_hr= (const float*)d_in[3];
  const float* feat_lr= (const float*)d_in[4];
  const float* ge_w1 = (const float*)d_in[5];
  const float* ge_b1 = (const float*)d_in[6];
  const float* ge_g1 = (const float*)d_in[7];
  const float* ge_bt1= (const float*)d_in[8];
  const float* ge_w2 = (const float*)d_in[9];
  const float* ge_b2 = (const float*)d_in[10];
  const float* ge_g2 = (const float*)d_in[11];
  const float* ge_bt2= (const float*)d_in[12];
  const float* sc_w = (const float*)d_in[13];
  const float* sc_b = (const float*)d_in[14];
  const float* sh_w = (const float*)d_in[15];
  const float* sh_b = (const float*)d_in[16];
  const float* q_w  = (const float*)d_in[17];
  const float* q_b  = (const float*)d_in[18];
  const float* k_w  = (const float*)d_in[19];
  const float* k_b  = (const float*)d_in[20];
  const float* bh_w1= (const float*)d_in[21];
  const float* bh_b1= (const float*)d_in[22];
  const float* bh_g = (const float*)d_in[23];
  const float* bh_bt= (const float*)d_in[24];
  const float* bh_w2= (const float*)d_in[25];
  const float* bh_b2= (const float*)d_in[26];
  const float* rp_w1= (const float*)d_in[27];
  const float* rp_b1= (const float*)d_in[28];
  const float* rp_g = (const float*)d_in[29];
  const float* rp_bt= (const float*)d_in[30];
  const float* rp_w2= (const float*)d_in[31];
  const float* rp_b2= (const float*)d_in[32];
  float* out = (float*)d_out;

  double* mom = (double*)d_ws;
  float* base = (float*)((char*)d_ws + 128);
  float* AB1h = base;          // 128
  float* AB2h = base + 128;    // 128
  float* AB1l = base + 256;    // 128
  float* AB2l = base + 384;    // 128
  float* ABb  = base + 512;    // 64
  float* AB2d = base + 576;    // 128
  float* big  = base + 768;
  float* t1_hr = big;                      // 2*64*16384
  float* t2_hr = t1_hr + 2097152;
  float* Qb    = t2_hr + 2097152;
  float* Qp    = Qb    + 2097152;
  float* t1_lr = Qp    + 2097152;          // 2*64*4096
  float* t2_lr = t1_lr + 524288;
  float* glr   = t2_lr + 524288;
  float* KfT   = glr   + 524288;           // [B,M,64]
  float* tb    = KfT   + 524288;           // 2*32*16384
  float* xyzT  = tb    + 1048576;          // [B,M,4]
  float* valT  = xyzT  + 32768;            // [B,M,8]
  int*   idxb  = (int*)(valT + 65536);     // 2*16384*16
  // kNN partials (33.5 MB) overlay t1_hr..Qp — consumed before conv pipeline runs
  float2* part = (float2*)t1_hr;           // B*N * SPL*16 pairs

  hipMemsetAsync(mom, 0, 9 * sizeof(double), stream);

  tlr_k<<<32, 256, 0, stream>>>(xyz_lr, val_lr, xyzT, valT);

  // ---- kNN first (uses the big region as scratch) ----
  knnA_k<<<(BB * NN * SPL) / 256, 256, 0, stream>>>(xyz_hr, xyzT, part);
  knnB_k<<<(BB * NN) / 256, 256, 0, stream>>>(part, idxb);
  mom_k<<<512, 256, 0, stream>>>(xyz_hr, xyzT, idxb, mom);
  bn2fin_k<<<1, 64, 0, stream>>>(mom, rp_w1, rp_b1, rp_g, rp_bt, AB2d);

  // ---- encoder pipeline (overwrites the kNN scratch) ----
  conv_k<GEOC, CQ, false, false><<<128, 256, 0, stream>>>(feat_hr, ge_w1, ge_b1, nullptr, t1_hr, NN);
  conv_k<GEOC, CQ, false, false><<<32,  256, 0, stream>>>(feat_lr, ge_w1, ge_b1, nullptr, t1_lr, MM);
  stats_k<CQ><<<64, 256, 0, stream>>>(t1_hr, NN, ge_g1, ge_bt1, AB1h);
  stats_k<CQ><<<64, 256, 0, stream>>>(t1_lr, MM, ge_g1, ge_bt1, AB1l);
  conv_k<CQ, CQ, false, false><<<128, 256, 0, stream>>>(t1_hr, ge_w2, ge_b2, AB1h, t2_hr, NN);
  conv_k<CQ, CQ, false, false><<<32,  256, 0, stream>>>(t1_lr, ge_w2, ge_b2, AB1l, t2_lr, MM);
  stats_k<CQ><<<64, 256, 0, stream>>>(t2_hr, NN, ge_g2, ge_bt2, AB2h);
  stats_k<CQ><<<64, 256, 0, stream>>>(t2_lr, MM, ge_g2, ge_bt2, AB2l);

  film_k<<<2048, 256, 0, stream>>>(t2_lr, AB2l, val_lr, sc_w, sc_b, sh_w, sh_b, glr);
  conv_k<CQ, CQ, true, false><<<32, 256, 0, stream>>>(glr, k_w, k_b, nullptr, KfT, MM);

  conv_k<CQ, 32, false, false><<<128, 256, 0, stream>>>(t2_hr, bh_w1, bh_b1, AB2h, tb, NN);
  stats_k<32><<<32, 256, 0, stream>>>(tb, NN, bh_g, bh_bt, ABb);
  bdy_k<<<128, 256, 0, stream>>>(tb, ABb, bh_w2, bh_b2, out + (size_t)BB * 6 * NN);

  conv_k<CQ, CQ, false, false><<<128, 256, 0, stream>>>(t2_hr, q_w, q_b, AB2h, Qb, NN);
  conv_k<CQ, CQ, false, true><<<128, 256, 0, stream>>>(Qb, rp_w2, nullptr, nullptr, Qp, NN);

  attn_k<<<2048, 256, 0, stream>>>(Qb, Qp, KfT, idxb, xyzT, valT, xyz_hr, AB2d,
                                   rp_w1, rp_b1, rp_b2, out);
}

// Round 5
// 833.712 us; speedup vs baseline: 3.3398x; 1.7425x over previous
//
#include <hip/hip_runtime.h>

#define BB 2
#define NN 16384
#define MM 4096
#define KK 16
#define CQ 64
#define GEOC 18
#define EPSV 1e-5
#define SPL 8   // M-split per query for kNN phase A

// exact numpy-order fp32 squared distance; contract(off) so bits are identical
// in every kernel that evaluates it (phase A gate vs phase C recollect).
__device__ __forceinline__ float dist2f(float sa, float ax, float ay, float az, float4 p) {
#pragma clang fp contract(off)
  return (sa + p.w) - 2.0f * ((ax * p.x + ay * p.y) + az * p.z);
}

// ---------------- transpose lr points/values (with |b|^2 precomputed) ----------------
__global__ __launch_bounds__(256) void tlr_k(const float* __restrict__ xyz,
    const float* __restrict__ val, float* __restrict__ xyzT, float* __restrict__ valT)
{
#pragma clang fp contract(off)
  int i = blockIdx.x * 256 + threadIdx.x;  // B*M
  int b = i / MM, m = i % MM;
  float x = xyz[(b * 3 + 0) * MM + m];
  float y = xyz[(b * 3 + 1) * MM + m];
  float z = xyz[(b * 3 + 2) * MM + m];
  float sb = (x * x + y * y) + z * z;      // exact numpy order: (x2+y2)+z2
  ((float4*)xyzT)[i] = make_float4(x, y, z, sb);
  float v0 = val[((size_t)b * 6 + 0) * MM + m];
  float v1 = val[((size_t)b * 6 + 1) * MM + m];
  float v2 = val[((size_t)b * 6 + 2) * MM + m];
  float v3 = val[((size_t)b * 6 + 3) * MM + m];
  float v4 = val[((size_t)b * 6 + 4) * MM + m];
  float v5 = val[((size_t)b * 6 + 5) * MM + m];
  ((float4*)valT)[2 * i]     = make_float4(v0, v1, v2, v3);
  ((float4*)valT)[2 * i + 1] = make_float4(v4, v5, 0.f, 0.f);
}

// ---------------- generic 1x1 conv; OBLK outputs/thread; optional fused BN+ReLU input ----------------
template<int CIN, int COUT, int OBLK, bool TOUT, bool TW>
__global__ __launch_bounds__(256) void conv_k(const float* __restrict__ x,
    const float* __restrict__ W, const float* __restrict__ bias,
    const float* __restrict__ AB, float* __restrict__ y, int L)
{
  int tid = blockIdx.x * 256 + threadIdx.x;   // B*L*(COUT/OBLK)
  int g = tid / (BB * L);                     // output-channel group (i fastest -> coalesced)
  int i = tid % (BB * L);
  int b = i / L, n = i % L;
  const float* xp = x + (size_t)b * CIN * L + n;
  float xr[CIN];
#pragma unroll
  for (int c = 0; c < CIN; c++) {
    float v = xp[(size_t)c * L];
    if (AB) v = fmaxf(fmaf(v, AB[c], AB[CIN + c]), 0.f);
    xr[c] = v;
  }
#pragma unroll
  for (int oo = 0; oo < OBLK; oo++) {
    int o = g * OBLK + oo;
    float acc = bias ? bias[o] : 0.f;
#pragma unroll
    for (int c = 0; c < CIN; c++)
      acc = fmaf(TW ? W[(size_t)c * COUT + o] : W[(size_t)o * CIN + c], xr[c], acc);
    if (TOUT) y[((size_t)b * L + n) * COUT + o] = acc;
    else      y[((size_t)b * COUT + o) * L + n] = acc;
  }
}

// ---------------- per-channel BN stats -> fused (A,B): y = relu(x*A + B) ----------------
template<int C>
__global__ __launch_bounds__(256) void stats_k(const float* __restrict__ t, int L,
    const float* __restrict__ g, const float* __restrict__ bt, float* __restrict__ AB)
{
  int c = blockIdx.x;
  double s = 0.0, ss = 0.0;
  for (int b = 0; b < BB; b++) {
    const float* p = t + ((size_t)b * C + c) * L;
    for (int i = threadIdx.x; i < L; i += 256) { double v = p[i]; s += v; ss += v * v; }
  }
  for (int o = 32; o >= 1; o >>= 1) { s += __shfl_down(s, o); ss += __shfl_down(ss, o); }
  __shared__ double sh[8];
  int w = threadIdx.x >> 6;
  if ((threadIdx.x & 63) == 0) { sh[2 * w] = s; sh[2 * w + 1] = ss; }
  __syncthreads();
  if (threadIdx.x == 0) {
    for (int j = 1; j < 4; j++) { s += sh[2 * j]; ss += sh[2 * j + 1]; }
    double n = (double)BB * L;
    double mean = s / n, var = ss / n - mean * mean;
    double A = (double)g[c] / sqrt(var + EPSV);
    AB[c] = (float)A;
    AB[C + c] = (float)((double)bt[c] - mean * A);
  }
}

// ---------------- FiLM: glr = relu(bn(t2))*(1+scale)+shift ----------------
__global__ __launch_bounds__(256) void film_k(const float* __restrict__ t2,
    const float* __restrict__ AB, const float* __restrict__ val,
    const float* __restrict__ scw, const float* __restrict__ scb,
    const float* __restrict__ shw, const float* __restrict__ shb,
    float* __restrict__ gout)
{
  int i = blockIdx.x * 256 + threadIdx.x;  // B*64*M
  int b = i / (CQ * MM);
  int c = (i / MM) % CQ;
  int m = i % MM;
  float gv = fmaxf(fmaf(t2[i], AB[c], AB[CQ + c]), 0.f);
  float sc = scb[c], sh = shb[c];
#pragma unroll
  for (int j = 0; j < 6; j++) {
    float v = val[((size_t)b * 6 + j) * MM + m];
    sc = fmaf(scw[c * 6 + j], v, sc);
    sh = fmaf(shw[c * 6 + j], v, sh);
  }
  gout[i] = fmaf(gv, 1.f + sc, sh);
}

// ---------------- boundary head output ----------------
__global__ __launch_bounds__(256) void bdy_k(const float* __restrict__ tb,
    const float* __restrict__ AB, const float* __restrict__ w2,
    const float* __restrict__ b2, float* __restrict__ out2)
{
  int i = blockIdx.x * 256 + threadIdx.x;  // B*N
  int b = i / NN, n = i % NN;
  float acc = b2[0];
#pragma unroll
  for (int c = 0; c < 32; c++) {
    float v = tb[((size_t)b * 32 + c) * NN + n];
    v = fmaxf(fmaf(v, AB[c], AB[32 + c]), 0.f);
    acc = fmaf(w2[c], v, acc);
  }
  out2[i] = 1.f / (1.f + expf(-acc));
}

// ---------------- kNN phase A: per-(query, residue) top-16 VALUES via min/max network ----------------
__global__ __launch_bounds__(256) void knnA_k(const float* __restrict__ xyz_hr,
    const float* __restrict__ xyzT, float* __restrict__ partv)
{
#pragma clang fp contract(off)
  int tid = blockIdx.x * 256 + threadIdx.x;  // B*N*SPL
  int s = tid & (SPL - 1);
  int qi = tid / SPL;                        // b*NN + n
  int b = qi / NN, n = qi % NN;
  float ax = xyz_hr[(b * 3 + 0) * NN + n];
  float ay = xyz_hr[(b * 3 + 1) * NN + n];
  float az = xyz_hr[(b * 3 + 2) * NN + n];
  float sa = (ax * ax + ay * ay) + az * az;
  const float4* __restrict__ Ps = ((const float4*)xyzT) + (size_t)b * MM + s;
  float dv[16];
#pragma unroll
  for (int j = 0; j < 16; j++) dv[j] = 3.4e38f;
  float cm = 3.4e38f;
  // sorted ascending; insert-and-drop-max: dv[j] = min(max(dv[j-1], t), dv[j])
  auto ins = [&](float t) {
#pragma unroll
    for (int j = 15; j >= 1; j--) dv[j] = fminf(fmaxf(dv[j - 1], t), dv[j]);
    dv[0] = fminf(t, dv[0]);
    cm = dv[15];
  };
  const int C = MM / SPL;  // 512 candidates per thread
  for (int j = 0; j < C; j += 4) {
    float d0 = dist2f(sa, ax, ay, az, Ps[(j + 0) * SPL]);
    float d1 = dist2f(sa, ax, ay, az, Ps[(j + 1) * SPL]);
    float d2 = dist2f(sa, ax, ay, az, Ps[(j + 2) * SPL]);
    float d3 = dist2f(sa, ax, ay, az, Ps[(j + 3) * SPL]);
    float mn = fminf(fminf(d0, d1), fminf(d2, d3));
    if (mn < cm) {
      if (d0 < cm) ins(d0);
      if (d1 < cm) ins(d1);
      if (d2 < cm) ins(d2);
      if (d3 < cm) ins(d3);
    }
  }
  float* op = partv + (size_t)qi * (SPL * 16) + s * 16;
#pragma unroll
  for (int j = 0; j < 16; j++) op[j] = dv[j];
}

// ---------------- kNN phase B: merge 128 values -> theta = 16th smallest ----------------
__global__ __launch_bounds__(256) void knnB_k(const float* __restrict__ partv,
    float* __restrict__ theta)
{
  int qi = blockIdx.x * 256 + threadIdx.x;  // B*N
  const float4* __restrict__ p = (const float4*)(partv + (size_t)qi * (SPL * 16));
  float dv[16];
#pragma unroll
  for (int j = 0; j < 16; j++) dv[j] = 3.4e38f;
  float cm = 3.4e38f;
  auto ins = [&](float t) {
#pragma unroll
    for (int j = 15; j >= 1; j--) dv[j] = fminf(fmaxf(dv[j - 1], t), dv[j]);
    dv[0] = fminf(t, dv[0]);
    cm = dv[15];
  };
  for (int j = 0; j < SPL * 16 / 4; j++) {
    float4 v = p[j];
    if (v.x < cm) ins(v.x);
    if (v.y < cm) ins(v.y);
    if (v.z < cm) ins(v.z);
    if (v.w < cm) ins(v.w);
  }
  theta[qi] = dv[15];
}

// ---------------- kNN phase C: one wave per query; collect idx with d<theta, ties d==theta by asc idx ----------------
__global__ __launch_bounds__(256) void knnC_k(const float* __restrict__ xyz_hr,
    const float* __restrict__ xyzT, const float* __restrict__ theta,
    int* __restrict__ idx_out)
{
#pragma clang fp contract(off)
  __shared__ int s_clt[4], s_ceq[4];
  __shared__ int s_lt[4][16];
  __shared__ int s_eq[4][64];
  int w = threadIdx.x >> 6, l = threadIdx.x & 63;
  int qi = blockIdx.x * 4 + w;               // B*N / 4 blocks
  int b = qi / NN, n = qi % NN;
  if (l == 0) { s_clt[w] = 0; s_ceq[w] = 0; }
  __syncthreads();
  float ax = xyz_hr[(b * 3 + 0) * NN + n];
  float ay = xyz_hr[(b * 3 + 1) * NN + n];
  float az = xyz_hr[(b * 3 + 2) * NN + n];
  float sa = (ax * ax + ay * ay) + az * az;
  float th = theta[qi];
  const float4* __restrict__ P = ((const float4*)xyzT) + (size_t)b * MM;
  for (int j = 0; j < MM / 64; j++) {
    int m = j * 64 + l;
    float d = dist2f(sa, ax, ay, az, P[m]);
    if (d < th) {
      int pos = atomicAdd(&s_clt[w], 1);
      if (pos < 16) s_lt[w][pos] = m;
    } else if (d == th) {
      int pos = atomicAdd(&s_ceq[w], 1);
      if (pos < 64) s_eq[w][pos] = m;
    }
  }
  __syncthreads();
  if (l == 0) {
    int clt = s_clt[w]; if (clt > 16) clt = 16;  // mathematically <= 15
    int ceq = s_ceq[w]; if (ceq > 64) ceq = 64;
    size_t base = (size_t)qi * KK;
    for (int j = 0; j < clt; j++) idx_out[base + j] = s_lt[w][j];
    int need = KK - clt;                          // >= 1, <= ceq
    for (int t = 0; t < need; t++) {
      int best = 0x7fffffff, bp = 0;
      for (int j = 0; j < ceq; j++) { int v = s_eq[w][j]; if (v < best) { best = v; bp = j; } }
      idx_out[base + clt + t] = best;
      s_eq[w][bp] = 0x7fffffff;
    }
  }
}

// ---------------- rel_pos first/second moments (BN2d stats via linearity) ----------------
__global__ __launch_bounds__(256) void mom_k(const float* __restrict__ xyz_hr,
    const float* __restrict__ xyzT, const int* __restrict__ idxb, double* __restrict__ mom)
{
  float a0=0,a1=0,a2=0,a3=0,a4=0,a5=0,a6=0,a7=0,a8=0;
  const size_t total = (size_t)BB * NN * KK;
  for (size_t i = (size_t)blockIdx.x * 256 + threadIdx.x; i < total; i += (size_t)gridDim.x * 256) {
    int b = (int)(i / ((size_t)NN * KK));
    int n = (int)((i / KK) % NN);
    int id = idxb[i];
    float ax = xyz_hr[(b * 3 + 0) * NN + n];
    float ay = xyz_hr[(b * 3 + 1) * NN + n];
    float az = xyz_hr[(b * 3 + 2) * NN + n];
    float4 p = ((const float4*)xyzT)[(size_t)b * MM + id];
    float rx = ax - p.x, ry = ay - p.y, rz = az - p.z;
    a0 += rx; a1 += ry; a2 += rz;
    a3 += rx * rx; a4 += ry * ry; a5 += rz * rz;
    a6 += rx * ry; a7 += rx * rz; a8 += ry * rz;
  }
  double d[9] = {a0,a1,a2,a3,a4,a5,a6,a7,a8};
#pragma unroll
  for (int j = 0; j < 9; j++)
    for (int o = 32; o >= 1; o >>= 1) d[j] += __shfl_down(d[j], o);
  __shared__ double sh[4][9];
  int w = threadIdx.x >> 6, l = threadIdx.x & 63;
  if (l == 0) { for (int j = 0; j < 9; j++) sh[w][j] = d[j]; }
  __syncthreads();
  if (threadIdx.x == 0) {
    for (int wv = 1; wv < 4; wv++) for (int j = 0; j < 9; j++) d[j] += sh[wv][j];
    for (int j = 0; j < 9; j++) atomicAdd(&mom[j], d[j]);
  }
}

__global__ void bn2fin_k(const double* __restrict__ mom, const float* __restrict__ w1,
    const float* __restrict__ b1, const float* __restrict__ g,
    const float* __restrict__ bt, float* __restrict__ AB)
{
  int c = threadIdx.x;
  if (c >= CQ) return;
  double cnt = (double)BB * NN * KK;
  double mx = mom[0]/cnt, my = mom[1]/cnt, mz = mom[2]/cnt;
  double cxx = mom[3]/cnt - mx*mx, cyy = mom[4]/cnt - my*my, czz = mom[5]/cnt - mz*mz;
  double cxy = mom[6]/cnt - mx*my, cxz = mom[7]/cnt - mx*mz, cyz = mom[8]/cnt - my*mz;
  double wx = w1[c*3], wy = w1[c*3+1], wz = w1[c*3+2];
  double mean = wx*mx + wy*my + wz*mz + (double)b1[c];
  double var = wx*wx*cxx + wy*wy*cyy + wz*wz*czz + 2.0*(wx*wy*cxy + wx*wz*cxz + wy*wz*cyz);
  double A = (double)g[c] / sqrt(var + EPSV);
  AB[c] = (float)A;
  AB[CQ + c] = (float)((double)bt[c] - mean * A);
}

// ---------------- fused pos-enc + attention + output ----------------
__global__ __launch_bounds__(256) void attn_k(
    const float* __restrict__ Q, const float* __restrict__ Qp,
    const float* __restrict__ KfT, const int* __restrict__ idxb,
    const float* __restrict__ xyzT, const float* __restrict__ valT,
    const float* __restrict__ xyz_hr, const float* __restrict__ AB,
    const float* __restrict__ w1, const float* __restrict__ b1,
    const float* __restrict__ b2, float* __restrict__ out)
{
  __shared__ float q_s[CQ * 16], qp_s[CQ * 16];
  const int ngrp = NN / 16;
  int b = blockIdx.x / ngrp;
  int n0 = (blockIdx.x % ngrp) * 16;
  for (int t = threadIdx.x; t < CQ * 16; t += 256) {
    int c = t >> 4, j = t & 15;
    q_s[t]  = Q [((size_t)b * CQ + c) * NN + n0 + j];
    qp_s[t] = Qp[((size_t)b * CQ + c) * NN + n0 + j];
  }
  __syncthreads();
  int q = threadIdx.x >> 4, k = threadIdx.x & 15;
  int n = n0 + q;
  int id = idxb[((size_t)b * NN + n) * KK + k];
  float ax = xyz_hr[(b * 3 + 0) * NN + n];
  float ay = xyz_hr[(b * 3 + 1) * NN + n];
  float az = xyz_hr[(b * 3 + 2) * NN + n];
  float4 pl = ((const float4*)xyzT)[(size_t)b * MM + id];
  float rx = ax - pl.x, ry = ay - pl.y, rz = az - pl.z;
  const float4* kg = (const float4*)(KfT + ((size_t)b * MM + id) * CQ);
  float s = 0.f;
#pragma unroll
  for (int c4 = 0; c4 < CQ / 4; c4++) {
    float4 g4 = kg[c4];
    float ga[4] = {g4.x, g4.y, g4.z, g4.w};
#pragma unroll
    for (int u = 0; u < 4; u++) {
      int c = 4 * c4 + u;
      float t0 = fmaf(w1[c * 3 + 0], rx, fmaf(w1[c * 3 + 1], ry, w1[c * 3 + 2] * rz)) + b1[c];
      float pe = fmaxf(fmaf(t0, AB[c], AB[CQ + c]), 0.f);
      s = fmaf(q_s[c * 16 + q], ga[u] + b2[c], s);
      s = fmaf(qp_s[c * 16 + q], pe, s);
    }
  }
  s *= 0.125f;  // /sqrt(64)
  float mx = s;
#pragma unroll
  for (int o = 8; o >= 1; o >>= 1) mx = fmaxf(mx, __shfl_xor(mx, o, 16));
  float p = expf(s - mx);
  float sum = p;
#pragma unroll
  for (int o = 8; o >= 1; o >>= 1) sum += __shfl_xor(sum, o, 16);
  float attn = p / sum;
  const float4* vt = (const float4*)(valT + ((size_t)b * MM + id) * 8);
  float4 va = vt[0], vb = vt[1];
  float oc[6] = {attn*va.x, attn*va.y, attn*va.z, attn*va.w, attn*vb.x, attn*vb.y};
#pragma unroll
  for (int c = 0; c < 6; c++) {
    float a = oc[c];
#pragma unroll
    for (int o = 8; o >= 1; o >>= 1) a += __shfl_xor(a, o, 16);
    oc[c] = a;
  }
  if (k == 0) {
#pragma unroll
    for (int c = 0; c < 6; c++) out[((size_t)b * 6 + c) * NN + n] = oc[c];
  }
}

extern "C" void kernel_launch(void* const* d_in, const int* in_sizes, int n_in,
                              void* d_out, int out_size, void* d_ws, size_t ws_size,
                              hipStream_t stream)
{
  const float* xyz_hr = (const float*)d_in[0];
  const float* xyz_lr = (const float*)d_in[1];
  const float* val_lr = (const float*)d_in[2];
  const float* feat_hr= (const float*)d_in[3];
  const float* feat_lr= (const float*)d_in[4];
  const float* ge_w1 = (const float*)d_in[5];
  const float* ge_b1 = (const float*)d_in[6];
  const float* ge_g1 = (const float*)d_in[7];
  const float* ge_bt1= (const float*)d_in[8];
  const float* ge_w2 = (const float*)d_in[9];
  const float* ge_b2 = (const float*)d_in[10];
  const float* ge_g2 = (const float*)d_in[11];
  const float* ge_bt2= (const float*)d_in[12];
  const float* sc_w = (const float*)d_in[13];
  const float* sc_b = (const float*)d_in[14];
  const float* sh_w = (const float*)d_in[15];
  const float* sh_b = (const float*)d_in[16];
  const float* q_w  = (const float*)d_in[17];
  const float* q_b  = (const float*)d_in[18];
  const float* k_w  = (const float*)d_in[19];
  const float* k_b  = (const float*)d_in[20];
  const float* bh_w1= (const float*)d_in[21];
  const float* bh_b1= (const float*)d_in[22];
  const float* bh_g = (const float*)d_in[23];
  const float* bh_bt= (const float*)d_in[24];
  const float* bh_w2= (const float*)d_in[25];
  const float* bh_b2= (const float*)d_in[26];
  const float* rp_w1= (const float*)d_in[27];
  const float* rp_b1= (const float*)d_in[28];
  const float* rp_g = (const float*)d_in[29];
  const float* rp_bt= (const float*)d_in[30];
  const float* rp_w2= (const float*)d_in[31];
  const float* rp_b2= (const float*)d_in[32];
  float* out = (float*)d_out;

  double* mom = (double*)d_ws;
  float* base = (float*)((char*)d_ws + 128);
  float* AB1h = base;          // 128
  float* AB2h = base + 128;    // 128
  float* AB1l = base + 256;    // 128
  float* AB2l = base + 384;    // 128
  float* ABb  = base + 512;    // 64
  float* AB2d = base + 576;    // 128
  float* big  = base + 768;
  float* t1_hr = big;                      // 2*64*16384
  float* t2_hr = t1_hr + 2097152;
  float* Qb    = t2_hr + 2097152;
  float* Qp    = Qb    + 2097152;
  float* t1_lr = Qp    + 2097152;          // 2*64*4096
  float* t2_lr = t1_lr + 524288;
  float* glr   = t2_lr + 524288;
  float* KfT   = glr   + 524288;           // [B,M,64]
  float* tb    = KfT   + 524288;           // 2*32*16384
  float* xyzT  = tb    + 1048576;          // [B,M,4]
  float* valT  = xyzT  + 32768;            // [B,M,8]
  int*   idxb  = (int*)(valT + 65536);     // 2*16384*16
  // kNN scratch overlays the conv temporaries (consumed before conv pipeline):
  float* partv = t1_hr;                    // B*N*SPL*16 floats = 4.19M (t1_hr + t2_hr)
  float* theta = Qb;                       // B*N floats

  (void)hipMemsetAsync(mom, 0, 9 * sizeof(double), stream);

  tlr_k<<<32, 256, 0, stream>>>(xyz_lr, val_lr, xyzT, valT);

  // ---- kNN first (uses the big region as scratch) ----
  knnA_k<<<(BB * NN * SPL) / 256, 256, 0, stream>>>(xyz_hr, xyzT, partv);
  knnB_k<<<(BB * NN) / 256, 256, 0, stream>>>(partv, theta);
  knnC_k<<<(BB * NN) / 4, 256, 0, stream>>>(xyz_hr, xyzT, theta, idxb);
  mom_k<<<512, 256, 0, stream>>>(xyz_hr, xyzT, idxb, mom);
  bn2fin_k<<<1, 64, 0, stream>>>(mom, rp_w1, rp_b1, rp_g, rp_bt, AB2d);

  // ---- encoder pipeline (overwrites the kNN scratch) ----
  conv_k<GEOC, CQ, 16, false, false><<<512, 256, 0, stream>>>(feat_hr, ge_w1, ge_b1, nullptr, t1_hr, NN);
  conv_k<GEOC, CQ, 16, false, false><<<128, 256, 0, stream>>>(feat_lr, ge_w1, ge_b1, nullptr, t1_lr, MM);
  stats_k<CQ><<<64, 256, 0, stream>>>(t1_hr, NN, ge_g1, ge_bt1, AB1h);
  stats_k<CQ><<<64, 256, 0, stream>>>(t1_lr, MM, ge_g1, ge_bt1, AB1l);
  conv_k<CQ, CQ, 16, false, false><<<512, 256, 0, stream>>>(t1_hr, ge_w2, ge_b2, AB1h, t2_hr, NN);
  conv_k<CQ, CQ, 16, false, false><<<128, 256, 0, stream>>>(t1_lr, ge_w2, ge_b2, AB1l, t2_lr, MM);
  stats_k<CQ><<<64, 256, 0, stream>>>(t2_hr, NN, ge_g2, ge_bt2, AB2h);
  stats_k<CQ><<<64, 256, 0, stream>>>(t2_lr, MM, ge_g2, ge_bt2, AB2l);

  film_k<<<2048, 256, 0, stream>>>(t2_lr, AB2l, val_lr, sc_w, sc_b, sh_w, sh_b, glr);
  conv_k<CQ, CQ, 16, true, false><<<128, 256, 0, stream>>>(glr, k_w, k_b, nullptr, KfT, MM);

  conv_k<CQ, 32, 16, false, false><<<256, 256, 0, stream>>>(t2_hr, bh_w1, bh_b1, AB2h, tb, NN);
  stats_k<32><<<32, 256, 0, stream>>>(tb, NN, bh_g, bh_bt, ABb);
  bdy_k<<<128, 256, 0, stream>>>(tb, ABb, bh_w2, bh_b2, out + (size_t)BB * 6 * NN);

  conv_k<CQ, CQ, 16, false, false><<<512, 256, 0, stream>>>(t2_hr, q_w, q_b, AB2h, Qb, NN);
  conv_k<CQ, CQ, 16, false, true><<<512, 256, 0, stream>>>(Qb, rp_w2, nullptr, nullptr, Qp, NN);

  attn_k<<<2048, 256, 0, stream>>>(Qb, Qp, KfT, idxb, xyzT, valT, xyz_hr, AB2d,
                                   rp_w1, rp_b1, rp_b2, out);
}

// Round 6
// 734.124 us; speedup vs baseline: 3.7928x; 1.1357x over previous
//
#include <hip/hip_runtime.h>

#define BB 2
#define NN 16384
#define MM 4096
#define KK 16
#define CQ 64
#define GEOC 18
#define EPSV 1e-5
#define SPL 8   // M-split per query for kNN phase A

// exact numpy-order fp32 squared distance; contract(off) so bits are identical
// in every kernel that evaluates it (phase A/B values vs phase C recollect).
__device__ __forceinline__ float dist2f(float sa, float ax, float ay, float az, float4 p) {
#pragma clang fp contract(off)
  return (sa + p.w) - 2.0f * ((ax * p.x + ay * p.y) + az * p.z);
}

// ---------------- transpose lr points/values (with |b|^2 precomputed) ----------------
__global__ __launch_bounds__(256) void tlr_k(const float* __restrict__ xyz,
    const float* __restrict__ val, float* __restrict__ xyzT, float* __restrict__ valT)
{
#pragma clang fp contract(off)
  int i = blockIdx.x * 256 + threadIdx.x;  // B*M
  int b = i / MM, m = i % MM;
  float x = xyz[(b * 3 + 0) * MM + m];
  float y = xyz[(b * 3 + 1) * MM + m];
  float z = xyz[(b * 3 + 2) * MM + m];
  float sb = (x * x + y * y) + z * z;      // exact numpy order: (x2+y2)+z2
  ((float4*)xyzT)[i] = make_float4(x, y, z, sb);
  float v0 = val[((size_t)b * 6 + 0) * MM + m];
  float v1 = val[((size_t)b * 6 + 1) * MM + m];
  float v2 = val[((size_t)b * 6 + 2) * MM + m];
  float v3 = val[((size_t)b * 6 + 3) * MM + m];
  float v4 = val[((size_t)b * 6 + 4) * MM + m];
  float v5 = val[((size_t)b * 6 + 5) * MM + m];
  ((float4*)valT)[2 * i]     = make_float4(v0, v1, v2, v3);
  ((float4*)valT)[2 * i + 1] = make_float4(v4, v5, 0.f, 0.f);
}

// ---------------- generic 1x1 conv; OBLK outputs/thread; optional fused BN+ReLU input ----------------
template<int CIN, int COUT, int OBLK, bool TOUT, bool TW>
__global__ __launch_bounds__(256) void conv_k(const float* __restrict__ x,
    const float* __restrict__ W, const float* __restrict__ bias,
    const float* __restrict__ AB, float* __restrict__ y, int L)
{
  int tid = blockIdx.x * 256 + threadIdx.x;   // B*L*(COUT/OBLK)
  int g = tid / (BB * L);                     // output-channel group (i fastest -> coalesced)
  int i = tid % (BB * L);
  int b = i / L, n = i % L;
  const float* xp = x + (size_t)b * CIN * L + n;
  float xr[CIN];
#pragma unroll
  for (int c = 0; c < CIN; c++) {
    float v = xp[(size_t)c * L];
    if (AB) v = fmaxf(fmaf(v, AB[c], AB[CIN + c]), 0.f);
    xr[c] = v;
  }
#pragma unroll
  for (int oo = 0; oo < OBLK; oo++) {
    int o = g * OBLK + oo;
    float acc = bias ? bias[o] : 0.f;
#pragma unroll
    for (int c = 0; c < CIN; c++)
      acc = fmaf(TW ? W[(size_t)c * COUT + o] : W[(size_t)o * CIN + c], xr[c], acc);
    if (TOUT) y[((size_t)b * L + n) * COUT + o] = acc;
    else      y[((size_t)b * COUT + o) * L + n] = acc;
  }
}

// ------------- BN stats, two-phase in one kernel: partials + last-block finalize -------------
template<int C, int NCH>
__global__ __launch_bounds__(256) void stats2_k(const float* __restrict__ t, int L,
    const float* __restrict__ g, const float* __restrict__ bt,
    double* __restrict__ sums, int* __restrict__ counter, float* __restrict__ AB)
{
  int c = blockIdx.x % C;
  int ch = blockIdx.x / C;
  const size_t tot = (size_t)BB * L;
  const size_t slab = tot / NCH;
  size_t beg = slab * ch, end = beg + slab;
  double s = 0.0, ss = 0.0;
  for (size_t idx = beg + threadIdx.x; idx < end; idx += 256) {
    int b = (int)(idx / L); int i = (int)(idx % L);
    double v = t[((size_t)b * C + c) * L + i];
    s += v; ss += v * v;
  }
  for (int o = 32; o >= 1; o >>= 1) { s += __shfl_down(s, o); ss += __shfl_down(ss, o); }
  __shared__ double sh[8];
  __shared__ int lastf;
  int w = threadIdx.x >> 6;
  if ((threadIdx.x & 63) == 0) { sh[2 * w] = s; sh[2 * w + 1] = ss; }
  __syncthreads();
  if (threadIdx.x == 0) {
    for (int j = 1; j < 4; j++) { s += sh[2 * j]; ss += sh[2 * j + 1]; }
    atomicAdd(&sums[c], s);
    atomicAdd(&sums[C + c], ss);
    __threadfence();
    int old = atomicAdd(counter, 1);
    lastf = (old == C * NCH - 1) ? 1 : 0;
  }
  __syncthreads();
  if (lastf && threadIdx.x < C) {
    __threadfence();
    int cc = threadIdx.x;
    double S  = atomicAdd(&sums[cc], 0.0);       // coherent read
    double SS = atomicAdd(&sums[C + cc], 0.0);
    double nn = (double)BB * L;
    double mean = S / nn, var = SS / nn - mean * mean;
    double A = (double)g[cc] / sqrt(var + EPSV);
    AB[cc] = (float)A;
    AB[C + cc] = (float)((double)bt[cc] - mean * A);
  }
}

// ---------------- FiLM: glr = relu(bn(t2))*(1+scale)+shift ----------------
__global__ __launch_bounds__(256) void film_k(const float* __restrict__ t2,
    const float* __restrict__ AB, const float* __restrict__ val,
    const float* __restrict__ scw, const float* __restrict__ scb,
    const float* __restrict__ shw, const float* __restrict__ shb,
    float* __restrict__ gout)
{
  int i = blockIdx.x * 256 + threadIdx.x;  // B*64*M
  int b = i / (CQ * MM);
  int c = (i / MM) % CQ;
  int m = i % MM;
  float gv = fmaxf(fmaf(t2[i], AB[c], AB[CQ + c]), 0.f);
  float sc = scb[c], sh = shb[c];
#pragma unroll
  for (int j = 0; j < 6; j++) {
    float v = val[((size_t)b * 6 + j) * MM + m];
    sc = fmaf(scw[c * 6 + j], v, sc);
    sh = fmaf(shw[c * 6 + j], v, sh);
  }
  gout[i] = fmaf(gv, 1.f + sc, sh);
}

// ---------------- boundary head output ----------------
__global__ __launch_bounds__(256) void bdy_k(const float* __restrict__ tb,
    const float* __restrict__ AB, const float* __restrict__ w2,
    const float* __restrict__ b2, float* __restrict__ out2)
{
  int i = blockIdx.x * 256 + threadIdx.x;  // B*N
  int b = i / NN, n = i % NN;
  float acc = b2[0];
#pragma unroll
  for (int c = 0; c < 32; c++) {
    float v = tb[((size_t)b * 32 + c) * NN + n];
    v = fmaxf(fmaf(v, AB[c], AB[32 + c]), 0.f);
    acc = fmaf(w2[c], v, acc);
  }
  out2[i] = 1.f / (1.f + expf(-acc));
}

// ------- kNN phase A: per-(query, residue) top-16 VALUES, UNCONDITIONAL sorted insert -------
// wave-level insert probability ~1 anyway (m5 PMC), so gates/branches were pure overhead.
__global__ __launch_bounds__(256) void knnA_k(const float* __restrict__ xyz_hr,
    const float* __restrict__ xyzT, float* __restrict__ partv)
{
#pragma clang fp contract(off)
  int tid = blockIdx.x * 256 + threadIdx.x;  // B*N*SPL
  int s = tid & (SPL - 1);
  int qi = tid / SPL;                        // b*NN + n
  int b = qi / NN, n = qi % NN;
  float ax = xyz_hr[(b * 3 + 0) * NN + n];
  float ay = xyz_hr[(b * 3 + 1) * NN + n];
  float az = xyz_hr[(b * 3 + 2) * NN + n];
  float sa = (ax * ax + ay * ay) + az * az;
  const float4* __restrict__ Ps = ((const float4*)xyzT) + (size_t)b * MM + s;
  float dv[16];
#pragma unroll
  for (int j = 0; j < 16; j++) dv[j] = 3.4e38f;
  for (int j = 0; j < MM / SPL; j += 8) {
#pragma unroll
    for (int u = 0; u < 8; u++) {
      float4 p = Ps[(size_t)(j + u) * SPL];
      float t = dist2f(sa, ax, ay, az, p);
#pragma unroll
      for (int q = 15; q >= 1; q--) dv[q] = fminf(fmaxf(dv[q - 1], t), dv[q]);
      dv[0] = fminf(t, dv[0]);
    }
  }
  float4* op = (float4*)(partv + (size_t)qi * (SPL * 16) + s * 16);
#pragma unroll
  for (int q = 0; q < 4; q++)
    op[q] = make_float4(dv[4 * q], dv[4 * q + 1], dv[4 * q + 2], dv[4 * q + 3]);
}

// ---------------- kNN phase B: merge 128 values -> theta = 16th smallest ----------------
__global__ __launch_bounds__(256) void knnB_k(const float* __restrict__ partv,
    float* __restrict__ theta)
{
  int qi = blockIdx.x * 256 + threadIdx.x;  // B*N
  const float4* __restrict__ p = (const float4*)(partv + (size_t)qi * (SPL * 16));
  float dv[16];
#pragma unroll
  for (int j = 0; j < 16; j++) dv[j] = 3.4e38f;
  auto ins = [&](float t) {
#pragma unroll
    for (int j = 15; j >= 1; j--) dv[j] = fminf(fmaxf(dv[j - 1], t), dv[j]);
    dv[0] = fminf(t, dv[0]);
  };
  for (int j = 0; j < SPL * 16 / 4; j++) {
    float4 v = p[j];
    ins(v.x); ins(v.y); ins(v.z); ins(v.w);
  }
  theta[qi] = dv[15];
}

// ---------------- kNN phase C: one wave per query; collect idx with d<theta, ties d==theta by asc idx ----------------
__global__ __launch_bounds__(256) void knnC_k(const float* __restrict__ xyz_hr,
    const float* __restrict__ xyzT, const float* __restrict__ theta,
    int* __restrict__ idx_out)
{
#pragma clang fp contract(off)
  __shared__ int s_clt[4], s_ceq[4];
  __shared__ int s_lt[4][16];
  __shared__ int s_eq[4][64];
  int w = threadIdx.x >> 6, l = threadIdx.x & 63;
  int qi = blockIdx.x * 4 + w;               // B*N / 4 blocks
  int b = qi / NN, n = qi % NN;
  if (l == 0) { s_clt[w] = 0; s_ceq[w] = 0; }
  __syncthreads();
  float ax = xyz_hr[(b * 3 + 0) * NN + n];
  float ay = xyz_hr[(b * 3 + 1) * NN + n];
  float az = xyz_hr[(b * 3 + 2) * NN + n];
  float sa = (ax * ax + ay * ay) + az * az;
  float th = theta[qi];
  const float4* __restrict__ P = ((const float4*)xyzT) + (size_t)b * MM;
  for (int j = 0; j < MM / 64; j++) {
    int m = j * 64 + l;
    float d = dist2f(sa, ax, ay, az, P[m]);
    if (d < th) {
      int pos = atomicAdd(&s_clt[w], 1);
      if (pos < 16) s_lt[w][pos] = m;
    } else if (d == th) {
      int pos = atomicAdd(&s_ceq[w], 1);
      if (pos < 64) s_eq[w][pos] = m;
    }
  }
  __syncthreads();
  if (l == 0) {
    int clt = s_clt[w]; if (clt > 16) clt = 16;  // mathematically <= 15
    int ceq = s_ceq[w]; if (ceq > 64) ceq = 64;
    size_t base = (size_t)qi * KK;
    for (int j = 0; j < clt; j++) idx_out[base + j] = s_lt[w][j];
    int need = KK - clt;                          // >= 1, <= ceq
    for (int t = 0; t < need; t++) {
      int best = 0x7fffffff, bp = 0;
      for (int j = 0; j < ceq; j++) { int v = s_eq[w][j]; if (v < best) { best = v; bp = j; } }
      idx_out[base + clt + t] = best;
      s_eq[w][bp] = 0x7fffffff;
    }
  }
}

// -------- rel_pos moments (BN2d stats via linearity) + last-block AB2d finalize --------
__global__ __launch_bounds__(256) void mom_k(const float* __restrict__ xyz_hr,
    const float* __restrict__ xyzT, const int* __restrict__ idxb,
    double* __restrict__ mom, int* __restrict__ counter, int nblk,
    const float* __restrict__ w1, const float* __restrict__ b1,
    const float* __restrict__ g, const float* __restrict__ bt, float* __restrict__ AB)
{
  float a0=0,a1=0,a2=0,a3=0,a4=0,a5=0,a6=0,a7=0,a8=0;
  const size_t total = (size_t)BB * NN * KK;
  for (size_t i = (size_t)blockIdx.x * 256 + threadIdx.x; i < total; i += (size_t)nblk * 256) {
    int b = (int)(i / ((size_t)NN * KK));
    int n = (int)((i / KK) % NN);
    int id = idxb[i];
    float ax = xyz_hr[(b * 3 + 0) * NN + n];
    float ay = xyz_hr[(b * 3 + 1) * NN + n];
    float az = xyz_hr[(b * 3 + 2) * NN + n];
    float4 p = ((const float4*)xyzT)[(size_t)b * MM + id];
    float rx = ax - p.x, ry = ay - p.y, rz = az - p.z;
    a0 += rx; a1 += ry; a2 += rz;
    a3 += rx * rx; a4 += ry * ry; a5 += rz * rz;
    a6 += rx * ry; a7 += rx * rz; a8 += ry * rz;
  }
  double d[9] = {a0,a1,a2,a3,a4,a5,a6,a7,a8};
#pragma unroll
  for (int j = 0; j < 9; j++)
    for (int o = 32; o >= 1; o >>= 1) d[j] += __shfl_down(d[j], o);
  __shared__ double sh[4][9];
  __shared__ int lastf;
  int w = threadIdx.x >> 6, l = threadIdx.x & 63;
  if (l == 0) { for (int j = 0; j < 9; j++) sh[w][j] = d[j]; }
  __syncthreads();
  if (threadIdx.x == 0) {
    for (int wv = 1; wv < 4; wv++) for (int j = 0; j < 9; j++) d[j] += sh[wv][j];
    for (int j = 0; j < 9; j++) atomicAdd(&mom[j], d[j]);
    __threadfence();
    int old = atomicAdd(counter, 1);
    lastf = (old == nblk - 1) ? 1 : 0;
  }
  __syncthreads();
  if (lastf && threadIdx.x < CQ) {
    __threadfence();
    double mo[9];
    for (int j = 0; j < 9; j++) mo[j] = atomicAdd(&mom[j], 0.0);
    int c = threadIdx.x;
    double cnt = (double)BB * NN * KK;
    double mx = mo[0]/cnt, my = mo[1]/cnt, mz = mo[2]/cnt;
    double cxx = mo[3]/cnt - mx*mx, cyy = mo[4]/cnt - my*my, czz = mo[5]/cnt - mz*mz;
    double cxy = mo[6]/cnt - mx*my, cxz = mo[7]/cnt - mx*mz, cyz = mo[8]/cnt - my*mz;
    double wx = w1[c*3], wy = w1[c*3+1], wz = w1[c*3+2];
    double mean = wx*mx + wy*my + wz*mz + (double)b1[c];
    double var = wx*wx*cxx + wy*wy*cyy + wz*wz*czz + 2.0*(wx*wy*cxy + wx*wz*cxz + wy*wz*cyz);
    double A = (double)g[c] / sqrt(var + EPSV);
    AB[c] = (float)A;
    AB[CQ + c] = (float)((double)bt[c] - mean * A);
  }
}

// ---------------- fused pos-enc + attention + output ----------------
__global__ __launch_bounds__(256) void attn_k(
    const float* __restrict__ Q, const float* __restrict__ Qp,
    const float* __restrict__ KfT, const int* __restrict__ idxb,
    const float* __restrict__ xyzT, const float* __restrict__ valT,
    const float* __restrict__ xyz_hr, const float* __restrict__ AB,
    const float* __restrict__ w1, const float* __restrict__ b1,
    const float* __restrict__ b2, float* __restrict__ out)
{
  __shared__ float q_s[CQ * 16], qp_s[CQ * 16];
  const int ngrp = NN / 16;
  int b = blockIdx.x / ngrp;
  int n0 = (blockIdx.x % ngrp) * 16;
  for (int t = threadIdx.x; t < CQ * 16; t += 256) {
    int c = t >> 4, j = t & 15;
    q_s[t]  = Q [((size_t)b * CQ + c) * NN + n0 + j];
    qp_s[t] = Qp[((size_t)b * CQ + c) * NN + n0 + j];
  }
  __syncthreads();
  int q = threadIdx.x >> 4, k = threadIdx.x & 15;
  int n = n0 + q;
  int id = idxb[((size_t)b * NN + n) * KK + k];
  float ax = xyz_hr[(b * 3 + 0) * NN + n];
  float ay = xyz_hr[(b * 3 + 1) * NN + n];
  float az = xyz_hr[(b * 3 + 2) * NN + n];
  float4 pl = ((const float4*)xyzT)[(size_t)b * MM + id];
  float rx = ax - pl.x, ry = ay - pl.y, rz = az - pl.z;
  const float4* kg = (const float4*)(KfT + ((size_t)b * MM + id) * CQ);
  float s = 0.f;
#pragma unroll
  for (int c4 = 0; c4 < CQ / 4; c4++) {
    float4 g4 = kg[c4];
    float ga[4] = {g4.x, g4.y, g4.z, g4.w};
#pragma unroll
    for (int u = 0; u < 4; u++) {
      int c = 4 * c4 + u;
      float t0 = fmaf(w1[c * 3 + 0], rx, fmaf(w1[c * 3 + 1], ry, w1[c * 3 + 2] * rz)) + b1[c];
      float pe = fmaxf(fmaf(t0, AB[c], AB[CQ + c]), 0.f);
      s = fmaf(q_s[c * 16 + q], ga[u] + b2[c], s);
      s = fmaf(qp_s[c * 16 + q], pe, s);
    }
  }
  s *= 0.125f;  // /sqrt(64)
  float mx = s;
#pragma unroll
  for (int o = 8; o >= 1; o >>= 1) mx = fmaxf(mx, __shfl_xor(mx, o, 16));
  float p = expf(s - mx);
  float sum = p;
#pragma unroll
  for (int o = 8; o >= 1; o >>= 1) sum += __shfl_xor(sum, o, 16);
  float attn = p / sum;
  const float4* vt = (const float4*)(valT + ((size_t)b * MM + id) * 8);
  float4 va = vt[0], vb = vt[1];
  float oc[6] = {attn*va.x, attn*va.y, attn*va.z, attn*va.w, attn*vb.x, attn*vb.y};
#pragma unroll
  for (int c = 0; c < 6; c++) {
    float a = oc[c];
#pragma unroll
    for (int o = 8; o >= 1; o >>= 1) a += __shfl_xor(a, o, 16);
    oc[c] = a;
  }
  if (k == 0) {
#pragma unroll
    for (int c = 0; c < 6; c++) out[((size_t)b * 6 + c) * NN + n] = oc[c];
  }
}

extern "C" void kernel_launch(void* const* d_in, const int* in_sizes, int n_in,
                              void* d_out, int out_size, void* d_ws, size_t ws_size,
                              hipStream_t stream)
{
  const float* xyz_hr = (const float*)d_in[0];
  const float* xyz_lr = (const float*)d_in[1];
  const float* val_lr = (const float*)d_in[2];
  const float* feat_hr= (const float*)d_in[3];
  const float* feat_lr= (const float*)d_in[4];
  const float* ge_w1 = (const float*)d_in[5];
  const float* ge_b1 = (const float*)d_in[6];
  const float* ge_g1 = (const float*)d_in[7];
  const float* ge_bt1= (const float*)d_in[8];
  const float* ge_w2 = (const float*)d_in[9];
  const float* ge_b2 = (const float*)d_in[10];
  const float* ge_g2 = (const float*)d_in[11];
  const float* ge_bt2= (const float*)d_in[12];
  const float* sc_w = (const float*)d_in[13];
  const float* sc_b = (const float*)d_in[14];
  const float* sh_w = (const float*)d_in[15];
  const float* sh_b = (const float*)d_in[16];
  const float* q_w  = (const float*)d_in[17];
  const float* q_b  = (const float*)d_in[18];
  const float* k_w  = (const float*)d_in[19];
  const float* k_b  = (const float*)d_in[20];
  const float* bh_w1= (const float*)d_in[21];
  const float* bh_b1= (const float*)d_in[22];
  const float* bh_g = (const float*)d_in[23];
  const float* bh_bt= (const float*)d_in[24];
  const float* bh_w2= (const float*)d_in[25];
  const float* bh_b2= (const float*)d_in[26];
  const float* rp_w1= (const float*)d_in[27];
  const float* rp_b1= (const float*)d_in[28];
  const float* rp_g = (const float*)d_in[29];
  const float* rp_bt= (const float*)d_in[30];
  const float* rp_w2= (const float*)d_in[31];
  const float* rp_b2= (const float*)d_in[32];
  float* out = (float*)d_out;

  // ---- zero-init scratch header: mom(9 dbl) | 6 counters | 5x128 dbl sums ----
  double* mom  = (double*)d_ws;                       // 0..72
  int*    ctrs = (int*)((char*)d_ws + 96);            // 6 ints
  double* sums = (double*)((char*)d_ws + 128);        // 5 * 128 doubles
  float*  base = (float*)((char*)d_ws + 5376);
  float* AB1h = base;          // 128
  float* AB2h = base + 128;    // 128
  float* AB1l = base + 256;    // 128
  float* AB2l = base + 384;    // 128
  float* ABb  = base + 512;    // 64
  float* AB2d = base + 576;    // 128
  float* big  = base + 768;
  float* t1_hr = big;                      // 2*64*16384
  float* t2_hr = t1_hr + 2097152;
  float* Qb    = t2_hr + 2097152;
  float* Qp    = Qb    + 2097152;
  float* t1_lr = Qp    + 2097152;          // 2*64*4096
  float* t2_lr = t1_lr + 524288;
  float* glr   = t2_lr + 524288;
  float* KfT   = glr   + 524288;           // [B,M,64]
  float* tb    = KfT   + 524288;           // 2*32*16384
  float* xyzT  = tb    + 1048576;          // [B,M,4]
  float* valT  = xyzT  + 32768;            // [B,M,8]
  int*   idxb  = (int*)(valT + 65536);     // 2*16384*16
  // kNN scratch overlays the conv temporaries (consumed before conv pipeline):
  float* partv = t1_hr;                    // B*N*SPL*16 floats
  float* theta = Qb;                       // B*N floats

  (void)hipMemsetAsync(d_ws, 0, 5376, stream);

  tlr_k<<<32, 256, 0, stream>>>(xyz_lr, val_lr, xyzT, valT);

  // ---- kNN first (uses the big region as scratch) ----
  knnA_k<<<(BB * NN * SPL) / 256, 256, 0, stream>>>(xyz_hr, xyzT, partv);
  knnB_k<<<(BB * NN) / 256, 256, 0, stream>>>(partv, theta);
  knnC_k<<<(BB * NN) / 4, 256, 0, stream>>>(xyz_hr, xyzT, theta, idxb);
  mom_k<<<1024, 256, 0, stream>>>(xyz_hr, xyzT, idxb, mom, ctrs + 5, 1024,
                                  rp_w1, rp_b1, rp_g, rp_bt, AB2d);

  // ---- encoder pipeline (overwrites the kNN scratch) ----
  conv_k<GEOC, CQ, 8, false, false><<<1024, 256, 0, stream>>>(feat_hr, ge_w1, ge_b1, nullptr, t1_hr, NN);
  conv_k<GEOC, CQ, 8, false, false><<<256,  256, 0, stream>>>(feat_lr, ge_w1, ge_b1, nullptr, t1_lr, MM);
  stats2_k<CQ, 8><<<512, 256, 0, stream>>>(t1_hr, NN, ge_g1, ge_bt1, sums,       ctrs + 0, AB1h);
  stats2_k<CQ, 8><<<512, 256, 0, stream>>>(t1_lr, MM, ge_g1, ge_bt1, sums + 128, ctrs + 1, AB1l);
  conv_k<CQ, CQ, 8, false, false><<<1024, 256, 0, stream>>>(t1_hr, ge_w2, ge_b2, AB1h, t2_hr, NN);
  conv_k<CQ, CQ, 8, false, false><<<256,  256, 0, stream>>>(t1_lr, ge_w2, ge_b2, AB1l, t2_lr, MM);
  stats2_k<CQ, 8><<<512, 256, 0, stream>>>(t2_hr, NN, ge_g2, ge_bt2, sums + 256, ctrs + 2, AB2h);
  stats2_k<CQ, 8><<<512, 256, 0, stream>>>(t2_lr, MM, ge_g2, ge_bt2, sums + 384, ctrs + 3, AB2l);

  film_k<<<2048, 256, 0, stream>>>(t2_lr, AB2l, val_lr, sc_w, sc_b, sh_w, sh_b, glr);
  conv_k<CQ, CQ, 8, true, false><<<256, 256, 0, stream>>>(glr, k_w, k_b, nullptr, KfT, MM);

  conv_k<CQ, 32, 8, false, false><<<512, 256, 0, stream>>>(t2_hr, bh_w1, bh_b1, AB2h, tb, NN);
  stats2_k<32, 8><<<256, 256, 0, stream>>>(tb, NN, bh_g, bh_bt, sums + 512, ctrs + 4, ABb);
  bdy_k<<<128, 256, 0, stream>>>(tb, ABb, bh_w2, bh_b2, out + (size_t)BB * 6 * NN);

  conv_k<CQ, CQ, 8, false, false><<<1024, 256, 0, stream>>>(t2_hr, q_w, q_b, AB2h, Qb, NN);
  conv_k<CQ, CQ, 8, false, true><<<1024, 256, 0, stream>>>(Qb, rp_w2, nullptr, nullptr, Qp, NN);

  attn_k<<<2048, 256, 0, stream>>>(Qb, Qp, KfT, idxb, xyzT, valT, xyz_hr, AB2d,
                                   rp_w1, rp_b1, rp_b2, out);
}

// Round 8
// 666.364 us; speedup vs baseline: 4.1785x; 1.1017x over previous
//
#include <hip/hip_runtime.h>

#define BB 2
#define NN 16384
#define MM 4096
#define KK 16
#define CQ 64
#define GEOC 18
#define EPSV 1e-5
#define SPL 8   // M-split per query for kNN phase A

// exact numpy-order fp32 squared distance; contract(off) so bits are identical
// in every kernel that evaluates it (phase A/B values vs phase C recollect).
__device__ __forceinline__ float dist2f(float sa, float ax, float ay, float az, float4 p) {
#pragma clang fp contract(off)
  return (sa + p.w) - 2.0f * ((ax * p.x + ay * p.y) + az * p.z);
}

// compare-exchange and sorting networks (value-preserving -> theta bit-exact)
__device__ __forceinline__ void ce(float& a, float& b) {
  float lo = fminf(a, b), hi = fmaxf(a, b); a = lo; b = hi;
}
// Batcher odd-even mergesort, 8 elements ascending (19 CE)
__device__ __forceinline__ void sort8(float* v) {
  ce(v[0],v[1]); ce(v[2],v[3]); ce(v[4],v[5]); ce(v[6],v[7]);
  ce(v[0],v[2]); ce(v[1],v[3]); ce(v[4],v[6]); ce(v[5],v[7]);
  ce(v[1],v[2]); ce(v[5],v[6]);
  ce(v[0],v[4]); ce(v[1],v[5]); ce(v[2],v[6]); ce(v[3],v[7]);
  ce(v[2],v[4]); ce(v[3],v[5]);
  ce(v[1],v[2]); ce(v[3],v[4]); ce(v[5],v[6]);
}
// keep lowest-16 of sorted dv[16] U sorted t[8]; dv stays sorted ascending.
// min-step makes dv bitonic (Batcher), then 4-stage bitonic merge sorts it.
__device__ __forceinline__ void merge16_8(float* dv, const float* t) {
  dv[8]  = fminf(dv[8],  t[7]);  dv[9]  = fminf(dv[9],  t[6]);
  dv[10] = fminf(dv[10], t[5]);  dv[11] = fminf(dv[11], t[4]);
  dv[12] = fminf(dv[12], t[3]);  dv[13] = fminf(dv[13], t[2]);
  dv[14] = fminf(dv[14], t[1]);  dv[15] = fminf(dv[15], t[0]);
#pragma unroll
  for (int i = 0; i < 8; i++) ce(dv[i], dv[i + 8]);
  ce(dv[0],dv[4]); ce(dv[1],dv[5]); ce(dv[2],dv[6]); ce(dv[3],dv[7]);
  ce(dv[8],dv[12]); ce(dv[9],dv[13]); ce(dv[10],dv[14]); ce(dv[11],dv[15]);
  ce(dv[0],dv[2]); ce(dv[1],dv[3]); ce(dv[4],dv[6]); ce(dv[5],dv[7]);
  ce(dv[8],dv[10]); ce(dv[9],dv[11]); ce(dv[12],dv[14]); ce(dv[13],dv[15]);
  ce(dv[0],dv[1]); ce(dv[2],dv[3]); ce(dv[4],dv[5]); ce(dv[6],dv[7]);
  ce(dv[8],dv[9]); ce(dv[10],dv[11]); ce(dv[12],dv[13]); ce(dv[14],dv[15]);
}

// ---------------- transpose lr points/values (with |b|^2 precomputed) ----------------
__global__ __launch_bounds__(256) void tlr_k(const float* __restrict__ xyz,
    const float* __restrict__ val, float* __restrict__ xyzT, float* __restrict__ valT)
{
#pragma clang fp contract(off)
  int i = blockIdx.x * 256 + threadIdx.x;  // B*M
  int b = i / MM, m = i % MM;
  float x = xyz[(b * 3 + 0) * MM + m];
  float y = xyz[(b * 3 + 1) * MM + m];
  float z = xyz[(b * 3 + 2) * MM + m];
  float sb = (x * x + y * y) + z * z;      // exact numpy order: (x2+y2)+z2
  ((float4*)xyzT)[i] = make_float4(x, y, z, sb);
  float v0 = val[((size_t)b * 6 + 0) * MM + m];
  float v1 = val[((size_t)b * 6 + 1) * MM + m];
  float v2 = val[((size_t)b * 6 + 2) * MM + m];
  float v3 = val[((size_t)b * 6 + 3) * MM + m];
  float v4 = val[((size_t)b * 6 + 4) * MM + m];
  float v5 = val[((size_t)b * 6 + 5) * MM + m];
  ((float4*)valT)[2 * i]     = make_float4(v0, v1, v2, v3);
  ((float4*)valT)[2 * i + 1] = make_float4(v4, v5, 0.f, 0.f);
}

// ---------------- 1x1 conv body; OBLK outputs/thread; optional fused BN+ReLU input ----------------
template<int CIN, int COUT, int OBLK, bool TOUT>
__device__ __forceinline__ void conv_body(int tid, const float* __restrict__ x,
    const float* __restrict__ W, const float* __restrict__ bias,
    const float* __restrict__ AB, float* __restrict__ y, int L)
{
  int g = tid / (BB * L);                     // output-channel group
  int i = tid % (BB * L);
  int b = i / L, n = i % L;
  const float* xp = x + (size_t)b * CIN * L + n;
  float xr[CIN];
#pragma unroll
  for (int c = 0; c < CIN; c++) {
    float v = xp[(size_t)c * L];
    if (AB) v = fmaxf(fmaf(v, AB[c], AB[CIN + c]), 0.f);
    xr[c] = v;
  }
#pragma unroll
  for (int oo = 0; oo < OBLK; oo++) {
    int o = g * OBLK + oo;
    float acc = bias ? bias[o] : 0.f;
#pragma unroll
    for (int c = 0; c < CIN; c++)
      acc = fmaf(W[(size_t)o * CIN + c], xr[c], acc);
    if (TOUT) y[((size_t)b * L + n) * COUT + o] = acc;
    else      y[((size_t)b * COUT + o) * L + n] = acc;
  }
}

template<int CIN, int COUT, int OBLK, bool TOUT>
__global__ __launch_bounds__(256) void conv_k(const float* __restrict__ x,
    const float* __restrict__ W, const float* __restrict__ bias,
    const float* __restrict__ AB, float* __restrict__ y, int L)
{
  conv_body<CIN, COUT, OBLK, TOUT>(blockIdx.x * 256 + threadIdx.x, x, W, bias, AB, y, L);
}

// hr + lr in one dispatch (same weights, different AB/in/out)
template<int CIN, int COUT, int OBLK>
__global__ __launch_bounds__(256) void convhl_k(const float* __restrict__ xh,
    const float* __restrict__ xl, const float* __restrict__ W, const float* __restrict__ bias,
    const float* __restrict__ ABh, const float* __restrict__ ABl,
    float* __restrict__ yh, float* __restrict__ yl, int hb)
{
  if ((int)blockIdx.x < hb)
    conv_body<CIN, COUT, OBLK, false>(blockIdx.x * 256 + threadIdx.x, xh, W, bias, ABh, yh, NN);
  else
    conv_body<CIN, COUT, OBLK, false>((blockIdx.x - hb) * 256 + threadIdx.x, xl, W, bias, ABl, yl, MM);
}

// ------------- BN stats body: partial sums + last-block finalize -> (A,B) -------------
template<int C, int NCH>
__device__ __forceinline__ void stats_body(int bid, const float* __restrict__ t, int L,
    const float* __restrict__ g, const float* __restrict__ bt,
    double* __restrict__ sums, int* __restrict__ counter, float* __restrict__ AB)
{
  int c = bid % C;
  int ch = bid / C;
  const size_t tot = (size_t)BB * L;
  const size_t slab = tot / NCH;
  size_t beg = slab * ch, end = beg + slab;
  double s = 0.0, ss = 0.0;
  for (size_t idx = beg + threadIdx.x; idx < end; idx += 256) {
    int b = (int)(idx / L); int i = (int)(idx % L);
    double v = t[((size_t)b * C + c) * L + i];
    s += v; ss += v * v;
  }
  for (int o = 32; o >= 1; o >>= 1) { s += __shfl_down(s, o); ss += __shfl_down(ss, o); }
  __shared__ double sh[8];
  __shared__ int lastf;
  int w = threadIdx.x >> 6;
  if ((threadIdx.x & 63) == 0) { sh[2 * w] = s; sh[2 * w + 1] = ss; }
  __syncthreads();
  if (threadIdx.x == 0) {
    for (int j = 1; j < 4; j++) { s += sh[2 * j]; ss += sh[2 * j + 1]; }
    atomicAdd(&sums[c], s);
    atomicAdd(&sums[C + c], ss);
    __threadfence();
    int old = atomicAdd(counter, 1);
    lastf = (old == C * NCH - 1) ? 1 : 0;
  }
  __syncthreads();
  if (lastf && threadIdx.x < C) {
    __threadfence();
    int cc = threadIdx.x;
    double S  = atomicAdd(&sums[cc], 0.0);
    double SS = atomicAdd(&sums[C + cc], 0.0);
    double nn = (double)BB * L;
    double mean = S / nn, var = SS / nn - mean * mean;
    double A = (double)g[cc] / sqrt(var + EPSV);
    AB[cc] = (float)A;
    AB[C + cc] = (float)((double)bt[cc] - mean * A);
  }
}

template<int C, int NCH>
__global__ __launch_bounds__(256) void statsone_k(const float* __restrict__ t, int L,
    const float* __restrict__ g, const float* __restrict__ bt,
    double* __restrict__ sums, int* __restrict__ counter, float* __restrict__ AB)
{
  stats_body<C, NCH>(blockIdx.x, t, L, g, bt, sums, counter, AB);
}

template<int C, int NCH>
__global__ __launch_bounds__(256) void statshl_k(const float* __restrict__ t0, int L0,
    const float* __restrict__ t1, int L1, const float* __restrict__ g,
    const float* __restrict__ bt, double* __restrict__ sums, int* __restrict__ ctrs,
    float* __restrict__ AB0, float* __restrict__ AB1)
{
  if ((int)blockIdx.x < C * NCH)
    stats_body<C, NCH>(blockIdx.x, t0, L0, g, bt, sums, ctrs, AB0);
  else
    stats_body<C, NCH>(blockIdx.x - C * NCH, t1, L1, g, bt, sums + 2 * C, ctrs + 1, AB1);
}

// ---------------- fused FiLM + K-conv: KfT[b,m,:] = k_w * film(bn(t2l)) + k_b ----------------
__global__ __launch_bounds__(256) void fk_k(const float* __restrict__ t2l,
    const float* __restrict__ ABl, const float* __restrict__ val,
    const float* __restrict__ scw, const float* __restrict__ scb,
    const float* __restrict__ shw, const float* __restrict__ shb,
    const float* __restrict__ kw, const float* __restrict__ kb,
    float* __restrict__ KfT)
{
  int tid = blockIdx.x * 256 + threadIdx.x;  // B*M*8
  int g = tid & 7;
  int i = tid >> 3;                          // b*M + m
  int b = i / MM, m = i % MM;
  float v6[6];
#pragma unroll
  for (int j = 0; j < 6; j++) v6[j] = val[((size_t)b * 6 + j) * MM + m];
  float xr[CQ];
#pragma unroll
  for (int c = 0; c < CQ; c++) {
    float gv = fmaxf(fmaf(t2l[((size_t)b * CQ + c) * MM + m], ABl[c], ABl[CQ + c]), 0.f);
    float sc = scb[c], sh = shb[c];
#pragma unroll
    for (int j = 0; j < 6; j++) {
      sc = fmaf(scw[c * 6 + j], v6[j], sc);
      sh = fmaf(shw[c * 6 + j], v6[j], sh);
    }
    xr[c] = fmaf(gv, 1.f + sc, sh);
  }
#pragma unroll
  for (int oo = 0; oo < 8; oo++) {
    int o = g * 8 + oo;
    float acc = kb[o];
#pragma unroll
    for (int c = 0; c < CQ; c++) acc = fmaf(kw[o * CQ + c], xr[c], acc);
    KfT[(size_t)i * CQ + o] = acc;
  }
}

// ---------------- R = rp_w2^T * q_w, rb = rp_w2^T * q_b (effective Qp weights) ----------------
__global__ __launch_bounds__(256) void prepR_k(const float* __restrict__ qw,
    const float* __restrict__ qb, const float* __restrict__ w2,
    float* __restrict__ R, float* __restrict__ rb)
{
  int t = blockIdx.x * 256 + threadIdx.x;  // 4096
  int o = t >> 6, i = t & 63;
  float acc = 0.f;
#pragma unroll
  for (int p = 0; p < CQ; p++) acc = fmaf(w2[p * CQ + o], qw[p * CQ + i], acc);
  R[o * CQ + i] = acc;
  if (i == 0) {
    float a = 0.f;
#pragma unroll
    for (int p = 0; p < CQ; p++) a = fmaf(w2[p * CQ + o], qb[p], a);
    rb[o] = a;
  }
}

// ---------------- fused Q + Qp conv (one input pass, two weight sets) ----------------
__global__ __launch_bounds__(256) void convqq_k(const float* __restrict__ x,
    const float* __restrict__ Wq, const float* __restrict__ bq,
    const float* __restrict__ R, const float* __restrict__ rb,
    const float* __restrict__ AB, float* __restrict__ Q, float* __restrict__ Qp)
{
  int tid = blockIdx.x * 256 + threadIdx.x;  // 8 * B*NN
  int g = tid / (BB * NN);
  int i = tid % (BB * NN);
  int b = i / NN, n = i % NN;
  const float* xp = x + (size_t)b * CQ * NN + n;
  float xr[CQ];
#pragma unroll
  for (int c = 0; c < CQ; c++)
    xr[c] = fmaxf(fmaf(xp[(size_t)c * NN], AB[c], AB[CQ + c]), 0.f);
#pragma unroll
  for (int oo = 0; oo < 8; oo++) {
    int o = g * 8 + oo;
    float aq = bq[o], ap = rb[o];
#pragma unroll
    for (int c = 0; c < CQ; c++) {
      aq = fmaf(Wq[o * CQ + c], xr[c], aq);
      ap = fmaf(R[o * CQ + c], xr[c], ap);
    }
    Q[((size_t)b * CQ + o) * NN + n] = aq;
    Qp[((size_t)b * CQ + o) * NN + n] = ap;
  }
}

// ---------------- boundary head output ----------------
__global__ __launch_bounds__(256) void bdy_k(const float* __restrict__ tb,
    const float* __restrict__ AB, const float* __restrict__ w2,
    const float* __restrict__ b2, float* __restrict__ out2)
{
  int i = blockIdx.x * 256 + threadIdx.x;  // B*N
  int b = i / NN, n = i % NN;
  float acc = b2[0];
#pragma unroll
  for (int c = 0; c < 32; c++) {
    float v = tb[((size_t)b * 32 + c) * NN + n];
    v = fmaxf(fmaf(v, AB[c], AB[32 + c]), 0.f);
    acc = fmaf(w2[c], v, acc);
  }
  out2[i] = 1.f / (1.f + expf(-acc));
}

// ------- kNN phase A: per-(query, residue) top-16 values, batch-8 sort + bitonic merge -------
__global__ __launch_bounds__(256) void knnA_k(const float* __restrict__ xyz_hr,
    const float* __restrict__ xyzT, float* __restrict__ partv)
{
#pragma clang fp contract(off)
  int tid = blockIdx.x * 256 + threadIdx.x;  // B*N*SPL
  int s = tid & (SPL - 1);
  int qi = tid / SPL;                        // b*NN + n
  int b = qi / NN, n = qi % NN;
  float ax = xyz_hr[(b * 3 + 0) * NN + n];
  float ay = xyz_hr[(b * 3 + 1) * NN + n];
  float az = xyz_hr[(b * 3 + 2) * NN + n];
  float sa = (ax * ax + ay * ay) + az * az;
  const float4* __restrict__ Ps = ((const float4*)xyzT) + (size_t)b * MM + s;
  float dv[16];
#pragma unroll
  for (int j = 0; j < 16; j++) dv[j] = 3.4e38f;
  for (int j = 0; j < MM / SPL; j += 8) {
    float t[8];
#pragma unroll
    for (int u = 0; u < 8; u++) {
      float4 p = Ps[(size_t)(j + u) * SPL];
      t[u] = dist2f(sa, ax, ay, az, p);
    }
    sort8(t);
    merge16_8(dv, t);
  }
  float4* op = (float4*)(partv + (size_t)qi * (SPL * 16) + s * 16);
#pragma unroll
  for (int q = 0; q < 4; q++)
    op[q] = make_float4(dv[4 * q], dv[4 * q + 1], dv[4 * q + 2], dv[4 * q + 3]);
}

// ---------------- kNN phase B: merge 8 sorted-16 runs -> theta = 16th smallest ----------------
__global__ __launch_bounds__(256) void knnB_k(const float* __restrict__ partv,
    float* __restrict__ theta)
{
  int qi = blockIdx.x * 256 + threadIdx.x;  // B*N
  const float4* __restrict__ p = (const float4*)(partv + (size_t)qi * (SPL * 16));
  float dv[16];
#pragma unroll
  for (int j = 0; j < 16; j++) dv[j] = 3.4e38f;
  for (int j = 0; j < SPL * 2; j++) {        // each half-run of 8 is already sorted
    float4 v0 = p[2 * j], v1 = p[2 * j + 1];
    float t[8] = {v0.x, v0.y, v0.z, v0.w, v1.x, v1.y, v1.z, v1.w};
    merge16_8(dv, t);
  }
  theta[qi] = dv[15];
}

// ---------------- kNN phase C: one wave per query; collect idx with d<theta, ties d==theta by asc idx ----------------
__global__ __launch_bounds__(256) void knnC_k(const float* __restrict__ xyz_hr,
    const float* __restrict__ xyzT, const float* __restrict__ theta,
    int* __restrict__ idx_out)
{
#pragma clang fp contract(off)
  __shared__ int s_clt[4], s_ceq[4];
  __shared__ int s_lt[4][16];
  __shared__ int s_eq[4][64];
  int w = threadIdx.x >> 6, l = threadIdx.x & 63;
  int qi = blockIdx.x * 4 + w;               // B*N / 4 blocks
  int b = qi / NN, n = qi % NN;
  if (l == 0) { s_clt[w] = 0; s_ceq[w] = 0; }
  __syncthreads();
  float ax = xyz_hr[(b * 3 + 0) * NN + n];
  float ay = xyz_hr[(b * 3 + 1) * NN + n];
  float az = xyz_hr[(b * 3 + 2) * NN + n];
  float sa = (ax * ax + ay * ay) + az * az;
  float th = theta[qi];
  const float4* __restrict__ P = ((const float4*)xyzT) + (size_t)b * MM;
  for (int j = 0; j < MM / 64; j++) {
    int m = j * 64 + l;
    float d = dist2f(sa, ax, ay, az, P[m]);
    if (d < th) {
      int pos = atomicAdd(&s_clt[w], 1);
      if (pos < 16) s_lt[w][pos] = m;
    } else if (d == th) {
      int pos = atomicAdd(&s_ceq[w], 1);
      if (pos < 64) s_eq[w][pos] = m;
    }
  }
  __syncthreads();
  if (l == 0) {
    int clt = s_clt[w]; if (clt > 16) clt = 16;  // mathematically <= 15
    int ceq = s_ceq[w]; if (ceq > 64) ceq = 64;
    size_t base = (size_t)qi * KK;
    for (int j = 0; j < clt; j++) idx_out[base + j] = s_lt[w][j];
    int need = KK - clt;                          // >= 1, <= ceq
    for (int t = 0; t < need; t++) {
      int best = 0x7fffffff, bp = 0;
      for (int j = 0; j < ceq; j++) { int v = s_eq[w][j]; if (v < best) { best = v; bp = j; } }
      idx_out[base + clt + t] = best;
      s_eq[w][bp] = 0x7fffffff;
    }
  }
}

// -------- rel_pos moments (BN2d stats via linearity) + last-block AB2d finalize --------
__global__ __launch_bounds__(256) void mom_k(const float* __restrict__ xyz_hr,
    const float* __restrict__ xyzT, const int* __restrict__ idxb,
    double* __restrict__ mom, int* __restrict__ counter, int nblk,
    const float* __restrict__ w1, const float* __restrict__ b1,
    const float* __restrict__ g, const float* __restrict__ bt, float* __restrict__ AB)
{
  float a0=0,a1=0,a2=0,a3=0,a4=0,a5=0,a6=0,a7=0,a8=0;
  const size_t total = (size_t)BB * NN * KK;
  for (size_t i = (size_t)blockIdx.x * 256 + threadIdx.x; i < total; i += (size_t)nblk * 256) {
    int b = (int)(i / ((size_t)NN * KK));
    int n = (int)((i / KK) % NN);
    int id = idxb[i];
    float ax = xyz_hr[(b * 3 + 0) * NN + n];
    float ay = xyz_hr[(b * 3 + 1) * NN + n];
    float az = xyz_hr[(b * 3 + 2) * NN + n];
    float4 p = ((const float4*)xyzT)[(size_t)b * MM + id];
    float rx = ax - p.x, ry = ay - p.y, rz = az - p.z;
    a0 += rx; a1 += ry; a2 += rz;
    a3 += rx * rx; a4 += ry * ry; a5 += rz * rz;
    a6 += rx * ry; a7 += rx * rz; a8 += ry * rz;
  }
  double d[9] = {a0,a1,a2,a3,a4,a5,a6,a7,a8};
#pragma unroll
  for (int j = 0; j < 9; j++)
    for (int o = 32; o >= 1; o >>= 1) d[j] += __shfl_down(d[j], o);
  __shared__ double sh[4][9];
  __shared__ int lastf;
  int w = threadIdx.x >> 6, l = threadIdx.x & 63;
  if (l == 0) { for (int j = 0; j < 9; j++) sh[w][j] = d[j]; }
  __syncthreads();
  if (threadIdx.x == 0) {
    for (int wv = 1; wv < 4; wv++) for (int j = 0; j < 9; j++) d[j] += sh[wv][j];
    for (int j = 0; j < 9; j++) atomicAdd(&mom[j], d[j]);
    __threadfence();
    int old = atomicAdd(counter, 1);
    lastf = (old == nblk - 1) ? 1 : 0;
  }
  __syncthreads();
  if (lastf && threadIdx.x < CQ) {
    __threadfence();
    double mo[9];
    for (int j = 0; j < 9; j++) mo[j] = atomicAdd(&mom[j], 0.0);
    int c = threadIdx.x;
    double cnt = (double)BB * NN * KK;
    double mx = mo[0]/cnt, my = mo[1]/cnt, mz = mo[2]/cnt;
    double cxx = mo[3]/cnt - mx*mx, cyy = mo[4]/cnt - my*my, czz = mo[5]/cnt - mz*mz;
    double cxy = mo[6]/cnt - mx*my, cxz = mo[7]/cnt - mx*mz, cyz = mo[8]/cnt - my*mz;
    double wx = w1[c*3], wy = w1[c*3+1], wz = w1[c*3+2];
    double mean = wx*mx + wy*my + wz*mz + (double)b1[c];
    double var = wx*wx*cxx + wy*wy*cyy + wz*wz*czz + 2.0*(wx*wy*cxy + wx*wz*cxz + wy*wz*cyz);
    double A = (double)g[c] / sqrt(var + EPSV);
    AB[c] = (float)A;
    AB[CQ + c] = (float)((double)bt[c] - mean * A);
  }
}

// ---------------- fused pos-enc + attention + output ----------------
__global__ __launch_bounds__(256) void attn_k(
    const float* __restrict__ Q, const float* __restrict__ Qp,
    const float* __restrict__ KfT, const int* __restrict__ idxb,
    const float* __restrict__ xyzT, const float* __restrict__ valT,
    const float* __restrict__ xyz_hr, const float* __restrict__ AB,
    const float* __restrict__ w1, const float* __restrict__ b1,
    const float* __restrict__ b2, float* __restrict__ out)
{
  __shared__ float q_s[CQ * 16], qp_s[CQ * 16];
  const int ngrp = NN / 16;
  int b = blockIdx.x / ngrp;
  int n0 = (blockIdx.x % ngrp) * 16;
  for (int t = threadIdx.x; t < CQ * 16; t += 256) {
    int c = t >> 4, j = t & 15;
    q_s[t]  = Q [((size_t)b * CQ + c) * NN + n0 + j];
    qp_s[t] = Qp[((size_t)b * CQ + c) * NN + n0 + j];
  }
  __syncthreads();
  int q = threadIdx.x >> 4, k = threadIdx.x & 15;
  int n = n0 + q;
  int id = idxb[((size_t)b * NN + n) * KK + k];
  float ax = xyz_hr[(b * 3 + 0) * NN + n];
  float ay = xyz_hr[(b * 3 + 1) * NN + n];
  float az = xyz_hr[(b * 3 + 2) * NN + n];
  float4 pl = ((const float4*)xyzT)[(size_t)b * MM + id];
  float rx = ax - pl.x, ry = ay - pl.y, rz = az - pl.z;
  const float4* kg = (const float4*)(KfT + ((size_t)b * MM + id) * CQ);
  float s = 0.f;
#pragma unroll
  for (int c4 = 0; c4 < CQ / 4; c4++) {
    float4 g4 = kg[c4];
    float ga[4] = {g4.x, g4.y, g4.z, g4.w};
#pragma unroll
    for (int u = 0; u < 4; u++) {
      int c = 4 * c4 + u;
      float t0 = fmaf(w1[c * 3 + 0], rx, fmaf(w1[c * 3 + 1], ry, w1[c * 3 + 2] * rz)) + b1[c];
      float pe = fmaxf(fmaf(t0, AB[c], AB[CQ + c]), 0.f);
      s = fmaf(q_s[c * 16 + q], ga[u] + b2[c], s);
      s = fmaf(qp_s[c * 16 + q], pe, s);
    }
  }
  s *= 0.125f;  // /sqrt(64)
  float mx = s;
#pragma unroll
  for (int o = 8; o >= 1; o >>= 1) mx = fmaxf(mx, __shfl_xor(mx, o, 16));
  float p = expf(s - mx);
  float sum = p;
#pragma unroll
  for (int o = 8; o >= 1; o >>= 1) sum += __shfl_xor(sum, o, 16);
  float attn = p / sum;
  const float4* vt = (const float4*)(valT + ((size_t)b * MM + id) * 8);
  float4 va = vt[0], vb = vt[1];
  float oc[6] = {attn*va.x, attn*va.y, attn*va.z, attn*va.w, attn*vb.x, attn*vb.y};
#pragma unroll
  for (int c = 0; c < 6; c++) {
    float a = oc[c];
#pragma unroll
    for (int o = 8; o >= 1; o >>= 1) a += __shfl_xor(a, o, 16);
    oc[c] = a;
  }
  if (k == 0) {
#pragma unroll
    for (int c = 0; c < 6; c++) out[((size_t)b * 6 + c) * NN + n] = oc[c];
  }
}

extern "C" void kernel_launch(void* const* d_in, const int* in_sizes, int n_in,
                              void* d_out, int out_size, void* d_ws, size_t ws_size,
                              hipStream_t stream)
{
  const float* xyz_hr = (const float*)d_in[0];
  const float* xyz_lr = (const float*)d_in[1];
  const float* val_lr = (const float*)d_in[2];
  const float* feat_hr= (const float*)d_in[3];
  const float* feat_lr= (const float*)d_in[4];
  const float* ge_w1 = (const float*)d_in[5];
  const float* ge_b1 = (const float*)d_in[6];
  const float* ge_g1 = (const float*)d_in[7];
  const float* ge_bt1= (const float*)d_in[8];
  const float* ge_w2 = (const float*)d_in[9];
  const float* ge_b2 = (const float*)d_in[10];
  const float* ge_g2 = (const float*)d_in[11];
  const float* ge_bt2= (const float*)d_in[12];
  const float* sc_w = (const float*)d_in[13];
  const float* sc_b = (const float*)d_in[14];
  const float* sh_w = (const float*)d_in[15];
  const float* sh_b = (const float*)d_in[16];
  const float* q_w  = (const float*)d_in[17];
  const float* q_b  = (const float*)d_in[18];
  const float* k_w  = (const float*)d_in[19];
  const float* k_b  = (const float*)d_in[20];
  const float* bh_w1= (const float*)d_in[21];
  const float* bh_b1= (const float*)d_in[22];
  const float* bh_g = (const float*)d_in[23];
  const float* bh_bt= (const float*)d_in[24];
  const float* bh_w2= (const float*)d_in[25];
  const float* bh_b2= (const float*)d_in[26];
  const float* rp_w1= (const float*)d_in[27];
  const float* rp_b1= (const float*)d_in[28];
  const float* rp_g = (const float*)d_in[29];
  const float* rp_bt= (const float*)d_in[30];
  const float* rp_w2= (const float*)d_in[31];
  const float* rp_b2= (const float*)d_in[32];
  float* out = (float*)d_out;

  // ---- zero-init scratch header: mom(9 dbl) | 6 counters | 5x128 dbl sums ----
  double* mom  = (double*)d_ws;                       // 0..72
  int*    ctrs = (int*)((char*)d_ws + 96);            // 6 ints
  double* sums = (double*)((char*)d_ws + 128);        // 5 * 128 doubles
  float*  base = (float*)((char*)d_ws + 5376);
  float* AB1h = base;          // 128
  float* AB2h = base + 128;    // 128
  float* AB1l = base + 256;    // 128
  float* AB2l = base + 384;    // 128
  float* ABb  = base + 512;    // 64
  float* AB2d = base + 576;    // 128
  float* big  = base + 768;
  float* t1_hr = big;                      // 2*64*16384
  float* t2_hr = t1_hr + 2097152;
  float* Qb    = t2_hr + 2097152;
  float* Qp    = Qb    + 2097152;
  float* t1_lr = Qp    + 2097152;          // 2*64*4096
  float* t2_lr = t1_lr + 524288;
  float* Rbuf  = t2_lr + 524288;           // 4096 R + 64 rb (old glr slot)
  float* KfT   = Rbuf  + 524288;           // [B,M,64]
  float* tb    = KfT   + 524288;           // 2*32*16384
  float* xyzT  = tb    + 1048576;          // [B,M,4]
  float* valT  = xyzT  + 32768;            // [B,M,8]
  int*   idxb  = (int*)(valT + 65536);     // 2*16384*16
  // kNN scratch overlays the conv temporaries (consumed before conv pipeline):
  float* partv = t1_hr;                    // B*N*SPL*16 floats
  float* theta = Qb;                       // B*N floats
  float* Rw    = Rbuf;                     // effective Qp weights
  float* rbv   = Rbuf + 4096;

  (void)hipMemsetAsync(d_ws, 0, 5376, stream);

  tlr_k<<<32, 256, 0, stream>>>(xyz_lr, val_lr, xyzT, valT);
  prepR_k<<<16, 256, 0, stream>>>(q_w, q_b, rp_w2, Rw, rbv);

  // ---- kNN first (uses the big region as scratch) ----
  knnA_k<<<(BB * NN * SPL) / 256, 256, 0, stream>>>(xyz_hr, xyzT, partv);
  knnB_k<<<(BB * NN) / 256, 256, 0, stream>>>(partv, theta);
  knnC_k<<<(BB * NN) / 4, 256, 0, stream>>>(xyz_hr, xyzT, theta, idxb);
  mom_k<<<1024, 256, 0, stream>>>(xyz_hr, xyzT, idxb, mom, ctrs + 5, 1024,
                                  rp_w1, rp_b1, rp_g, rp_bt, AB2d);

  // ---- encoder pipeline (overwrites the kNN scratch) ----
  convhl_k<GEOC, CQ, 8><<<1280, 256, 0, stream>>>(feat_hr, feat_lr, ge_w1, ge_b1,
                                                  nullptr, nullptr, t1_hr, t1_lr, 1024);
  statshl_k<CQ, 8><<<1024, 256, 0, stream>>>(t1_hr, NN, t1_lr, MM, ge_g1, ge_bt1,
                                             sums, ctrs + 0, AB1h, AB1l);
  convhl_k<CQ, CQ, 8><<<1280, 256, 0, stream>>>(t1_hr, t1_lr, ge_w2, ge_b2,
                                                AB1h, AB1l, t2_hr, t2_lr, 1024);
  statshl_k<CQ, 8><<<1024, 256, 0, stream>>>(t2_hr, NN, t2_lr, MM, ge_g2, ge_bt2,
                                             sums + 256, ctrs + 2, AB2h, AB2l);

  fk_k<<<256, 256, 0, stream>>>(t2_lr, AB2l, val_lr, sc_w, sc_b, sh_w, sh_b,
                                k_w, k_b, KfT);

  conv_k<CQ, 32, 8, false><<<512, 256, 0, stream>>>(t2_hr, bh_w1, bh_b1, AB2h, tb, NN);
  statsone_k<32, 8><<<256, 256, 0, stream>>>(tb, NN, bh_g, bh_bt, sums + 512, ctrs + 4, ABb);
  bdy_k<<<128, 256, 0, stream>>>(tb, ABb, bh_w2, bh_b2, out + (size_t)BB * 6 * NN);

  convqq_k<<<1024, 256, 0, stream>>>(t2_hr, q_w, q_b, Rw, rbv, AB2h, Qb, Qp);

  attn_k<<<2048, 256, 0, stream>>>(Qb, Qp, KfT, idxb, xyzT, valT, xyz_hr, AB2d,
                                   rp_w1, rp_b1, rp_b2, out);
}

// Round 9
// 592.216 us; speedup vs baseline: 4.7017x; 1.1252x over previous
//
#include <hip/hip_runtime.h>

#define BB 2
#define NN 16384
#define MM 4096
#define KK 16
#define CQ 64
#define GEOC 18
#define EPSV 1e-5
#define SPL 8   // M-split per query for kNN phase A

// exact numpy-order fp32 squared distance; contract(off) so bits are identical
// in every kernel that evaluates it (phase A/B values vs phase C recollect).
__device__ __forceinline__ float dist2f(float sa, float ax, float ay, float az, float4 p) {
#pragma clang fp contract(off)
  return (sa + p.w) - 2.0f * ((ax * p.x + ay * p.y) + az * p.z);
}

// compare-exchange and sorting networks (value-preserving -> theta bit-exact)
__device__ __forceinline__ void ce(float& a, float& b) {
  float lo = fminf(a, b), hi = fmaxf(a, b); a = lo; b = hi;
}
// Batcher odd-even mergesort, 8 elements ascending (19 CE)
__device__ __forceinline__ void sort8(float* v) {
  ce(v[0],v[1]); ce(v[2],v[3]); ce(v[4],v[5]); ce(v[6],v[7]);
  ce(v[0],v[2]); ce(v[1],v[3]); ce(v[4],v[6]); ce(v[5],v[7]);
  ce(v[1],v[2]); ce(v[5],v[6]);
  ce(v[0],v[4]); ce(v[1],v[5]); ce(v[2],v[6]); ce(v[3],v[7]);
  ce(v[2],v[4]); ce(v[3],v[5]);
  ce(v[1],v[2]); ce(v[3],v[4]); ce(v[5],v[6]);
}
// keep lowest-16 of sorted dv[16] U sorted t[8]; dv stays sorted ascending.
// min-step makes dv bitonic (Batcher), then 4-stage bitonic merge sorts it.
__device__ __forceinline__ void merge16_8(float* dv, const float* t) {
  dv[8]  = fminf(dv[8],  t[7]);  dv[9]  = fminf(dv[9],  t[6]);
  dv[10] = fminf(dv[10], t[5]);  dv[11] = fminf(dv[11], t[4]);
  dv[12] = fminf(dv[12], t[3]);  dv[13] = fminf(dv[13], t[2]);
  dv[14] = fminf(dv[14], t[1]);  dv[15] = fminf(dv[15], t[0]);
#pragma unroll
  for (int i = 0; i < 8; i++) ce(dv[i], dv[i + 8]);
  ce(dv[0],dv[4]); ce(dv[1],dv[5]); ce(dv[2],dv[6]); ce(dv[3],dv[7]);
  ce(dv[8],dv[12]); ce(dv[9],dv[13]); ce(dv[10],dv[14]); ce(dv[11],dv[15]);
  ce(dv[0],dv[2]); ce(dv[1],dv[3]); ce(dv[4],dv[6]); ce(dv[5],dv[7]);
  ce(dv[8],dv[10]); ce(dv[9],dv[11]); ce(dv[12],dv[14]); ce(dv[13],dv[15]);
  ce(dv[0],dv[1]); ce(dv[2],dv[3]); ce(dv[4],dv[5]); ce(dv[6],dv[7]);
  ce(dv[8],dv[9]); ce(dv[10],dv[11]); ce(dv[12],dv[13]); ce(dv[14],dv[15]);
}

// ---------------- transpose lr points/values (with |b|^2 precomputed) ----------------
__global__ __launch_bounds__(256) void tlr_k(const float* __restrict__ xyz,
    const float* __restrict__ val, float* __restrict__ xyzT, float* __restrict__ valT)
{
#pragma clang fp contract(off)
  int i = blockIdx.x * 256 + threadIdx.x;  // B*M
  int b = i / MM, m = i % MM;
  float x = xyz[(b * 3 + 0) * MM + m];
  float y = xyz[(b * 3 + 1) * MM + m];
  float z = xyz[(b * 3 + 2) * MM + m];
  float sb = (x * x + y * y) + z * z;      // exact numpy order: (x2+y2)+z2
  ((float4*)xyzT)[i] = make_float4(x, y, z, sb);
  float v0 = val[((size_t)b * 6 + 0) * MM + m];
  float v1 = val[((size_t)b * 6 + 1) * MM + m];
  float v2 = val[((size_t)b * 6 + 2) * MM + m];
  float v3 = val[((size_t)b * 6 + 3) * MM + m];
  float v4 = val[((size_t)b * 6 + 4) * MM + m];
  float v5 = val[((size_t)b * 6 + 5) * MM + m];
  ((float4*)valT)[2 * i]     = make_float4(v0, v1, v2, v3);
  ((float4*)valT)[2 * i + 1] = make_float4(v4, v5, 0.f, 0.f);
}

// ---------------- 1x1 conv body; OBLK outputs/thread; optional fused BN+ReLU input ----------------
template<int CIN, int COUT, int OBLK, bool TOUT>
__device__ __forceinline__ void conv_body(int tid, const float* __restrict__ x,
    const float* __restrict__ W, const float* __restrict__ bias,
    const float* __restrict__ AB, float* __restrict__ y, int L)
{
  int g = tid / (BB * L);                     // output-channel group
  int i = tid % (BB * L);
  int b = i / L, n = i % L;
  const float* xp = x + (size_t)b * CIN * L + n;
  float xr[CIN];
#pragma unroll
  for (int c = 0; c < CIN; c++) {
    float v = xp[(size_t)c * L];
    if (AB) v = fmaxf(fmaf(v, AB[c], AB[CIN + c]), 0.f);
    xr[c] = v;
  }
#pragma unroll
  for (int oo = 0; oo < OBLK; oo++) {
    int o = g * OBLK + oo;
    float acc = bias ? bias[o] : 0.f;
#pragma unroll
    for (int c = 0; c < CIN; c++)
      acc = fmaf(W[(size_t)o * CIN + c], xr[c], acc);
    if (TOUT) y[((size_t)b * L + n) * COUT + o] = acc;
    else      y[((size_t)b * COUT + o) * L + n] = acc;
  }
}

template<int CIN, int COUT, int OBLK, bool TOUT>
__global__ __launch_bounds__(256) void conv_k(const float* __restrict__ x,
    const float* __restrict__ W, const float* __restrict__ bias,
    const float* __restrict__ AB, float* __restrict__ y, int L)
{
  conv_body<CIN, COUT, OBLK, TOUT>(blockIdx.x * 256 + threadIdx.x, x, W, bias, AB, y, L);
}

// hr + lr in one dispatch (same weights, different AB/in/out)
template<int CIN, int COUT, int OBLK>
__global__ __launch_bounds__(256) void convhl_k(const float* __restrict__ xh,
    const float* __restrict__ xl, const float* __restrict__ W, const float* __restrict__ bias,
    const float* __restrict__ ABh, const float* __restrict__ ABl,
    float* __restrict__ yh, float* __restrict__ yl, int hb)
{
  if ((int)blockIdx.x < hb)
    conv_body<CIN, COUT, OBLK, false>(blockIdx.x * 256 + threadIdx.x, xh, W, bias, ABh, yh, NN);
  else
    conv_body<CIN, COUT, OBLK, false>((blockIdx.x - hb) * 256 + threadIdx.x, xl, W, bias, ABl, yl, MM);
}

// ------------- BN stats body: partial sums + last-block finalize -> (A,B) -------------
template<int C, int NCH>
__device__ __forceinline__ void stats_body(int bid, const float* __restrict__ t, int L,
    const float* __restrict__ g, const float* __restrict__ bt,
    double* __restrict__ sums, int* __restrict__ counter, float* __restrict__ AB)
{
  int c = bid % C;
  int ch = bid / C;
  const size_t tot = (size_t)BB * L;
  const size_t slab = tot / NCH;
  size_t beg = slab * ch, end = beg + slab;
  double s = 0.0, ss = 0.0;
  for (size_t idx = beg + threadIdx.x; idx < end; idx += 256) {
    int b = (int)(idx / L); int i = (int)(idx % L);
    double v = t[((size_t)b * C + c) * L + i];
    s += v; ss += v * v;
  }
  for (int o = 32; o >= 1; o >>= 1) { s += __shfl_down(s, o); ss += __shfl_down(ss, o); }
  __shared__ double sh[8];
  __shared__ int lastf;
  int w = threadIdx.x >> 6;
  if ((threadIdx.x & 63) == 0) { sh[2 * w] = s; sh[2 * w + 1] = ss; }
  __syncthreads();
  if (threadIdx.x == 0) {
    for (int j = 1; j < 4; j++) { s += sh[2 * j]; ss += sh[2 * j + 1]; }
    atomicAdd(&sums[c], s);
    atomicAdd(&sums[C + c], ss);
    __threadfence();
    int old = atomicAdd(counter, 1);
    lastf = (old == C * NCH - 1) ? 1 : 0;
  }
  __syncthreads();
  if (lastf && threadIdx.x < C) {
    __threadfence();
    int cc = threadIdx.x;
    double S  = atomicAdd(&sums[cc], 0.0);
    double SS = atomicAdd(&sums[C + cc], 0.0);
    double nn = (double)BB * L;
    double mean = S / nn, var = SS / nn - mean * mean;
    double A = (double)g[cc] / sqrt(var + EPSV);
    AB[cc] = (float)A;
    AB[C + cc] = (float)((double)bt[cc] - mean * A);
  }
}

template<int C, int NCH>
__global__ __launch_bounds__(256) void statsone_k(const float* __restrict__ t, int L,
    const float* __restrict__ g, const float* __restrict__ bt,
    double* __restrict__ sums, int* __restrict__ counter, float* __restrict__ AB)
{
  stats_body<C, NCH>(blockIdx.x, t, L, g, bt, sums, counter, AB);
}

template<int C, int NCH>
__global__ __launch_bounds__(256) void statshl_k(const float* __restrict__ t0, int L0,
    const float* __restrict__ t1, int L1, const float* __restrict__ g,
    const float* __restrict__ bt, double* __restrict__ sums, int* __restrict__ ctrs,
    float* __restrict__ AB0, float* __restrict__ AB1)
{
  if ((int)blockIdx.x < C * NCH)
    stats_body<C, NCH>(blockIdx.x, t0, L0, g, bt, sums, ctrs, AB0);
  else
    stats_body<C, NCH>(blockIdx.x - C * NCH, t1, L1, g, bt, sums + 2 * C, ctrs + 1, AB1);
}

// ---------------- fused FiLM + K-conv: KfT[b,m,:] = k_w * film(bn(t2l)) + k_b ----------------
__global__ __launch_bounds__(256) void fk_k(const float* __restrict__ t2l,
    const float* __restrict__ ABl, const float* __restrict__ val,
    const float* __restrict__ scw, const float* __restrict__ scb,
    const float* __restrict__ shw, const float* __restrict__ shb,
    const float* __restrict__ kw, const float* __restrict__ kb,
    float* __restrict__ KfT)
{
  int tid = blockIdx.x * 256 + threadIdx.x;  // B*M*8
  int g = tid & 7;
  int i = tid >> 3;                          // b*M + m
  int b = i / MM, m = i % MM;
  float v6[6];
#pragma unroll
  for (int j = 0; j < 6; j++) v6[j] = val[((size_t)b * 6 + j) * MM + m];
  float xr[CQ];
#pragma unroll
  for (int c = 0; c < CQ; c++) {
    float gv = fmaxf(fmaf(t2l[((size_t)b * CQ + c) * MM + m], ABl[c], ABl[CQ + c]), 0.f);
    float sc = scb[c], sh = shb[c];
#pragma unroll
    for (int j = 0; j < 6; j++) {
      sc = fmaf(scw[c * 6 + j], v6[j], sc);
      sh = fmaf(shw[c * 6 + j], v6[j], sh);
    }
    xr[c] = fmaf(gv, 1.f + sc, sh);
  }
#pragma unroll
  for (int oo = 0; oo < 8; oo++) {
    int o = g * 8 + oo;
    float acc = kb[o];
#pragma unroll
    for (int c = 0; c < CQ; c++) acc = fmaf(kw[o * CQ + c], xr[c], acc);
    KfT[(size_t)i * CQ + o] = acc;
  }
}

// ---------------- R = rp_w2^T * q_w, rb = rp_w2^T * q_b (effective Qp weights) ----------------
__global__ __launch_bounds__(256) void prepR_k(const float* __restrict__ qw,
    const float* __restrict__ qb, const float* __restrict__ w2,
    float* __restrict__ R, float* __restrict__ rb)
{
  int t = blockIdx.x * 256 + threadIdx.x;  // 4096
  int o = t >> 6, i = t & 63;
  float acc = 0.f;
#pragma unroll
  for (int p = 0; p < CQ; p++) acc = fmaf(w2[p * CQ + o], qw[p * CQ + i], acc);
  R[o * CQ + i] = acc;
  if (i == 0) {
    float a = 0.f;
#pragma unroll
    for (int p = 0; p < CQ; p++) a = fmaf(w2[p * CQ + o], qb[p], a);
    rb[o] = a;
  }
}

// ---------------- fused Q + Qp conv (one input pass, two weight sets) ----------------
__global__ __launch_bounds__(256) void convqq_k(const float* __restrict__ x,
    const float* __restrict__ Wq, const float* __restrict__ bq,
    const float* __restrict__ R, const float* __restrict__ rb,
    const float* __restrict__ AB, float* __restrict__ Q, float* __restrict__ Qp)
{
  int tid = blockIdx.x * 256 + threadIdx.x;  // 8 * B*NN
  int g = tid / (BB * NN);
  int i = tid % (BB * NN);
  int b = i / NN, n = i % NN;
  const float* xp = x + (size_t)b * CQ * NN + n;
  float xr[CQ];
#pragma unroll
  for (int c = 0; c < CQ; c++)
    xr[c] = fmaxf(fmaf(xp[(size_t)c * NN], AB[c], AB[CQ + c]), 0.f);
#pragma unroll
  for (int oo = 0; oo < 8; oo++) {
    int o = g * 8 + oo;
    float aq = bq[o], ap = rb[o];
#pragma unroll
    for (int c = 0; c < CQ; c++) {
      aq = fmaf(Wq[o * CQ + c], xr[c], aq);
      ap = fmaf(R[o * CQ + c], xr[c], ap);
    }
    Q[((size_t)b * CQ + o) * NN + n] = aq;
    Qp[((size_t)b * CQ + o) * NN + n] = ap;
  }
}

// ---------------- boundary head output ----------------
__global__ __launch_bounds__(256) void bdy_k(const float* __restrict__ tb,
    const float* __restrict__ AB, const float* __restrict__ w2,
    const float* __restrict__ b2, float* __restrict__ out2)
{
  int i = blockIdx.x * 256 + threadIdx.x;  // B*N
  int b = i / NN, n = i % NN;
  float acc = b2[0];
#pragma unroll
  for (int c = 0; c < 32; c++) {
    float v = tb[((size_t)b * 32 + c) * NN + n];
    v = fmaxf(fmaf(v, AB[c], AB[32 + c]), 0.f);
    acc = fmaf(w2[c], v, acc);
  }
  out2[i] = 1.f / (1.f + expf(-acc));
}

// ------- kNN phase A: per-(query, residue) top-16 values, batch-8 sort + bitonic merge -------
__global__ __launch_bounds__(256) void knnA_k(const float* __restrict__ xyz_hr,
    const float* __restrict__ xyzT, float* __restrict__ partv)
{
#pragma clang fp contract(off)
  int tid = blockIdx.x * 256 + threadIdx.x;  // B*N*SPL
  int s = tid & (SPL - 1);
  int qi = tid / SPL;                        // b*NN + n
  int b = qi / NN, n = qi % NN;
  float ax = xyz_hr[(b * 3 + 0) * NN + n];
  float ay = xyz_hr[(b * 3 + 1) * NN + n];
  float az = xyz_hr[(b * 3 + 2) * NN + n];
  float sa = (ax * ax + ay * ay) + az * az;
  const float4* __restrict__ Ps = ((const float4*)xyzT) + (size_t)b * MM + s;
  float dv[16];
#pragma unroll
  for (int j = 0; j < 16; j++) dv[j] = 3.4e38f;
  for (int j = 0; j < MM / SPL; j += 8) {
    float t[8];
#pragma unroll
    for (int u = 0; u < 8; u++) {
      float4 p = Ps[(size_t)(j + u) * SPL];
      t[u] = dist2f(sa, ax, ay, az, p);
    }
    sort8(t);
    merge16_8(dv, t);
  }
  float4* op = (float4*)(partv + (size_t)qi * (SPL * 16) + s * 16);
#pragma unroll
  for (int q = 0; q < 4; q++)
    op[q] = make_float4(dv[4 * q], dv[4 * q + 1], dv[4 * q + 2], dv[4 * q + 3]);
}

// ---------------- kNN phase B: merge 8 sorted-16 runs -> theta = 16th smallest ----------------
__global__ __launch_bounds__(256) void knnB_k(const float* __restrict__ partv,
    float* __restrict__ theta)
{
  int qi = blockIdx.x * 256 + threadIdx.x;  // B*N
  const float4* __restrict__ p = (const float4*)(partv + (size_t)qi * (SPL * 16));
  float dv[16];
#pragma unroll
  for (int j = 0; j < 16; j++) dv[j] = 3.4e38f;
  for (int j = 0; j < SPL * 2; j++) {        // each half-run of 8 is already sorted
    float4 v0 = p[2 * j], v1 = p[2 * j + 1];
    float t[8] = {v0.x, v0.y, v0.z, v0.w, v1.x, v1.y, v1.z, v1.w};
    merge16_8(dv, t);
  }
  theta[qi] = dv[15];
}

// ---------------- kNN phase C: one wave per query; collect idx with d<theta, ties d==theta by asc idx ----------------
__global__ __launch_bounds__(256) void knnC_k(const float* __restrict__ xyz_hr,
    const float* __restrict__ xyzT, const float* __restrict__ theta,
    int* __restrict__ idx_out)
{
#pragma clang fp contract(off)
  __shared__ int s_clt[4], s_ceq[4];
  __shared__ int s_lt[4][16];
  __shared__ int s_eq[4][64];
  int w = threadIdx.x >> 6, l = threadIdx.x & 63;
  int qi = blockIdx.x * 4 + w;               // B*N / 4 blocks
  int b = qi / NN, n = qi % NN;
  if (l == 0) { s_clt[w] = 0; s_ceq[w] = 0; }
  __syncthreads();
  float ax = xyz_hr[(b * 3 + 0) * NN + n];
  float ay = xyz_hr[(b * 3 + 1) * NN + n];
  float az = xyz_hr[(b * 3 + 2) * NN + n];
  float sa = (ax * ax + ay * ay) + az * az;
  float th = theta[qi];
  const float4* __restrict__ P = ((const float4*)xyzT) + (size_t)b * MM;
  for (int j = 0; j < MM / 64; j++) {
    int m = j * 64 + l;
    float d = dist2f(sa, ax, ay, az, P[m]);
    if (d < th) {
      int pos = atomicAdd(&s_clt[w], 1);
      if (pos < 16) s_lt[w][pos] = m;
    } else if (d == th) {
      int pos = atomicAdd(&s_ceq[w], 1);
      if (pos < 64) s_eq[w][pos] = m;
    }
  }
  __syncthreads();
  if (l == 0) {
    int clt = s_clt[w]; if (clt > 16) clt = 16;  // mathematically <= 15
    int ceq = s_ceq[w]; if (ceq > 64) ceq = 64;
    size_t base = (size_t)qi * KK;
    for (int j = 0; j < clt; j++) idx_out[base + j] = s_lt[w][j];
    int need = KK - clt;                          // >= 1, <= ceq
    for (int t = 0; t < need; t++) {
      int best = 0x7fffffff, bp = 0;
      for (int j = 0; j < ceq; j++) { int v = s_eq[w][j]; if (v < best) { best = v; bp = j; } }
      idx_out[base + clt + t] = best;
      s_eq[w][bp] = 0x7fffffff;
    }
  }
}

// -------- rel_pos moments phase 1: per-block partials to DISTINCT slots (no atomics) --------
__global__ __launch_bounds__(256) void mom1_k(const float* __restrict__ xyz_hr,
    const float* __restrict__ xyzT, const int* __restrict__ idxb,
    double* __restrict__ part, int nblk)
{
  float a0=0,a1=0,a2=0,a3=0,a4=0,a5=0,a6=0,a7=0,a8=0;
  const size_t total = (size_t)BB * NN * KK;
  for (size_t i = (size_t)blockIdx.x * 256 + threadIdx.x; i < total; i += (size_t)nblk * 256) {
    int b = (int)(i / ((size_t)NN * KK));
    int n = (int)((i / KK) % NN);
    int id = idxb[i];
    float ax = xyz_hr[(b * 3 + 0) * NN + n];
    float ay = xyz_hr[(b * 3 + 1) * NN + n];
    float az = xyz_hr[(b * 3 + 2) * NN + n];
    float4 p = ((const float4*)xyzT)[(size_t)b * MM + id];
    float rx = ax - p.x, ry = ay - p.y, rz = az - p.z;
    a0 += rx; a1 += ry; a2 += rz;
    a3 += rx * rx; a4 += ry * ry; a5 += rz * rz;
    a6 += rx * ry; a7 += rx * rz; a8 += ry * rz;
  }
  double d[9] = {a0,a1,a2,a3,a4,a5,a6,a7,a8};
#pragma unroll
  for (int j = 0; j < 9; j++)
    for (int o = 32; o >= 1; o >>= 1) d[j] += __shfl_down(d[j], o);
  __shared__ double sh[4][9];
  int w = threadIdx.x >> 6, l = threadIdx.x & 63;
  if (l == 0) { for (int j = 0; j < 9; j++) sh[w][j] = d[j]; }
  __syncthreads();
  if (threadIdx.x == 0) {
    for (int wv = 1; wv < 4; wv++) for (int j = 0; j < 9; j++) d[j] += sh[wv][j];
    double* op = part + (size_t)blockIdx.x * 9;
    for (int j = 0; j < 9; j++) op[j] = d[j];
  }
}

// -------- rel_pos moments phase 2: one block reduces partials, finalizes AB2d --------
__global__ __launch_bounds__(256) void mom2_k(const double* __restrict__ part, int nblk,
    const float* __restrict__ w1, const float* __restrict__ b1,
    const float* __restrict__ g, const float* __restrict__ bt, float* __restrict__ AB)
{
  double acc[9];
#pragma unroll
  for (int j = 0; j < 9; j++) acc[j] = 0.0;
  for (int blk = threadIdx.x; blk < nblk; blk += 256) {
    const double* p = part + (size_t)blk * 9;
#pragma unroll
    for (int j = 0; j < 9; j++) acc[j] += p[j];
  }
#pragma unroll
  for (int j = 0; j < 9; j++)
    for (int o = 32; o >= 1; o >>= 1) acc[j] += __shfl_down(acc[j], o);
  __shared__ double sh[4][9];
  __shared__ double mo[9];
  int w = threadIdx.x >> 6, l = threadIdx.x & 63;
  if (l == 0) { for (int j = 0; j < 9; j++) sh[w][j] = acc[j]; }
  __syncthreads();
  if (threadIdx.x == 0) {
    for (int wv = 1; wv < 4; wv++) for (int j = 0; j < 9; j++) sh[0][j] += sh[wv][j];
    for (int j = 0; j < 9; j++) mo[j] = sh[0][j];
  }
  __syncthreads();
  if (threadIdx.x < CQ) {
    int c = threadIdx.x;
    double cnt = (double)BB * NN * KK;
    double mx = mo[0]/cnt, my = mo[1]/cnt, mz = mo[2]/cnt;
    double cxx = mo[3]/cnt - mx*mx, cyy = mo[4]/cnt - my*my, czz = mo[5]/cnt - mz*mz;
    double cxy = mo[6]/cnt - mx*my, cxz = mo[7]/cnt - mx*mz, cyz = mo[8]/cnt - my*mz;
    double wx = w1[c*3], wy = w1[c*3+1], wz = w1[c*3+2];
    double mean = wx*mx + wy*my + wz*mz + (double)b1[c];
    double var = wx*wx*cxx + wy*wy*cyy + wz*wz*czz + 2.0*(wx*wy*cxy + wx*wz*cxz + wy*wz*cyz);
    double A = (double)g[c] / sqrt(var + EPSV);
    AB[c] = (float)A;
    AB[CQ + c] = (float)((double)bt[c] - mean * A);
  }
}

// ---------------- fused pos-enc + attention + output ----------------
__global__ __launch_bounds__(256) void attn_k(
    const float* __restrict__ Q, const float* __restrict__ Qp,
    const float* __restrict__ KfT, const int* __restrict__ idxb,
    const float* __restrict__ xyzT, const float* __restrict__ valT,
    const float* __restrict__ xyz_hr, const float* __restrict__ AB,
    const float* __restrict__ w1, const float* __restrict__ b1,
    const float* __restrict__ b2, float* __restrict__ out)
{
  __shared__ float q_s[CQ * 16], qp_s[CQ * 16];
  const int ngrp = NN / 16;
  int b = blockIdx.x / ngrp;
  int n0 = (blockIdx.x % ngrp) * 16;
  for (int t = threadIdx.x; t < CQ * 16; t += 256) {
    int c = t >> 4, j = t & 15;
    q_s[t]  = Q [((size_t)b * CQ + c) * NN + n0 + j];
    qp_s[t] = Qp[((size_t)b * CQ + c) * NN + n0 + j];
  }
  __syncthreads();
  int q = threadIdx.x >> 4, k = threadIdx.x & 15;
  int n = n0 + q;
  int id = idxb[((size_t)b * NN + n) * KK + k];
  float ax = xyz_hr[(b * 3 + 0) * NN + n];
  float ay = xyz_hr[(b * 3 + 1) * NN + n];
  float az = xyz_hr[(b * 3 + 2) * NN + n];
  float4 pl = ((const float4*)xyzT)[(size_t)b * MM + id];
  float rx = ax - pl.x, ry = ay - pl.y, rz = az - pl.z;
  const float4* kg = (const float4*)(KfT + ((size_t)b * MM + id) * CQ);
  float s = 0.f;
#pragma unroll
  for (int c4 = 0; c4 < CQ / 4; c4++) {
    float4 g4 = kg[c4];
    float ga[4] = {g4.x, g4.y, g4.z, g4.w};
#pragma unroll
    for (int u = 0; u < 4; u++) {
      int c = 4 * c4 + u;
      float t0 = fmaf(w1[c * 3 + 0], rx, fmaf(w1[c * 3 + 1], ry, w1[c * 3 + 2] * rz)) + b1[c];
      float pe = fmaxf(fmaf(t0, AB[c], AB[CQ + c]), 0.f);
      s = fmaf(q_s[c * 16 + q], ga[u] + b2[c], s);
      s = fmaf(qp_s[c * 16 + q], pe, s);
    }
  }
  s *= 0.125f;  // /sqrt(64)
  float mx = s;
#pragma unroll
  for (int o = 8; o >= 1; o >>= 1) mx = fmaxf(mx, __shfl_xor(mx, o, 16));
  float p = expf(s - mx);
  float sum = p;
#pragma unroll
  for (int o = 8; o >= 1; o >>= 1) sum += __shfl_xor(sum, o, 16);
  float attn = p / sum;
  const float4* vt = (const float4*)(valT + ((size_t)b * MM + id) * 8);
  float4 va = vt[0], vb = vt[1];
  float oc[6] = {attn*va.x, attn*va.y, attn*va.z, attn*va.w, attn*vb.x, attn*vb.y};
#pragma unroll
  for (int c = 0; c < 6; c++) {
    float a = oc[c];
#pragma unroll
    for (int o = 8; o >= 1; o >>= 1) a += __shfl_xor(a, o, 16);
    oc[c] = a;
  }
  if (k == 0) {
#pragma unroll
    for (int c = 0; c < 6; c++) out[((size_t)b * 6 + c) * NN + n] = oc[c];
  }
}

extern "C" void kernel_launch(void* const* d_in, const int* in_sizes, int n_in,
                              void* d_out, int out_size, void* d_ws, size_t ws_size,
                              hipStream_t stream)
{
  const float* xyz_hr = (const float*)d_in[0];
  const float* xyz_lr = (const float*)d_in[1];
  const float* val_lr = (const float*)d_in[2];
  const float* feat_hr= (const float*)d_in[3];
  const float* feat_lr= (const float*)d_in[4];
  const float* ge_w1 = (const float*)d_in[5];
  const float* ge_b1 = (const float*)d_in[6];
  const float* ge_g1 = (const float*)d_in[7];
  const float* ge_bt1= (const float*)d_in[8];
  const float* ge_w2 = (const float*)d_in[9];
  const float* ge_b2 = (const float*)d_in[10];
  const float* ge_g2 = (const float*)d_in[11];
  const float* ge_bt2= (const float*)d_in[12];
  const float* sc_w = (const float*)d_in[13];
  const float* sc_b = (const float*)d_in[14];
  const float* sh_w = (const float*)d_in[15];
  const float* sh_b = (const float*)d_in[16];
  const float* q_w  = (const float*)d_in[17];
  const float* q_b  = (const float*)d_in[18];
  const float* k_w  = (const float*)d_in[19];
  const float* k_b  = (const float*)d_in[20];
  const float* bh_w1= (const float*)d_in[21];
  const float* bh_b1= (const float*)d_in[22];
  const float* bh_g = (const float*)d_in[23];
  const float* bh_bt= (const float*)d_in[24];
  const float* bh_w2= (const float*)d_in[25];
  const float* bh_b2= (const float*)d_in[26];
  const float* rp_w1= (const float*)d_in[27];
  const float* rp_b1= (const float*)d_in[28];
  const float* rp_g = (const float*)d_in[29];
  const float* rp_bt= (const float*)d_in[30];
  const float* rp_w2= (const float*)d_in[31];
  const float* rp_b2= (const float*)d_in[32];
  float* out = (float*)d_out;

  // ---- zero-init scratch header: 6 counters | 5x128 dbl sums ----
  int*    ctrs = (int*)((char*)d_ws + 96);            // 6 ints
  double* sums = (double*)((char*)d_ws + 128);        // 5 * 128 doubles
  float*  base = (float*)((char*)d_ws + 5376);
  float* AB1h = base;          // 128
  float* AB2h = base + 128;    // 128
  float* AB1l = base + 256;    // 128
  float* AB2l = base + 384;    // 128
  float* ABb  = base + 512;    // 64
  float* AB2d = base + 576;    // 128
  float* big  = base + 768;
  float* t1_hr = big;                      // 2*64*16384
  float* t2_hr = t1_hr + 2097152;
  float* Qb    = t2_hr + 2097152;
  float* Qp    = Qb    + 2097152;
  float* t1_lr = Qp    + 2097152;          // 2*64*4096
  float* t2_lr = t1_lr + 524288;
  float* Rbuf  = t2_lr + 524288;           // 4096 R + 64 rb (old glr slot)
  float* KfT   = Rbuf  + 524288;           // [B,M,64]
  float* tb    = KfT   + 524288;           // 2*32*16384
  float* xyzT  = tb    + 1048576;          // [B,M,4]
  float* valT  = xyzT  + 32768;            // [B,M,8]
  int*   idxb  = (int*)(valT + 65536);     // 2*16384*16
  // kNN scratch overlays the conv temporaries (consumed before conv pipeline):
  float* partv = t1_hr;                    // B*N*SPL*16 floats
  float* theta = Qb;                       // B*N floats
  double* mompart = (double*)Qp;           // 1024*9 doubles (Qp free until convqq)
  float* Rw    = Rbuf;                     // effective Qp weights
  float* rbv   = Rbuf + 4096;

  (void)hipMemsetAsync(d_ws, 0, 5376, stream);

  tlr_k<<<32, 256, 0, stream>>>(xyz_lr, val_lr, xyzT, valT);
  prepR_k<<<16, 256, 0, stream>>>(q_w, q_b, rp_w2, Rw, rbv);

  // ---- kNN first (uses the big region as scratch) ----
  knnA_k<<<(BB * NN * SPL) / 256, 256, 0, stream>>>(xyz_hr, xyzT, partv);
  knnB_k<<<(BB * NN) / 256, 256, 0, stream>>>(partv, theta);
  knnC_k<<<(BB * NN) / 4, 256, 0, stream>>>(xyz_hr, xyzT, theta, idxb);
  mom1_k<<<1024, 256, 0, stream>>>(xyz_hr, xyzT, idxb, mompart, 1024);
  mom2_k<<<1, 256, 0, stream>>>(mompart, 1024, rp_w1, rp_b1, rp_g, rp_bt, AB2d);

  // ---- encoder pipeline (overwrites the kNN scratch) ----
  convhl_k<GEOC, CQ, 8><<<1280, 256, 0, stream>>>(feat_hr, feat_lr, ge_w1, ge_b1,
                                                  nullptr, nullptr, t1_hr, t1_lr, 1024);
  statshl_k<CQ, 8><<<1024, 256, 0, stream>>>(t1_hr, NN, t1_lr, MM, ge_g1, ge_bt1,
                                             sums, ctrs + 0, AB1h, AB1l);
  convhl_k<CQ, CQ, 8><<<1280, 256, 0, stream>>>(t1_hr, t1_lr, ge_w2, ge_b2,
                                                AB1h, AB1l, t2_hr, t2_lr, 1024);
  statshl_k<CQ, 8><<<1024, 256, 0, stream>>>(t2_hr, NN, t2_lr, MM, ge_g2, ge_bt2,
                                             sums + 256, ctrs + 2, AB2h, AB2l);

  fk_k<<<256, 256, 0, stream>>>(t2_lr, AB2l, val_lr, sc_w, sc_b, sh_w, sh_b,
                                k_w, k_b, KfT);

  conv_k<CQ, 32, 8, false><<<512, 256, 0, stream>>>(t2_hr, bh_w1, bh_b1, AB2h, tb, NN);
  statsone_k<32, 8><<<256, 256, 0, stream>>>(tb, NN, bh_g, bh_bt, sums + 512, ctrs + 4, ABb);
  bdy_k<<<128, 256, 0, stream>>>(tb, ABb, bh_w2, bh_b2, out + (size_t)BB * 6 * NN);

  convqq_k<<<1024, 256, 0, stream>>>(t2_hr, q_w, q_b, Rw, rbv, AB2h, Qb, Qp);

  attn_k<<<2048, 256, 0, stream>>>(Qb, Qp, KfT, idxb, xyzT, valT, xyz_hr, AB2d,
                                   rp_w1, rp_b1, rp_b2, out);
}

// Round 10
// 570.616 us; speedup vs baseline: 4.8796x; 1.0379x over previous
//
#include <hip/hip_runtime.h>

#define BB 2
#define NN 16384
#define MM 4096
#define KK 16
#define CQ 64
#define GEOC 18
#define EPSV 1e-5
#define SPL 8   // M-split per query for kNN phase A

// exact numpy-order fp32 squared distance; contract(off) so bits are identical
// in every kernel that evaluates it.
__device__ __forceinline__ float dist2f(float sa, float ax, float ay, float az, float4 p) {
#pragma clang fp contract(off)
  return (sa + p.w) - 2.0f * ((ax * p.x + ay * p.y) + az * p.z);
}

// compare-exchange and sorting networks (value-preserving -> theta bit-exact)
__device__ __forceinline__ void ce(float& a, float& b) {
  float lo = fminf(a, b), hi = fmaxf(a, b); a = lo; b = hi;
}
// Batcher odd-even mergesort, 8 elements ascending (19 CE)
__device__ __forceinline__ void sort8(float* v) {
  ce(v[0],v[1]); ce(v[2],v[3]); ce(v[4],v[5]); ce(v[6],v[7]);
  ce(v[0],v[2]); ce(v[1],v[3]); ce(v[4],v[6]); ce(v[5],v[7]);
  ce(v[1],v[2]); ce(v[5],v[6]);
  ce(v[0],v[4]); ce(v[1],v[5]); ce(v[2],v[6]); ce(v[3],v[7]);
  ce(v[2],v[4]); ce(v[3],v[5]);
  ce(v[1],v[2]); ce(v[3],v[4]); ce(v[5],v[6]);
}
// sort a bitonic 16-sequence ascending (4 stages)
__device__ __forceinline__ void bitonic16(float* v) {
#pragma unroll
  for (int i = 0; i < 8; i++) ce(v[i], v[i + 8]);
  ce(v[0],v[4]); ce(v[1],v[5]); ce(v[2],v[6]); ce(v[3],v[7]);
  ce(v[8],v[12]); ce(v[9],v[13]); ce(v[10],v[14]); ce(v[11],v[15]);
  ce(v[0],v[2]); ce(v[1],v[3]); ce(v[4],v[6]); ce(v[5],v[7]);
  ce(v[8],v[10]); ce(v[9],v[11]); ce(v[12],v[14]); ce(v[13],v[15]);
  ce(v[0],v[1]); ce(v[2],v[3]); ce(v[4],v[5]); ce(v[6],v[7]);
  ce(v[8],v[9]); ce(v[10],v[11]); ce(v[12],v[13]); ce(v[14],v[15]);
}
// keep lowest-16 of sorted dv[16] U sorted t[8]; dv stays sorted ascending.
__device__ __forceinline__ void merge16_8(float* dv, const float* t) {
  dv[8]  = fminf(dv[8],  t[7]);  dv[9]  = fminf(dv[9],  t[6]);
  dv[10] = fminf(dv[10], t[5]);  dv[11] = fminf(dv[11], t[4]);
  dv[12] = fminf(dv[12], t[3]);  dv[13] = fminf(dv[13], t[2]);
  dv[14] = fminf(dv[14], t[1]);  dv[15] = fminf(dv[15], t[0]);
  bitonic16(dv);
}

// ------- init: transpose lr points/values, effective Qp weights R/rb, zero stats header -------
__global__ __launch_bounds__(256) void init_k(const float* __restrict__ xyz,
    const float* __restrict__ val, float* __restrict__ xyzT, float* __restrict__ valT,
    const float* __restrict__ qw, const float* __restrict__ qb, const float* __restrict__ w2,
    float* __restrict__ R, float* __restrict__ rb, int* __restrict__ hdr)
{
#pragma clang fp contract(off)
  if (blockIdx.x < 32) {
    int i = blockIdx.x * 256 + threadIdx.x;  // B*M
    int b = i / MM, m = i % MM;
    float x = xyz[(b * 3 + 0) * MM + m];
    float y = xyz[(b * 3 + 1) * MM + m];
    float z = xyz[(b * 3 + 2) * MM + m];
    float sb = (x * x + y * y) + z * z;      // exact numpy order: (x2+y2)+z2
    ((float4*)xyzT)[i] = make_float4(x, y, z, sb);
    float v0 = val[((size_t)b * 6 + 0) * MM + m];
    float v1 = val[((size_t)b * 6 + 1) * MM + m];
    float v2 = val[((size_t)b * 6 + 2) * MM + m];
    float v3 = val[((size_t)b * 6 + 3) * MM + m];
    float v4 = val[((size_t)b * 6 + 4) * MM + m];
    float v5 = val[((size_t)b * 6 + 5) * MM + m];
    ((float4*)valT)[2 * i]     = make_float4(v0, v1, v2, v3);
    ((float4*)valT)[2 * i + 1] = make_float4(v4, v5, 0.f, 0.f);
  } else {
    int t = threadIdx.x;
    for (int wd = t; wd < 1376; wd += 256) hdr[wd] = 0;   // ctrs + sums region
#pragma unroll
    for (int e = t * 16; e < t * 16 + 16; e++) {          // R = rp_w2^T * q_w
      int o = e >> 6, i = e & 63;
      float acc = 0.f;
#pragma unroll
      for (int p = 0; p < CQ; p++) acc = fmaf(w2[p * CQ + o], qw[p * CQ + i], acc);
      R[e] = acc;
    }
    if (t < CQ) {
      float a = 0.f;
#pragma unroll
      for (int p = 0; p < CQ; p++) a = fmaf(w2[p * CQ + t], qb[p], a);
      rb[t] = a;
    }
  }
}

// ---------------- 1x1 conv body; OBLK outputs/thread; optional fused BN+ReLU input ----------------
template<int CIN, int COUT, int OBLK, bool TOUT>
__device__ __forceinline__ void conv_body(int tid, const float* __restrict__ x,
    const float* __restrict__ W, const float* __restrict__ bias,
    const float* __restrict__ AB, float* __restrict__ y, int L)
{
  int g = tid / (BB * L);                     // output-channel group
  int i = tid % (BB * L);
  int b = i / L, n = i % L;
  const float* xp = x + (size_t)b * CIN * L + n;
  float xr[CIN];
#pragma unroll
  for (int c = 0; c < CIN; c++) {
    float v = xp[(size_t)c * L];
    if (AB) v = fmaxf(fmaf(v, AB[c], AB[CIN + c]), 0.f);
    xr[c] = v;
  }
#pragma unroll
  for (int oo = 0; oo < OBLK; oo++) {
    int o = g * OBLK + oo;
    float acc = bias ? bias[o] : 0.f;
#pragma unroll
    for (int c = 0; c < CIN; c++)
      acc = fmaf(W[(size_t)o * CIN + c], xr[c], acc);
    if (TOUT) y[((size_t)b * L + n) * COUT + o] = acc;
    else      y[((size_t)b * COUT + o) * L + n] = acc;
  }
}

template<int CIN, int COUT, int OBLK, bool TOUT>
__global__ __launch_bounds__(256) void conv_k(const float* __restrict__ x,
    const float* __restrict__ W, const float* __restrict__ bias,
    const float* __restrict__ AB, float* __restrict__ y, int L)
{
  conv_body<CIN, COUT, OBLK, TOUT>(blockIdx.x * 256 + threadIdx.x, x, W, bias, AB, y, L);
}

// hr + lr in one dispatch (same weights, different AB/in/out)
template<int CIN, int COUT, int OBLK>
__global__ __launch_bounds__(256) void convhl_k(const float* __restrict__ xh,
    const float* __restrict__ xl, const float* __restrict__ W, const float* __restrict__ bias,
    const float* __restrict__ ABh, const float* __restrict__ ABl,
    float* __restrict__ yh, float* __restrict__ yl, int hb)
{
  if ((int)blockIdx.x < hb)
    conv_body<CIN, COUT, OBLK, false>(blockIdx.x * 256 + threadIdx.x, xh, W, bias, ABh, yh, NN);
  else
    conv_body<CIN, COUT, OBLK, false>((blockIdx.x - hb) * 256 + threadIdx.x, xl, W, bias, ABl, yl, MM);
}

// ------------- BN stats body: partial sums + last-block finalize -> (A,B) -------------
template<int C, int NCH>
__device__ __forceinline__ void stats_body(int bid, const float* __restrict__ t, int L,
    const float* __restrict__ g, const float* __restrict__ bt,
    double* __restrict__ sums, int* __restrict__ counter, float* __restrict__ AB)
{
  int c = bid % C;
  int ch = bid / C;
  const size_t tot = (size_t)BB * L;
  const size_t slab = tot / NCH;
  size_t beg = slab * ch, end = beg + slab;
  double s = 0.0, ss = 0.0;
  for (size_t idx = beg + threadIdx.x; idx < end; idx += 256) {
    int b = (int)(idx / L); int i = (int)(idx % L);
    double v = t[((size_t)b * C + c) * L + i];
    s += v; ss += v * v;
  }
  for (int o = 32; o >= 1; o >>= 1) { s += __shfl_down(s, o); ss += __shfl_down(ss, o); }
  __shared__ double sh[8];
  __shared__ int lastf;
  int w = threadIdx.x >> 6;
  if ((threadIdx.x & 63) == 0) { sh[2 * w] = s; sh[2 * w + 1] = ss; }
  __syncthreads();
  if (threadIdx.x == 0) {
    for (int j = 1; j < 4; j++) { s += sh[2 * j]; ss += sh[2 * j + 1]; }
    atomicAdd(&sums[c], s);
    atomicAdd(&sums[C + c], ss);
    __threadfence();
    int old = atomicAdd(counter, 1);
    lastf = (old == C * NCH - 1) ? 1 : 0;
  }
  __syncthreads();
  if (lastf && threadIdx.x < C) {
    __threadfence();
    int cc = threadIdx.x;
    double S  = atomicAdd(&sums[cc], 0.0);
    double SS = atomicAdd(&sums[C + cc], 0.0);
    double nn = (double)BB * L;
    double mean = S / nn, var = SS / nn - mean * mean;
    double A = (double)g[cc] / sqrt(var + EPSV);
    AB[cc] = (float)A;
    AB[C + cc] = (float)((double)bt[cc] - mean * A);
  }
}

template<int C, int NCH>
__global__ __launch_bounds__(256) void statsone_k(const float* __restrict__ t, int L,
    const float* __restrict__ g, const float* __restrict__ bt,
    double* __restrict__ sums, int* __restrict__ counter, float* __restrict__ AB)
{
  stats_body<C, NCH>(blockIdx.x, t, L, g, bt, sums, counter, AB);
}

template<int C, int NCH>
__global__ __launch_bounds__(256) void statshl_k(const float* __restrict__ t0, int L0,
    const float* __restrict__ t1, int L1, const float* __restrict__ g,
    const float* __restrict__ bt, double* __restrict__ sums, int* __restrict__ ctrs,
    float* __restrict__ AB0, float* __restrict__ AB1)
{
  if ((int)blockIdx.x < C * NCH)
    stats_body<C, NCH>(blockIdx.x, t0, L0, g, bt, sums, ctrs, AB0);
  else
    stats_body<C, NCH>(blockIdx.x - C * NCH, t1, L1, g, bt, sums + 2 * C, ctrs + 1, AB1);
}

// ---------------- fused FiLM + K-conv: KfT[b,m,:] = k_w * film(bn(t2l)) + k_b ----------------
__global__ __launch_bounds__(256) void fk_k(const float* __restrict__ t2l,
    const float* __restrict__ ABl, const float* __restrict__ val,
    const float* __restrict__ scw, const float* __restrict__ scb,
    const float* __restrict__ shw, const float* __restrict__ shb,
    const float* __restrict__ kw, const float* __restrict__ kb,
    float* __restrict__ KfT)
{
  int tid = blockIdx.x * 256 + threadIdx.x;  // B*M*8
  int g = tid & 7;
  int i = tid >> 3;                          // b*M + m
  int b = i / MM, m = i % MM;
  float v6[6];
#pragma unroll
  for (int j = 0; j < 6; j++) v6[j] = val[((size_t)b * 6 + j) * MM + m];
  float xr[CQ];
#pragma unroll
  for (int c = 0; c < CQ; c++) {
    float gv = fmaxf(fmaf(t2l[((size_t)b * CQ + c) * MM + m], ABl[c], ABl[CQ + c]), 0.f);
    float sc = scb[c], sh = shb[c];
#pragma unroll
    for (int j = 0; j < 6; j++) {
      sc = fmaf(scw[c * 6 + j], v6[j], sc);
      sh = fmaf(shw[c * 6 + j], v6[j], sh);
    }
    xr[c] = fmaf(gv, 1.f + sc, sh);
  }
#pragma unroll
  for (int oo = 0; oo < 8; oo++) {
    int o = g * 8 + oo;
    float acc = kb[o];
#pragma unroll
    for (int c = 0; c < CQ; c++) acc = fmaf(kw[o * CQ + c], xr[c], acc);
    KfT[(size_t)i * CQ + o] = acc;
  }
}

// ---------------- fused Q + Qp conv (one input pass, two weight sets) ----------------
__global__ __launch_bounds__(256) void convqq_k(const float* __restrict__ x,
    const float* __restrict__ Wq, const float* __restrict__ bq,
    const float* __restrict__ R, const float* __restrict__ rb,
    const float* __restrict__ AB, float* __restrict__ Q, float* __restrict__ Qp)
{
  int tid = blockIdx.x * 256 + threadIdx.x;  // 4 * B*NN
  int g = tid / (BB * NN);
  int i = tid % (BB * NN);
  int b = i / NN, n = i % NN;
  const float* xp = x + (size_t)b * CQ * NN + n;
  float xr[CQ];
#pragma unroll
  for (int c = 0; c < CQ; c++)
    xr[c] = fmaxf(fmaf(xp[(size_t)c * NN], AB[c], AB[CQ + c]), 0.f);
#pragma unroll
  for (int oo = 0; oo < 16; oo++) {
    int o = g * 16 + oo;
    float aq = bq[o], ap = rb[o];
#pragma unroll
    for (int c = 0; c < CQ; c++) {
      aq = fmaf(Wq[o * CQ + c], xr[c], aq);
      ap = fmaf(R[o * CQ + c], xr[c], ap);
    }
    Q[((size_t)b * CQ + o) * NN + n] = aq;
    Qp[((size_t)b * CQ + o) * NN + n] = ap;
  }
}

// ---------------- boundary head output ----------------
__global__ __launch_bounds__(256) void bdy_k(const float* __restrict__ tb,
    const float* __restrict__ AB, const float* __restrict__ w2,
    const float* __restrict__ b2, float* __restrict__ out2)
{
  int i = blockIdx.x * 256 + threadIdx.x;  // B*N
  int b = i / NN, n = i % NN;
  float acc = b2[0];
#pragma unroll
  for (int c = 0; c < 32; c++) {
    float v = tb[((size_t)b * 32 + c) * NN + n];
    v = fmaxf(fmaf(v, AB[c], AB[32 + c]), 0.f);
    acc = fmaf(w2[c], v, acc);
  }
  out2[i] = 1.f / (1.f + expf(-acc));
}

// ------- kNN phase A: per-(query, residue) top-16 values + in-wave butterfly merge -> theta -------
// The 8 residue-threads of a query are 8 consecutive lanes of one wave; after the scan,
// 3 shfl_xor levels (mask 1,2,4) merge sorted-16 runs keep-low-16. Both partners compute
// the identical sorted union (multiset equality) -> uniform, divergence-free; theta bit-exact.
__global__ __launch_bounds__(256) void knnA_k(const float* __restrict__ xyz_hr,
    const float* __restrict__ xyzT, float* __restrict__ theta)
{
#pragma clang fp contract(off)
  int tid = blockIdx.x * 256 + threadIdx.x;  // B*N*SPL
  int s = tid & (SPL - 1);
  int qi = tid / SPL;                        // b*NN + n
  int b = qi / NN, n = qi % NN;
  float ax = xyz_hr[(b * 3 + 0) * NN + n];
  float ay = xyz_hr[(b * 3 + 1) * NN + n];
  float az = xyz_hr[(b * 3 + 2) * NN + n];
  float sa = (ax * ax + ay * ay) + az * az;
  const float4* __restrict__ Ps = ((const float4*)xyzT) + (size_t)b * MM + s;
  float dv[16];
#pragma unroll
  for (int j = 0; j < 16; j++) dv[j] = 3.4e38f;
  for (int j = 0; j < MM / SPL; j += 8) {
    float t[8];
#pragma unroll
    for (int u = 0; u < 8; u++) {
      float4 p = Ps[(size_t)(j + u) * SPL];
      t[u] = dist2f(sa, ax, ay, az, p);
    }
    sort8(t);
    merge16_8(dv, t);
  }
  // butterfly merge across the 8 lanes of this query
#pragma unroll
  for (int mask = 1; mask <= 4; mask <<= 1) {
    float c[16];
#pragma unroll
    for (int j = 0; j < 16; j++) c[j] = __shfl_xor(dv[15 - j], mask);
#pragma unroll
    for (int j = 0; j < 16; j++) dv[j] = fminf(dv[j], c[j]);
    bitonic16(dv);
  }
  if (s == 0) theta[qi] = dv[15];
}

// ---- kNN phase C + rel_pos moments: collect idx (d<theta; ties d==theta by asc idx),
// ---- then accumulate BN2d moments of the 16 selected rel_pos per query, block partials out.
__global__ __launch_bounds__(256) void knnC_k(const float* __restrict__ xyz_hr,
    const float* __restrict__ xyzT, const float* __restrict__ theta,
    int* __restrict__ idx_out, double* __restrict__ mompart)
{
#pragma clang fp contract(off)
  __shared__ int s_clt[4], s_ceq[4];
  __shared__ int s_lt[4][16];
  __shared__ int s_eq[4][64];
  __shared__ int s_sel[4][16];
  __shared__ float s_mom[4][9];
  int w = threadIdx.x >> 6, l = threadIdx.x & 63;
  int qi = blockIdx.x * 4 + w;               // B*N / 4 blocks
  int b = qi / NN, n = qi % NN;
  if (l == 0) { s_clt[w] = 0; s_ceq[w] = 0; }
  __syncthreads();
  float ax = xyz_hr[(b * 3 + 0) * NN + n];
  float ay = xyz_hr[(b * 3 + 1) * NN + n];
  float az = xyz_hr[(b * 3 + 2) * NN + n];
  float sa = (ax * ax + ay * ay) + az * az;
  float th = theta[qi];
  const float4* __restrict__ P = ((const float4*)xyzT) + (size_t)b * MM;
  for (int j = 0; j < MM / 64; j++) {
    int m = j * 64 + l;
    float d = dist2f(sa, ax, ay, az, P[m]);
    if (d < th) {
      int pos = atomicAdd(&s_clt[w], 1);
      if (pos < 16) s_lt[w][pos] = m;
    } else if (d == th) {
      int pos = atomicAdd(&s_ceq[w], 1);
      if (pos < 64) s_eq[w][pos] = m;
    }
  }
  __syncthreads();
  if (l == 0) {
    int clt = s_clt[w]; if (clt > 16) clt = 16;  // mathematically <= 15
    int ceq = s_ceq[w]; if (ceq > 64) ceq = 64;
    for (int j = 0; j < clt; j++) s_sel[w][j] = s_lt[w][j];
    int need = KK - clt;                          // >= 1, <= ceq
    for (int t = 0; t < need; t++) {
      int best = 0x7fffffff, bp = 0;
      for (int j = 0; j < ceq; j++) { int v = s_eq[w][j]; if (v < best) { best = v; bp = j; } }
      s_sel[w][clt + t] = best;
      s_eq[w][bp] = 0x7fffffff;
    }
    size_t base = (size_t)qi * KK;
    for (int j = 0; j < KK; j++) idx_out[base + j] = s_sel[w][j];
  }
  __syncthreads();
  // moments of the 16 selected rel_pos (lanes 0-15 active; others contribute 0)
  float t9[9];
#pragma unroll
  for (int j = 0; j < 9; j++) t9[j] = 0.f;
  if (l < 16) {
    float4 p = P[s_sel[w][l]];
    float rx = ax - p.x, ry = ay - p.y, rz = az - p.z;
    t9[0] = rx; t9[1] = ry; t9[2] = rz;
    t9[3] = rx * rx; t9[4] = ry * ry; t9[5] = rz * rz;
    t9[6] = rx * ry; t9[7] = rx * rz; t9[8] = ry * rz;
  }
#pragma unroll
  for (int j = 0; j < 9; j++)
    for (int o = 32; o >= 1; o >>= 1) t9[j] += __shfl_down(t9[j], o);
  if (l == 0) { for (int j = 0; j < 9; j++) s_mom[w][j] = t9[j]; }
  __syncthreads();
  if (threadIdx.x == 0) {
    double* op = mompart + (size_t)blockIdx.x * 9;
    for (int j = 0; j < 9; j++)
      op[j] = (double)s_mom[0][j] + (double)s_mom[1][j] + (double)s_mom[2][j] + (double)s_mom[3][j];
  }
}

// -------- moments phase 2: one block reduces 8192 partials, finalizes AB2d --------
__global__ __launch_bounds__(256) void mom2_k(const double* __restrict__ part, int nblk,
    const float* __restrict__ w1, const float* __restrict__ b1,
    const float* __restrict__ g, const float* __restrict__ bt, float* __restrict__ AB)
{
  double acc[9];
#pragma unroll
  for (int j = 0; j < 9; j++) acc[j] = 0.0;
  for (int blk = threadIdx.x; blk < nblk; blk += 256) {
    const double* p = part + (size_t)blk * 9;
#pragma unroll
    for (int j = 0; j < 9; j++) acc[j] += p[j];
  }
#pragma unroll
  for (int j = 0; j < 9; j++)
    for (int o = 32; o >= 1; o >>= 1) acc[j] += __shfl_down(acc[j], o);
  __shared__ double sh[4][9];
  __shared__ double mo[9];
  int w = threadIdx.x >> 6, l = threadIdx.x & 63;
  if (l == 0) { for (int j = 0; j < 9; j++) sh[w][j] = acc[j]; }
  __syncthreads();
  if (threadIdx.x == 0) {
    for (int wv = 1; wv < 4; wv++) for (int j = 0; j < 9; j++) sh[0][j] += sh[wv][j];
    for (int j = 0; j < 9; j++) mo[j] = sh[0][j];
  }
  __syncthreads();
  if (threadIdx.x < CQ) {
    int c = threadIdx.x;
    double cnt = (double)BB * NN * KK;
    double mx = mo[0]/cnt, my = mo[1]/cnt, mz = mo[2]/cnt;
    double cxx = mo[3]/cnt - mx*mx, cyy = mo[4]/cnt - my*my, czz = mo[5]/cnt - mz*mz;
    double cxy = mo[6]/cnt - mx*my, cxz = mo[7]/cnt - mx*mz, cyz = mo[8]/cnt - my*mz;
    double wx = w1[c*3], wy = w1[c*3+1], wz = w1[c*3+2];
    double mean = wx*mx + wy*my + wz*mz + (double)b1[c];
    double var = wx*wx*cxx + wy*wy*cyy + wz*wz*czz + 2.0*(wx*wy*cxy + wx*wz*cxz + wy*wz*cyz);
    double A = (double)g[c] / sqrt(var + EPSV);
    AB[c] = (float)A;
    AB[CQ + c] = (float)((double)bt[c] - mean * A);
  }
}

// ---------------- fused pos-enc + attention + output ----------------
__global__ __launch_bounds__(256) void attn_k(
    const float* __restrict__ Q, const float* __restrict__ Qp,
    const float* __restrict__ KfT, const int* __restrict__ idxb,
    const float* __restrict__ xyzT, const float* __restrict__ valT,
    const float* __restrict__ xyz_hr, const float* __restrict__ AB,
    const float* __restrict__ w1, const float* __restrict__ b1,
    const float* __restrict__ b2, float* __restrict__ out)
{
  __shared__ float q_s[CQ * 16], qp_s[CQ * 16];
  const int ngrp = NN / 16;
  int b = blockIdx.x / ngrp;
  int n0 = (blockIdx.x % ngrp) * 16;
  for (int t = threadIdx.x; t < CQ * 16; t += 256) {
    int c = t >> 4, j = t & 15;
    q_s[t]  = Q [((size_t)b * CQ + c) * NN + n0 + j];
    qp_s[t] = Qp[((size_t)b * CQ + c) * NN + n0 + j];
  }
  __syncthreads();
  int q = threadIdx.x >> 4, k = threadIdx.x & 15;
  int n = n0 + q;
  int id = idxb[((size_t)b * NN + n) * KK + k];
  float ax = xyz_hr[(b * 3 + 0) * NN + n];
  float ay = xyz_hr[(b * 3 + 1) * NN + n];
  float az = xyz_hr[(b * 3 + 2) * NN + n];
  float4 pl = ((const float4*)xyzT)[(size_t)b * MM + id];
  float rx = ax - pl.x, ry = ay - pl.y, rz = az - pl.z;
  const float4* kg = (const float4*)(KfT + ((size_t)b * MM + id) * CQ);
  float s = 0.f;
#pragma unroll
  for (int c4 = 0; c4 < CQ / 4; c4++) {
    float4 g4 = kg[c4];
    float ga[4] = {g4.x, g4.y, g4.z, g4.w};
#pragma unroll
    for (int u = 0; u < 4; u++) {
      int c = 4 * c4 + u;
      float t0 = fmaf(w1[c * 3 + 0], rx, fmaf(w1[c * 3 + 1], ry, w1[c * 3 + 2] * rz)) + b1[c];
      float pe = fmaxf(fmaf(t0, AB[c], AB[CQ + c]), 0.f);
      s = fmaf(q_s[c * 16 + q], ga[u] + b2[c], s);
      s = fmaf(qp_s[c * 16 + q], pe, s);
    }
  }
  s *= 0.125f;  // /sqrt(64)
  float mx = s;
#pragma unroll
  for (int o = 8; o >= 1; o >>= 1) mx = fmaxf(mx, __shfl_xor(mx, o, 16));
  float p = expf(s - mx);
  float sum = p;
#pragma unroll
  for (int o = 8; o >= 1; o >>= 1) sum += __shfl_xor(sum, o, 16);
  float attn = p / sum;
  const float4* vt = (const float4*)(valT + ((size_t)b * MM + id) * 8);
  float4 va = vt[0], vb = vt[1];
  float oc[6] = {attn*va.x, attn*va.y, attn*va.z, attn*va.w, attn*vb.x, attn*vb.y};
#pragma unroll
  for (int c = 0; c < 6; c++) {
    float a = oc[c];
#pragma unroll
    for (int o = 8; o >= 1; o >>= 1) a += __shfl_xor(a, o, 16);
    oc[c] = a;
  }
  if (k == 0) {
#pragma unroll
    for (int c = 0; c < 6; c++) out[((size_t)b * 6 + c) * NN + n] = oc[c];
  }
}

extern "C" void kernel_launch(void* const* d_in, const int* in_sizes, int n_in,
                              void* d_out, int out_size, void* d_ws, size_t ws_size,
                              hipStream_t stream)
{
  const float* xyz_hr = (const float*)d_in[0];
  const float* xyz_lr = (const float*)d_in[1];
  const float* val_lr = (const float*)d_in[2];
  const float* feat_hr= (const float*)d_in[3];
  const float* feat_lr= (const float*)d_in[4];
  const float* ge_w1 = (const float*)d_in[5];
  const float* ge_b1 = (const float*)d_in[6];
  const float* ge_g1 = (const float*)d_in[7];
  const float* ge_bt1= (const float*)d_in[8];
  const float* ge_w2 = (const float*)d_in[9];
  const float* ge_b2 = (const float*)d_in[10];
  const float* ge_g2 = (const float*)d_in[11];
  const float* ge_bt2= (const float*)d_in[12];
  const float* sc_w = (const float*)d_in[13];
  const float* sc_b = (const float*)d_in[14];
  const float* sh_w = (const float*)d_in[15];
  const float* sh_b = (const float*)d_in[16];
  const float* q_w  = (const float*)d_in[17];
  const float* q_b  = (const float*)d_in[18];
  const float* k_w  = (const float*)d_in[19];
  const float* k_b  = (const float*)d_in[20];
  const float* bh_w1= (const float*)d_in[21];
  const float* bh_b1= (const float*)d_in[22];
  const float* bh_g = (const float*)d_in[23];
  const float* bh_bt= (const float*)d_in[24];
  const float* bh_w2= (const float*)d_in[25];
  const float* bh_b2= (const float*)d_in[26];
  const float* rp_w1= (const float*)d_in[27];
  const float* rp_b1= (const float*)d_in[28];
  const float* rp_g = (const float*)d_in[29];
  const float* rp_bt= (const float*)d_in[30];
  const float* rp_w2= (const float*)d_in[31];
  const float* rp_b2= (const float*)d_in[32];
  float* out = (float*)d_out;

  // ---- scratch header (zeroed by init_k block 32): [0,96) pad | ctrs 6 ints | sums 5*128 dbl ----
  int*    hdr  = (int*)d_ws;
  int*    ctrs = (int*)((char*)d_ws + 96);            // 6 ints
  double* sums = (double*)((char*)d_ws + 128);        // 5 * 128 doubles
  float*  base = (float*)((char*)d_ws + 5504);
  float* AB1h = base;          // 128
  float* AB2h = base + 128;    // 128
  float* AB1l = base + 256;    // 128
  float* AB2l = base + 384;    // 128
  float* ABb  = base + 512;    // 64
  float* AB2d = base + 576;    // 128
  float* big  = base + 768;
  float* t1_hr = big;                      // 2*64*16384
  float* t2_hr = t1_hr + 2097152;
  float* Qb    = t2_hr + 2097152;
  float* Qp    = Qb    + 2097152;
  float* t1_lr = Qp    + 2097152;          // 2*64*4096
  float* t2_lr = t1_lr + 524288;
  float* Rbuf  = t2_lr + 524288;           // 4096 R + 64 rb
  float* KfT   = Rbuf  + 524288;           // [B,M,64]
  float* tb    = KfT   + 524288;           // 2*32*16384
  float* xyzT  = tb    + 1048576;          // [B,M,4]
  float* valT  = xyzT  + 32768;            // [B,M,8]
  int*   idxb  = (int*)(valT + 65536);     // 2*16384*16
  // kNN scratch overlays conv temporaries (consumed before conv pipeline):
  float* theta = Qb;                       // B*N floats
  double* mompart = (double*)Qp;           // 8192*9 doubles (Qp free until convqq)
  float* Rw    = Rbuf;                     // effective Qp weights
  float* rbv   = Rbuf + 4096;

  init_k<<<33, 256, 0, stream>>>(xyz_lr, val_lr, xyzT, valT, q_w, q_b, rp_w2, Rw, rbv, hdr);

  // ---- kNN ----
  knnA_k<<<(BB * NN * SPL) / 256, 256, 0, stream>>>(xyz_hr, xyzT, theta);
  knnC_k<<<(BB * NN) / 4, 256, 0, stream>>>(xyz_hr, xyzT, theta, idxb, mompart);
  mom2_k<<<1, 256, 0, stream>>>(mompart, (BB * NN) / 4, rp_w1, rp_b1, rp_g, rp_bt, AB2d);

  // ---- encoder pipeline ----
  convhl_k<GEOC, CQ, 16><<<640, 256, 0, stream>>>(feat_hr, feat_lr, ge_w1, ge_b1,
                                                  nullptr, nullptr, t1_hr, t1_lr, 512);
  statshl_k<CQ, 8><<<1024, 256, 0, stream>>>(t1_hr, NN, t1_lr, MM, ge_g1, ge_bt1,
                                             sums, ctrs + 0, AB1h, AB1l);
  convhl_k<CQ, CQ, 16><<<640, 256, 0, stream>>>(t1_hr, t1_lr, ge_w2, ge_b2,
                                                AB1h, AB1l, t2_hr, t2_lr, 512);
  statshl_k<CQ, 8><<<1024, 256, 0, stream>>>(t2_hr, NN, t2_lr, MM, ge_g2, ge_bt2,
                                             sums + 256, ctrs + 2, AB2h, AB2l);

  fk_k<<<256, 256, 0, stream>>>(t2_lr, AB2l, val_lr, sc_w, sc_b, sh_w, sh_b,
                                k_w, k_b, KfT);

  conv_k<CQ, 32, 16, false><<<256, 256, 0, stream>>>(t2_hr, bh_w1, bh_b1, AB2h, tb, NN);
  statsone_k<32, 8><<<256, 256, 0, stream>>>(tb, NN, bh_g, bh_bt, sums + 512, ctrs + 4, ABb);
  bdy_k<<<128, 256, 0, stream>>>(tb, ABb, bh_w2, bh_b2, out + (size_t)BB * 6 * NN);

  convqq_k<<<512, 256, 0, stream>>>(t2_hr, q_w, q_b, Rw, rbv, AB2h, Qb, Qp);

  attn_k<<<2048, 256, 0, stream>>>(Qb, Qp, KfT, idxb, xyzT, valT, xyz_hr, AB2d,
                                   rp_w1, rp_b1, rp_b2, out);
}

// Round 11
// 530.909 us; speedup vs baseline: 5.2446x; 1.0748x over previous
//
#include <hip/hip_runtime.h>

#define BB 2
#define NN 16384
#define MM 4096
#define KK 16
#define CQ 64
#define GEOC 18
#define EPSV 1e-5
#define SPL 8   // M-split per query for kNN phase A

// exact numpy-order fp32 squared distance; contract(off) so bits are identical
// in every kernel that evaluates it.
__device__ __forceinline__ float dist2f(float sa, float ax, float ay, float az, float4 p) {
#pragma clang fp contract(off)
  return (sa + p.w) - 2.0f * ((ax * p.x + ay * p.y) + az * p.z);
}

// compare-exchange and sorting networks (value-preserving -> theta bit-exact)
__device__ __forceinline__ void ce(float& a, float& b) {
  float lo = fminf(a, b), hi = fmaxf(a, b); a = lo; b = hi;
}
// Batcher odd-even mergesort, 8 elements ascending (19 CE)
__device__ __forceinline__ void sort8(float* v) {
  ce(v[0],v[1]); ce(v[2],v[3]); ce(v[4],v[5]); ce(v[6],v[7]);
  ce(v[0],v[2]); ce(v[1],v[3]); ce(v[4],v[6]); ce(v[5],v[7]);
  ce(v[1],v[2]); ce(v[5],v[6]);
  ce(v[0],v[4]); ce(v[1],v[5]); ce(v[2],v[6]); ce(v[3],v[7]);
  ce(v[2],v[4]); ce(v[3],v[5]);
  ce(v[1],v[2]); ce(v[3],v[4]); ce(v[5],v[6]);
}
// sort a bitonic 16-sequence ascending (4 stages)
__device__ __forceinline__ void bitonic16(float* v) {
#pragma unroll
  for (int i = 0; i < 8; i++) ce(v[i], v[i + 8]);
  ce(v[0],v[4]); ce(v[1],v[5]); ce(v[2],v[6]); ce(v[3],v[7]);
  ce(v[8],v[12]); ce(v[9],v[13]); ce(v[10],v[14]); ce(v[11],v[15]);
  ce(v[0],v[2]); ce(v[1],v[3]); ce(v[4],v[6]); ce(v[5],v[7]);
  ce(v[8],v[10]); ce(v[9],v[11]); ce(v[12],v[14]); ce(v[13],v[15]);
  ce(v[0],v[1]); ce(v[2],v[3]); ce(v[4],v[5]); ce(v[6],v[7]);
  ce(v[8],v[9]); ce(v[10],v[11]); ce(v[12],v[13]); ce(v[14],v[15]);
}
// keep lowest-16 of sorted dv[16] U sorted t[8]; dv stays sorted ascending.
__device__ __forceinline__ void merge16_8(float* dv, const float* t) {
  dv[8]  = fminf(dv[8],  t[7]);  dv[9]  = fminf(dv[9],  t[6]);
  dv[10] = fminf(dv[10], t[5]);  dv[11] = fminf(dv[11], t[4]);
  dv[12] = fminf(dv[12], t[3]);  dv[13] = fminf(dv[13], t[2]);
  dv[14] = fminf(dv[14], t[1]);  dv[15] = fminf(dv[15], t[0]);
  bitonic16(dv);
}

// ------- init: transpose lr points/values, effective Qp weights R/rb, zero stats header -------
__global__ __launch_bounds__(256) void init_k(const float* __restrict__ xyz,
    const float* __restrict__ val, float* __restrict__ xyzT, float* __restrict__ valT,
    const float* __restrict__ qw, const float* __restrict__ qb, const float* __restrict__ w2,
    float* __restrict__ R, float* __restrict__ rb, int* __restrict__ hdr)
{
#pragma clang fp contract(off)
  if (blockIdx.x < 32) {
    int i = blockIdx.x * 256 + threadIdx.x;  // B*M
    int b = i / MM, m = i % MM;
    float x = xyz[(b * 3 + 0) * MM + m];
    float y = xyz[(b * 3 + 1) * MM + m];
    float z = xyz[(b * 3 + 2) * MM + m];
    float sb = (x * x + y * y) + z * z;      // exact numpy order: (x2+y2)+z2
    ((float4*)xyzT)[i] = make_float4(x, y, z, sb);
    float v0 = val[((size_t)b * 6 + 0) * MM + m];
    float v1 = val[((size_t)b * 6 + 1) * MM + m];
    float v2 = val[((size_t)b * 6 + 2) * MM + m];
    float v3 = val[((size_t)b * 6 + 3) * MM + m];
    float v4 = val[((size_t)b * 6 + 4) * MM + m];
    float v5 = val[((size_t)b * 6 + 5) * MM + m];
    ((float4*)valT)[2 * i]     = make_float4(v0, v1, v2, v3);
    ((float4*)valT)[2 * i + 1] = make_float4(v4, v5, 0.f, 0.f);
  } else {
    int t = threadIdx.x;
    for (int wd = t; wd < 1376; wd += 256) hdr[wd] = 0;   // ctrs + sums region
#pragma unroll
    for (int e = t * 16; e < t * 16 + 16; e++) {          // R = rp_w2^T * q_w
      int o = e >> 6, i = e & 63;
      float acc = 0.f;
#pragma unroll
      for (int p = 0; p < CQ; p++) acc = fmaf(w2[p * CQ + o], qw[p * CQ + i], acc);
      R[e] = acc;
    }
    if (t < CQ) {
      float a = 0.f;
#pragma unroll
      for (int p = 0; p < CQ; p++) a = fmaf(w2[p * CQ + t], qb[p], a);
      rb[t] = a;
    }
  }
}

// ---------------- 1x1 conv body; OBLK outputs/thread; optional fused BN+ReLU input ----------------
template<int CIN, int COUT, int OBLK, bool TOUT>
__device__ __forceinline__ void conv_body(int tid, const float* __restrict__ x,
    const float* __restrict__ W, const float* __restrict__ bias,
    const float* __restrict__ AB, float* __restrict__ y, int L)
{
  int g = tid / (BB * L);                     // output-channel group
  int i = tid % (BB * L);
  int b = i / L, n = i % L;
  const float* xp = x + (size_t)b * CIN * L + n;
  float xr[CIN];
#pragma unroll
  for (int c = 0; c < CIN; c++) {
    float v = xp[(size_t)c * L];
    if (AB) v = fmaxf(fmaf(v, AB[c], AB[CIN + c]), 0.f);
    xr[c] = v;
  }
#pragma unroll
  for (int oo = 0; oo < OBLK; oo++) {
    int o = g * OBLK + oo;
    float acc = bias ? bias[o] : 0.f;
#pragma unroll
    for (int c = 0; c < CIN; c++)
      acc = fmaf(W[(size_t)o * CIN + c], xr[c], acc);
    if (TOUT) y[((size_t)b * L + n) * COUT + o] = acc;
    else      y[((size_t)b * COUT + o) * L + n] = acc;
  }
}

// hr + lr in one dispatch (same weights, different AB/in/out)
template<int CIN, int COUT, int OBLK>
__global__ __launch_bounds__(256) void convhl_k(const float* __restrict__ xh,
    const float* __restrict__ xl, const float* __restrict__ W, const float* __restrict__ bias,
    const float* __restrict__ ABh, const float* __restrict__ ABl,
    float* __restrict__ yh, float* __restrict__ yl, int hb)
{
  if ((int)blockIdx.x < hb)
    conv_body<CIN, COUT, OBLK, false>(blockIdx.x * 256 + threadIdx.x, xh, W, bias, ABh, yh, NN);
  else
    conv_body<CIN, COUT, OBLK, false>((blockIdx.x - hb) * 256 + threadIdx.x, xl, W, bias, ABl, yl, MM);
}

// ------------- BN stats body: partial sums + last-block finalize -> (A,B) -------------
template<int C, int NCH>
__device__ __forceinline__ void stats_body(int bid, const float* __restrict__ t, int L,
    const float* __restrict__ g, const float* __restrict__ bt,
    double* __restrict__ sums, int* __restrict__ counter, float* __restrict__ AB)
{
  int c = bid % C;
  int ch = bid / C;
  const size_t tot = (size_t)BB * L;
  const size_t slab = tot / NCH;
  size_t beg = slab * ch, end = beg + slab;
  double s = 0.0, ss = 0.0;
  for (size_t idx = beg + threadIdx.x; idx < end; idx += 256) {
    int b = (int)(idx / L); int i = (int)(idx % L);
    double v = t[((size_t)b * C + c) * L + i];
    s += v; ss += v * v;
  }
  for (int o = 32; o >= 1; o >>= 1) { s += __shfl_down(s, o); ss += __shfl_down(ss, o); }
  __shared__ double sh[8];
  __shared__ int lastf;
  int w = threadIdx.x >> 6;
  if ((threadIdx.x & 63) == 0) { sh[2 * w] = s; sh[2 * w + 1] = ss; }
  __syncthreads();
  if (threadIdx.x == 0) {
    for (int j = 1; j < 4; j++) { s += sh[2 * j]; ss += sh[2 * j + 1]; }
    atomicAdd(&sums[c], s);
    atomicAdd(&sums[C + c], ss);
    __threadfence();
    int old = atomicAdd(counter, 1);
    lastf = (old == C * NCH - 1) ? 1 : 0;
  }
  __syncthreads();
  if (lastf && threadIdx.x < C) {
    __threadfence();
    int cc = threadIdx.x;
    double S  = atomicAdd(&sums[cc], 0.0);
    double SS = atomicAdd(&sums[C + cc], 0.0);
    double nn = (double)BB * L;
    double mean = S / nn, var = SS / nn - mean * mean;
    double A = (double)g[cc] / sqrt(var + EPSV);
    AB[cc] = (float)A;
    AB[C + cc] = (float)((double)bt[cc] - mean * A);
  }
}

template<int C, int NCH>
__global__ __launch_bounds__(256) void statsone_k(const float* __restrict__ t, int L,
    const float* __restrict__ g, const float* __restrict__ bt,
    double* __restrict__ sums, int* __restrict__ counter, float* __restrict__ AB)
{
  stats_body<C, NCH>(blockIdx.x, t, L, g, bt, sums, counter, AB);
}

template<int C, int NCH>
__global__ __launch_bounds__(256) void statshl_k(const float* __restrict__ t0, int L0,
    const float* __restrict__ t1, int L1, const float* __restrict__ g,
    const float* __restrict__ bt, double* __restrict__ sums, int* __restrict__ ctrs,
    float* __restrict__ AB0, float* __restrict__ AB1)
{
  if ((int)blockIdx.x < C * NCH)
    stats_body<C, NCH>(blockIdx.x, t0, L0, g, bt, sums, ctrs, AB0);
  else
    stats_body<C, NCH>(blockIdx.x - C * NCH, t1, L1, g, bt, sums + 2 * C, ctrs + 1, AB1);
}

// ---------------- fused FiLM + K-conv: KfT[b,m,:] = k_w * film(bn(t2l)) + k_b ----------------
__global__ __launch_bounds__(256) void fk_k(const float* __restrict__ t2l,
    const float* __restrict__ ABl, const float* __restrict__ val,
    const float* __restrict__ scw, const float* __restrict__ scb,
    const float* __restrict__ shw, const float* __restrict__ shb,
    const float* __restrict__ kw, const float* __restrict__ kb,
    float* __restrict__ KfT)
{
  int tid = blockIdx.x * 256 + threadIdx.x;  // B*M*8
  int g = tid & 7;
  int i = tid >> 3;                          // b*M + m
  int b = i / MM, m = i % MM;
  float v6[6];
#pragma unroll
  for (int j = 0; j < 6; j++) v6[j] = val[((size_t)b * 6 + j) * MM + m];
  float xr[CQ];
#pragma unroll
  for (int c = 0; c < CQ; c++) {
    float gv = fmaxf(fmaf(t2l[((size_t)b * CQ + c) * MM + m], ABl[c], ABl[CQ + c]), 0.f);
    float sc = scb[c], sh = shb[c];
#pragma unroll
    for (int j = 0; j < 6; j++) {
      sc = fmaf(scw[c * 6 + j], v6[j], sc);
      sh = fmaf(shw[c * 6 + j], v6[j], sh);
    }
    xr[c] = fmaf(gv, 1.f + sc, sh);
  }
#pragma unroll
  for (int oo = 0; oo < 8; oo++) {
    int o = g * 8 + oo;
    float acc = kb[o];
#pragma unroll
    for (int c = 0; c < CQ; c++) acc = fmaf(kw[o * CQ + c], xr[c], acc);
    KfT[(size_t)i * CQ + o] = acc;
  }
}

// ------- fused boundary-conv + Q + Qp: one t2_hr pass -> tb(32) | Q(64) | Qp(64) -------
__global__ __launch_bounds__(256) void convbqq_k(const float* __restrict__ x,
    const float* __restrict__ bw, const float* __restrict__ bb,
    const float* __restrict__ Wq, const float* __restrict__ bq,
    const float* __restrict__ R, const float* __restrict__ rb,
    const float* __restrict__ AB, float* __restrict__ tb,
    float* __restrict__ Q, float* __restrict__ Qp)
{
  int tid = blockIdx.x * 256 + threadIdx.x;  // 10 * B*NN
  int g = tid / (BB * NN);
  int i = tid % (BB * NN);
  int b = i / NN, n = i % NN;
  const float* xp = x + (size_t)b * CQ * NN + n;
  float xr[CQ];
#pragma unroll
  for (int c = 0; c < CQ; c++)
    xr[c] = fmaxf(fmaf(xp[(size_t)c * NN], AB[c], AB[CQ + c]), 0.f);
  const float* W; const float* bias; float* y; int o0;
  if (g < 2)      { W = bw; bias = bb; y = tb; o0 = g * 16;       }
  else if (g < 6) { W = Wq; bias = bq; y = Q;  o0 = (g - 2) * 16; }
  else            { W = R;  bias = rb; y = Qp; o0 = (g - 6) * 16; }
  int COUTL = (g < 2) ? 32 : CQ;
#pragma unroll
  for (int oo = 0; oo < 16; oo++) {
    int o = o0 + oo;
    float acc = bias[o];
#pragma unroll
    for (int c = 0; c < CQ; c++) acc = fmaf(W[o * CQ + c], xr[c], acc);
    y[((size_t)b * COUTL + o) * NN + n] = acc;
  }
}

// ------- kNN phase A: per-(query, residue) top-16 values + in-wave butterfly merge -> theta -------
__global__ __launch_bounds__(256) void knnA_k(const float* __restrict__ xyz_hr,
    const float* __restrict__ xyzT, float* __restrict__ theta)
{
#pragma clang fp contract(off)
  int tid = blockIdx.x * 256 + threadIdx.x;  // B*N*SPL
  int s = tid & (SPL - 1);
  int qi = tid / SPL;                        // b*NN + n
  int b = qi / NN, n = qi % NN;
  float ax = xyz_hr[(b * 3 + 0) * NN + n];
  float ay = xyz_hr[(b * 3 + 1) * NN + n];
  float az = xyz_hr[(b * 3 + 2) * NN + n];
  float sa = (ax * ax + ay * ay) + az * az;
  const float4* __restrict__ Ps = ((const float4*)xyzT) + (size_t)b * MM + s;
  float dv[16];
#pragma unroll
  for (int j = 0; j < 16; j++) dv[j] = 3.4e38f;
  for (int j = 0; j < MM / SPL; j += 8) {
    float t[8];
#pragma unroll
    for (int u = 0; u < 8; u++) {
      float4 p = Ps[(size_t)(j + u) * SPL];
      t[u] = dist2f(sa, ax, ay, az, p);
    }
    sort8(t);
    merge16_8(dv, t);
  }
  // butterfly merge across the 8 lanes of this query
#pragma unroll
  for (int mask = 1; mask <= 4; mask <<= 1) {
    float c[16];
#pragma unroll
    for (int j = 0; j < 16; j++) c[j] = __shfl_xor(dv[15 - j], mask);
#pragma unroll
    for (int j = 0; j < 16; j++) dv[j] = fminf(dv[j], c[j]);
    bitonic16(dv);
  }
  if (s == 0) theta[qi] = dv[15];
}

// ---- kNN phase C v2: 8 queries/wave, 32 queries/block; each lane loads 1 point and
// ---- evaluates all 8 wave-queries (L2 traffic /8). Then select + moments.
__global__ __launch_bounds__(256) void knnC_k(const float* __restrict__ xyz_hr,
    const float* __restrict__ xyzT, const float* __restrict__ theta,
    int* __restrict__ idx_out, double* __restrict__ mompart)
{
#pragma clang fp contract(off)
  __shared__ int s_clt[32], s_ceq[32];
  __shared__ int s_lt[32][16];
  __shared__ int s_eq[32][64];
  __shared__ int s_sel[32][16];
  __shared__ float s_mom[4][9];
  int w = threadIdx.x >> 6, l = threadIdx.x & 63;
  int qblk = blockIdx.x * 32;                // 32 queries per block, same b (NN%32==0)
  int b = qblk / NN;
  int n0 = qblk % NN + w * 8;                // this wave's 8 queries
  if (threadIdx.x < 32) { s_clt[threadIdx.x] = 0; s_ceq[threadIdx.x] = 0; }
  __syncthreads();
  float qx[8], qy[8], qz[8], qs[8], th[8];
#pragma unroll
  for (int q = 0; q < 8; q++) {
    qx[q] = xyz_hr[(b * 3 + 0) * NN + n0 + q];
    qy[q] = xyz_hr[(b * 3 + 1) * NN + n0 + q];
    qz[q] = xyz_hr[(b * 3 + 2) * NN + n0 + q];
    qs[q] = (qx[q] * qx[q] + qy[q] * qy[q]) + qz[q] * qz[q];
    th[q] = theta[(size_t)b * NN + n0 + q];
  }
  const float4* __restrict__ P = ((const float4*)xyzT) + (size_t)b * MM;
  for (int j = 0; j < MM / 64; j++) {
    int m = j * 64 + l;
    float4 p = P[m];
#pragma unroll
    for (int q = 0; q < 8; q++) {
      float d = (qs[q] + p.w) - 2.0f * ((qx[q] * p.x + qy[q] * p.y) + qz[q] * p.z);
      int qq = w * 8 + q;
      if (d < th[q]) {
        int pos = atomicAdd(&s_clt[qq], 1);
        if (pos < 16) s_lt[qq][pos] = m;
      } else if (d == th[q]) {
        int pos = atomicAdd(&s_ceq[qq], 1);
        if (pos < 64) s_eq[qq][pos] = m;
      }
    }
  }
  __syncthreads();
  // selection: one thread per query
  if (threadIdx.x < 32) {
    int qq = threadIdx.x;
    int clt = s_clt[qq]; if (clt > 16) clt = 16;   // mathematically <= 15
    int ceq = s_ceq[qq]; if (ceq > 64) ceq = 64;
    for (int j = 0; j < clt; j++) s_sel[qq][j] = s_lt[qq][j];
    int need = KK - clt;                            // >= 1, <= ceq
    for (int t = 0; t < need; t++) {
      int best = 0x7fffffff, bp = 0;
      for (int j = 0; j < ceq; j++) { int v = s_eq[qq][j]; if (v < best) { best = v; bp = j; } }
      s_sel[qq][clt + t] = best;
      s_eq[qq][bp] = 0x7fffffff;
    }
    size_t base = ((size_t)qblk + qq) * KK;
    for (int j = 0; j < KK; j++) idx_out[base + j] = s_sel[qq][j];
  }
  __syncthreads();
  // moments of selected rel_pos: 32 queries x 16 neighbors = 512 slots, 2 per thread
  float t9[9];
#pragma unroll
  for (int j = 0; j < 9; j++) t9[j] = 0.f;
  for (int slot = threadIdx.x; slot < 512; slot += 256) {
    int qq = slot >> 4, jj = slot & 15;
    int nn_ = qblk % NN + qq;
    float ax = xyz_hr[(b * 3 + 0) * NN + nn_];
    float ay = xyz_hr[(b * 3 + 1) * NN + nn_];
    float az = xyz_hr[(b * 3 + 2) * NN + nn_];
    float4 p = P[s_sel[qq][jj]];
    float rx = ax - p.x, ry = ay - p.y, rz = az - p.z;
    t9[0] += rx; t9[1] += ry; t9[2] += rz;
    t9[3] += rx * rx; t9[4] += ry * ry; t9[5] += rz * rz;
    t9[6] += rx * ry; t9[7] += rx * rz; t9[8] += ry * rz;
  }
#pragma unroll
  for (int j = 0; j < 9; j++)
    for (int o = 32; o >= 1; o >>= 1) t9[j] += __shfl_down(t9[j], o);
  if (l == 0) { for (int j = 0; j < 9; j++) s_mom[w][j] = t9[j]; }
  __syncthreads();
  if (threadIdx.x == 0) {
    double* op = mompart + (size_t)blockIdx.x * 9;
    for (int j = 0; j < 9; j++)
      op[j] = (double)s_mom[0][j] + (double)s_mom[1][j] + (double)s_mom[2][j] + (double)s_mom[3][j];
  }
}

// -------- moments phase 2: one block reduces partials, finalizes AB2d --------
__global__ __launch_bounds__(256) void mom2_k(const double* __restrict__ part, int nblk,
    const float* __restrict__ w1, const float* __restrict__ b1,
    const float* __restrict__ g, const float* __restrict__ bt, float* __restrict__ AB)
{
  double acc[9];
#pragma unroll
  for (int j = 0; j < 9; j++) acc[j] = 0.0;
  for (int blk = threadIdx.x; blk < nblk; blk += 256) {
    const double* p = part + (size_t)blk * 9;
#pragma unroll
    for (int j = 0; j < 9; j++) acc[j] += p[j];
  }
#pragma unroll
  for (int j = 0; j < 9; j++)
    for (int o = 32; o >= 1; o >>= 1) acc[j] += __shfl_down(acc[j], o);
  __shared__ double sh[4][9];
  __shared__ double mo[9];
  int w = threadIdx.x >> 6, l = threadIdx.x & 63;
  if (l == 0) { for (int j = 0; j < 9; j++) sh[w][j] = acc[j]; }
  __syncthreads();
  if (threadIdx.x == 0) {
    for (int wv = 1; wv < 4; wv++) for (int j = 0; j < 9; j++) sh[0][j] += sh[wv][j];
    for (int j = 0; j < 9; j++) mo[j] = sh[0][j];
  }
  __syncthreads();
  if (threadIdx.x < CQ) {
    int c = threadIdx.x;
    double cnt = (double)BB * NN * KK;
    double mx = mo[0]/cnt, my = mo[1]/cnt, mz = mo[2]/cnt;
    double cxx = mo[3]/cnt - mx*mx, cyy = mo[4]/cnt - my*my, czz = mo[5]/cnt - mz*mz;
    double cxy = mo[6]/cnt - mx*my, cxz = mo[7]/cnt - mx*mz, cyz = mo[8]/cnt - my*mz;
    double wx = w1[c*3], wy = w1[c*3+1], wz = w1[c*3+2];
    double mean = wx*mx + wy*my + wz*mz + (double)b1[c];
    double var = wx*wx*cxx + wy*wy*cyy + wz*wz*czz + 2.0*(wx*wy*cxy + wx*wz*cxz + wy*wz*cyz);
    double A = (double)g[c] / sqrt(var + EPSV);
    AB[c] = (float)A;
    AB[CQ + c] = (float)((double)bt[c] - mean * A);
  }
}

// ---------------- fused pos-enc + attention + output (+ boundary head blocks) ----------------
__global__ __launch_bounds__(256) void attn_k(
    const float* __restrict__ Q, const float* __restrict__ Qp,
    const float* __restrict__ KfT, const int* __restrict__ idxb,
    const float* __restrict__ xyzT, const float* __restrict__ valT,
    const float* __restrict__ xyz_hr, const float* __restrict__ AB,
    const float* __restrict__ w1, const float* __restrict__ b1,
    const float* __restrict__ b2, float* __restrict__ out,
    const float* __restrict__ tb, const float* __restrict__ ABb,
    const float* __restrict__ bhw2, const float* __restrict__ bhb2)
{
  __shared__ float q_s[CQ * 16], qp_s[CQ * 16];
  if (blockIdx.x >= 2048) {          // boundary-head blocks
    int i = (blockIdx.x - 2048) * 256 + threadIdx.x;  // B*N
    int b = i / NN, n = i % NN;
    float acc = bhb2[0];
#pragma unroll
    for (int c = 0; c < 32; c++) {
      float v = tb[((size_t)b * 32 + c) * NN + n];
      v = fmaxf(fmaf(v, ABb[c], ABb[32 + c]), 0.f);
      acc = fmaf(bhw2[c], v, acc);
    }
    out[(size_t)BB * 6 * NN + i] = 1.f / (1.f + expf(-acc));
    return;
  }
  const int ngrp = NN / 16;
  int b = blockIdx.x / ngrp;
  int n0 = (blockIdx.x % ngrp) * 16;
  for (int t = threadIdx.x; t < CQ * 16; t += 256) {
    int c = t >> 4, j = t & 15;
    q_s[t]  = Q [((size_t)b * CQ + c) * NN + n0 + j];
    qp_s[t] = Qp[((size_t)b * CQ + c) * NN + n0 + j];
  }
  __syncthreads();
  int q = threadIdx.x >> 4, k = threadIdx.x & 15;
  int n = n0 + q;
  int id = idxb[((size_t)b * NN + n) * KK + k];
  float ax = xyz_hr[(b * 3 + 0) * NN + n];
  float ay = xyz_hr[(b * 3 + 1) * NN + n];
  float az = xyz_hr[(b * 3 + 2) * NN + n];
  float4 pl = ((const float4*)xyzT)[(size_t)b * MM + id];
  float rx = ax - pl.x, ry = ay - pl.y, rz = az - pl.z;
  const float4* kg = (const float4*)(KfT + ((size_t)b * MM + id) * CQ);
  float s = 0.f;
#pragma unroll
  for (int c4 = 0; c4 < CQ / 4; c4++) {
    float4 g4 = kg[c4];
    float ga[4] = {g4.x, g4.y, g4.z, g4.w};
#pragma unroll
    for (int u = 0; u < 4; u++) {
      int c = 4 * c4 + u;
      float t0 = fmaf(w1[c * 3 + 0], rx, fmaf(w1[c * 3 + 1], ry, w1[c * 3 + 2] * rz)) + b1[c];
      float pe = fmaxf(fmaf(t0, AB[c], AB[CQ + c]), 0.f);
      s = fmaf(q_s[c * 16 + q], ga[u] + b2[c], s);
      s = fmaf(qp_s[c * 16 + q], pe, s);
    }
  }
  s *= 0.125f;  // /sqrt(64)
  float mx = s;
#pragma unroll
  for (int o = 8; o >= 1; o >>= 1) mx = fmaxf(mx, __shfl_xor(mx, o, 16));
  float p = expf(s - mx);
  float sum = p;
#pragma unroll
  for (int o = 8; o >= 1; o >>= 1) sum += __shfl_xor(sum, o, 16);
  float attn = p / sum;
  const float4* vt = (const float4*)(valT + ((size_t)b * MM + id) * 8);
  float4 va = vt[0], vb = vt[1];
  float oc[6] = {attn*va.x, attn*va.y, attn*va.z, attn*va.w, attn*vb.x, attn*vb.y};
#pragma unroll
  for (int c = 0; c < 6; c++) {
    float a = oc[c];
#pragma unroll
    for (int o = 8; o >= 1; o >>= 1) a += __shfl_xor(a, o, 16);
    oc[c] = a;
  }
  if (k == 0) {
#pragma unroll
    for (int c = 0; c < 6; c++) out[((size_t)b * 6 + c) * NN + n] = oc[c];
  }
}

extern "C" void kernel_launch(void* const* d_in, const int* in_sizes, int n_in,
                              void* d_out, int out_size, void* d_ws, size_t ws_size,
                              hipStream_t stream)
{
  const float* xyz_hr = (const float*)d_in[0];
  const float* xyz_lr = (const float*)d_in[1];
  const float* val_lr = (const float*)d_in[2];
  const float* feat_hr= (const float*)d_in[3];
  const float* feat_lr= (const float*)d_in[4];
  const float* ge_w1 = (const float*)d_in[5];
  const float* ge_b1 = (const float*)d_in[6];
  const float* ge_g1 = (const float*)d_in[7];
  const float* ge_bt1= (const float*)d_in[8];
  const float* ge_w2 = (const float*)d_in[9];
  const float* ge_b2 = (const float*)d_in[10];
  const float* ge_g2 = (const float*)d_in[11];
  const float* ge_bt2= (const float*)d_in[12];
  const float* sc_w = (const float*)d_in[13];
  const float* sc_b = (const float*)d_in[14];
  const float* sh_w = (const float*)d_in[15];
  const float* sh_b = (const float*)d_in[16];
  const float* q_w  = (const float*)d_in[17];
  const float* q_b  = (const float*)d_in[18];
  const float* k_w  = (const float*)d_in[19];
  const float* k_b  = (const float*)d_in[20];
  const float* bh_w1= (const float*)d_in[21];
  const float* bh_b1= (const float*)d_in[22];
  const float* bh_g = (const float*)d_in[23];
  const float* bh_bt= (const float*)d_in[24];
  const float* bh_w2= (const float*)d_in[25];
  const float* bh_b2= (const float*)d_in[26];
  const float* rp_w1= (const float*)d_in[27];
  const float* rp_b1= (const float*)d_in[28];
  const float* rp_g = (const float*)d_in[29];
  const float* rp_bt= (const float*)d_in[30];
  const float* rp_w2= (const float*)d_in[31];
  const float* rp_b2= (const float*)d_in[32];
  float* out = (float*)d_out;

  // ---- scratch header (zeroed by init_k block 32): [0,96) pad | ctrs 6 ints | sums 5*128 dbl ----
  int*    hdr  = (int*)d_ws;
  int*    ctrs = (int*)((char*)d_ws + 96);            // 6 ints
  double* sums = (double*)((char*)d_ws + 128);        // 5 * 128 doubles
  float*  base = (float*)((char*)d_ws + 5504);
  float* AB1h = base;          // 128
  float* AB2h = base + 128;    // 128
  float* AB1l = base + 256;    // 128
  float* AB2l = base + 384;    // 128
  float* ABb  = base + 512;    // 64
  float* AB2d = base + 576;    // 128
  float* big  = base + 768;
  float* t1_hr = big;                      // 2*64*16384
  float* t2_hr = t1_hr + 2097152;
  float* Qb    = t2_hr + 2097152;
  float* Qp    = Qb    + 2097152;
  float* t1_lr = Qp    + 2097152;          // 2*64*4096
  float* t2_lr = t1_lr + 524288;
  float* Rbuf  = t2_lr + 524288;           // 4096 R + 64 rb
  float* KfT   = Rbuf  + 524288;           // [B,M,64]
  float* tb    = KfT   + 524288;           // 2*32*16384
  float* xyzT  = tb    + 1048576;          // [B,M,4]
  float* valT  = xyzT  + 32768;            // [B,M,8]
  int*   idxb  = (int*)(valT + 65536);     // 2*16384*16
  // kNN scratch overlays conv temporaries (consumed before conv pipeline):
  float* theta = Qb;                       // B*N floats
  double* mompart = (double*)Qp;           // 1024*9 doubles (Qp free until convbqq)
  float* Rw    = Rbuf;                     // effective Qp weights
  float* rbv   = Rbuf + 4096;

  init_k<<<33, 256, 0, stream>>>(xyz_lr, val_lr, xyzT, valT, q_w, q_b, rp_w2, Rw, rbv, hdr);

  // ---- kNN ----
  knnA_k<<<(BB * NN * SPL) / 256, 256, 0, stream>>>(xyz_hr, xyzT, theta);
  knnC_k<<<(BB * NN) / 32, 256, 0, stream>>>(xyz_hr, xyzT, theta, idxb, mompart);
  mom2_k<<<1, 256, 0, stream>>>(mompart, (BB * NN) / 32, rp_w1, rp_b1, rp_g, rp_bt, AB2d);

  // ---- encoder pipeline ----
  convhl_k<GEOC, CQ, 16><<<640, 256, 0, stream>>>(feat_hr, feat_lr, ge_w1, ge_b1,
                                                  nullptr, nullptr, t1_hr, t1_lr, 512);
  statshl_k<CQ, 8><<<1024, 256, 0, stream>>>(t1_hr, NN, t1_lr, MM, ge_g1, ge_bt1,
                                             sums, ctrs + 0, AB1h, AB1l);
  convhl_k<CQ, CQ, 16><<<640, 256, 0, stream>>>(t1_hr, t1_lr, ge_w2, ge_b2,
                                                AB1h, AB1l, t2_hr, t2_lr, 512);
  statshl_k<CQ, 8><<<1024, 256, 0, stream>>>(t2_hr, NN, t2_lr, MM, ge_g2, ge_bt2,
                                             sums + 256, ctrs + 2, AB2h, AB2l);

  fk_k<<<256, 256, 0, stream>>>(t2_lr, AB2l, val_lr, sc_w, sc_b, sh_w, sh_b,
                                k_w, k_b, KfT);

  convbqq_k<<<1280, 256, 0, stream>>>(t2_hr, bh_w1, bh_b1, q_w, q_b, Rw, rbv,
                                      AB2h, tb, Qb, Qp);
  statsone_k<32, 8><<<256, 256, 0, stream>>>(tb, NN, bh_g, bh_bt, sums + 512, ctrs + 4, ABb);

  attn_k<<<2048 + 128, 256, 0, stream>>>(Qb, Qp, KfT, idxb, xyzT, valT, xyz_hr, AB2d,
                                         rp_w1, rp_b1, rp_b2, out, tb, ABb, bh_w2, bh_b2);
}

// Round 12
// 463.427 us; speedup vs baseline: 6.0083x; 1.1456x over previous
//
#include <hip/hip_runtime.h>

#define BB 2
#define NN 16384
#define MM 4096
#define KK 16
#define CQ 64
#define GEOC 18
#define EPSV 1e-5
#define SPL 8   // M-split per query for kNN phase A

// exact numpy-order fp32 squared distance; contract(off) so bits are identical
// in every kernel that evaluates it.
__device__ __forceinline__ float dist2f(float sa, float ax, float ay, float az, float4 p) {
#pragma clang fp contract(off)
  return (sa + p.w) - 2.0f * ((ax * p.x + ay * p.y) + az * p.z);
}

__device__ __forceinline__ void ce(float& a, float& b) {
  float lo = fminf(a, b), hi = fmaxf(a, b); a = lo; b = hi;
}
__device__ __forceinline__ void sort8(float* v) {
  ce(v[0],v[1]); ce(v[2],v[3]); ce(v[4],v[5]); ce(v[6],v[7]);
  ce(v[0],v[2]); ce(v[1],v[3]); ce(v[4],v[6]); ce(v[5],v[7]);
  ce(v[1],v[2]); ce(v[5],v[6]);
  ce(v[0],v[4]); ce(v[1],v[5]); ce(v[2],v[6]); ce(v[3],v[7]);
  ce(v[2],v[4]); ce(v[3],v[5]);
  ce(v[1],v[2]); ce(v[3],v[4]); ce(v[5],v[6]);
}
__device__ __forceinline__ void bitonic16(float* v) {
#pragma unroll
  for (int i = 0; i < 8; i++) ce(v[i], v[i + 8]);
  ce(v[0],v[4]); ce(v[1],v[5]); ce(v[2],v[6]); ce(v[3],v[7]);
  ce(v[8],v[12]); ce(v[9],v[13]); ce(v[10],v[14]); ce(v[11],v[15]);
  ce(v[0],v[2]); ce(v[1],v[3]); ce(v[4],v[6]); ce(v[5],v[7]);
  ce(v[8],v[10]); ce(v[9],v[11]); ce(v[12],v[14]); ce(v[13],v[15]);
  ce(v[0],v[1]); ce(v[2],v[3]); ce(v[4],v[5]); ce(v[6],v[7]);
  ce(v[8],v[9]); ce(v[10],v[11]); ce(v[12],v[13]); ce(v[14],v[15]);
}
__device__ __forceinline__ void merge16_8(float* dv, const float* t) {
  dv[8]  = fminf(dv[8],  t[7]);  dv[9]  = fminf(dv[9],  t[6]);
  dv[10] = fminf(dv[10], t[5]);  dv[11] = fminf(dv[11], t[4]);
  dv[12] = fminf(dv[12], t[3]);  dv[13] = fminf(dv[13], t[2]);
  dv[14] = fminf(dv[14], t[1]);  dv[15] = fminf(dv[15], t[0]);
  bitonic16(dv);
}

// ------- init: transpose lr points/values, effective Qp weights R/rb, zero stats header -------
__global__ __launch_bounds__(256) void init_k(const float* __restrict__ xyz,
    const float* __restrict__ val, float* __restrict__ xyzT, float* __restrict__ valT,
    const float* __restrict__ qw, const float* __restrict__ qb, const float* __restrict__ w2,
    float* __restrict__ R, float* __restrict__ rb, int* __restrict__ hdr)
{
#pragma clang fp contract(off)
  if (blockIdx.x < 32) {
    int i = blockIdx.x * 256 + threadIdx.x;  // B*M
    int b = i / MM, m = i % MM;
    float x = xyz[(b * 3 + 0) * MM + m];
    float y = xyz[(b * 3 + 1) * MM + m];
    float z = xyz[(b * 3 + 2) * MM + m];
    float sb = (x * x + y * y) + z * z;      // exact numpy order
    ((float4*)xyzT)[i] = make_float4(x, y, z, sb);
    float v0 = val[((size_t)b * 6 + 0) * MM + m];
    float v1 = val[((size_t)b * 6 + 1) * MM + m];
    float v2 = val[((size_t)b * 6 + 2) * MM + m];
    float v3 = val[((size_t)b * 6 + 3) * MM + m];
    float v4 = val[((size_t)b * 6 + 4) * MM + m];
    float v5 = val[((size_t)b * 6 + 5) * MM + m];
    ((float4*)valT)[2 * i]     = make_float4(v0, v1, v2, v3);
    ((float4*)valT)[2 * i + 1] = make_float4(v4, v5, 0.f, 0.f);
  } else {
    int t = threadIdx.x;
    for (int wd = t; wd < 1376; wd += 256) hdr[wd] = 0;   // ctrs + sums region
#pragma unroll
    for (int e = t * 16; e < t * 16 + 16; e++) {          // R = rp_w2^T * q_w
      int o = e >> 6, i = e & 63;
      float acc = 0.f;
#pragma unroll
      for (int p = 0; p < CQ; p++) acc = fmaf(w2[p * CQ + o], qw[p * CQ + i], acc);
      R[e] = acc;
    }
    if (t < CQ) {
      float a = 0.f;
#pragma unroll
      for (int p = 0; p < CQ; p++) a = fmaf(w2[p * CQ + t], qb[p], a);
      rb[t] = a;
    }
  }
}

// ---- knnA body: per-(query, residue) top-16 values + in-wave butterfly merge -> theta ----
__device__ __forceinline__ void knnA_body(int tid, const float* __restrict__ xyz_hr,
    const float* __restrict__ xyzT, float* __restrict__ theta)
{
#pragma clang fp contract(off)
  int s = tid & (SPL - 1);
  int qi = tid / SPL;                        // b*NN + n
  int b = qi / NN, n = qi % NN;
  float ax = xyz_hr[(b * 3 + 0) * NN + n];
  float ay = xyz_hr[(b * 3 + 1) * NN + n];
  float az = xyz_hr[(b * 3 + 2) * NN + n];
  float sa = (ax * ax + ay * ay) + az * az;
  const float4* __restrict__ Ps = ((const float4*)xyzT) + (size_t)b * MM + s;
  float dv[16];
#pragma unroll
  for (int j = 0; j < 16; j++) dv[j] = 3.4e38f;
  for (int j = 0; j < MM / SPL; j += 8) {
    float t[8];
#pragma unroll
    for (int u = 0; u < 8; u++) {
      float4 p = Ps[(size_t)(j + u) * SPL];
      t[u] = dist2f(sa, ax, ay, az, p);
    }
    sort8(t);
    merge16_8(dv, t);
  }
#pragma unroll
  for (int mask = 1; mask <= 4; mask <<= 1) {
    float c[16];
#pragma unroll
    for (int j = 0; j < 16; j++) c[j] = __shfl_xor(dv[15 - j], mask);
#pragma unroll
    for (int j = 0; j < 16; j++) dv[j] = fminf(dv[j], c[j]);
    bitonic16(dv);
  }
  if (s == 0) theta[qi] = dv[15];
}

// ---- fused hr+lr conv (COUT=64, 16 out/thread) + BN stats (block LDS reduce ->
// ---- spread double atomics -> counter last-block finalize to (A,B) pairs) ----
template<int CIN>
__device__ __forceinline__ void convstats_hl(int cbid,
    const float* __restrict__ xh, const float* __restrict__ xl,
    const float* __restrict__ W, const float* __restrict__ bias,
    const float* __restrict__ ABh_in, const float* __restrict__ ABl_in,
    float* __restrict__ yh, float* __restrict__ yl,
    double* __restrict__ sums, int* __restrict__ ctr,
    const float* __restrict__ gw, const float* __restrict__ btw,
    float* __restrict__ ABh_out, float* __restrict__ ABl_out,
    float* red, int* plastf)
{
  bool ish = cbid < 512;
  const float* x = ish ? xh : xl;
  const float* ABi = ish ? ABh_in : ABl_in;
  float* y = ish ? yh : yl;
  int L = ish ? NN : MM;
  int lb = ish ? cbid : cbid - 512;
  int tid = lb * 256 + threadIdx.x;
  int g = tid / (BB * L);                    // uniform per block
  int i = tid % (BB * L);
  int b = i / L, n = i % L;
  const float* xp = x + (size_t)b * CIN * L + n;
  float xr[CIN];
#pragma unroll
  for (int c = 0; c < CIN; c++) {
    float v = xp[(size_t)c * L];
    if (ABi) v = fmaxf(fmaf(v, ABi[c], ABi[CIN + c]), 0.f);
    xr[c] = v;
  }
  float acc[16];
#pragma unroll
  for (int oo = 0; oo < 16; oo++) {
    int o = g * 16 + oo;
    float a = bias[o];
#pragma unroll
    for (int c = 0; c < CIN; c++) a = fmaf(W[(size_t)o * CIN + c], xr[c], a);
    acc[oo] = a;
    y[((size_t)b * CQ + o) * L + n] = a;
  }
  // block stats reduce via LDS
#pragma unroll
  for (int oo = 0; oo < 16; oo++) red[oo * 257 + threadIdx.x] = acc[oo];
  __syncthreads();
  float* r2 = red + 16 * 257;
  int t = threadIdx.x;
  if (t < 128) {
    int oo = t >> 3, seg = t & 7;
    float s = 0.f, ss = 0.f;
    for (int j = seg * 32; j < seg * 32 + 32; j++) {
      float v = red[oo * 257 + j]; s += v; ss += v * v;
    }
    r2[(oo * 8 + seg) * 2] = s; r2[(oo * 8 + seg) * 2 + 1] = ss;
  }
  __syncthreads();
  if (t < 16) {
    double s = 0.0, ss = 0.0;
    for (int j = 0; j < 8; j++) { s += r2[(t * 8 + j) * 2]; ss += r2[(t * 8 + j) * 2 + 1]; }
    int c = g * 16 + t;
    int base = ish ? 0 : 128;
    atomicAdd(&sums[base + c], s);
    atomicAdd(&sums[base + 64 + c], ss);
  }
  __syncthreads();   // drains vmem: the stats atomics are device-visible
  if (t == 0) {
    __threadfence();
    int old = atomicAdd(ctr, 1);
    *plastf = (old == 640 - 1) ? 1 : 0;
  }
  __syncthreads();
  if (*plastf && t < 128) {
    bool fh = t < 64;
    int c = fh ? t : t - 64;
    int base = fh ? 0 : 128;
    double S  = atomicAdd(&sums[base + c], 0.0);
    double SS = atomicAdd(&sums[base + 64 + c], 0.0);
    double nn2 = (double)BB * (fh ? NN : MM);
    double mean = S / nn2, var = SS / nn2 - mean * mean;
    double A = (double)gw[c] / sqrt(var + EPSV);
    float* ABo = fh ? ABh_out : ABl_out;
    ABo[c] = (float)A;
    ABo[64 + c] = (float)((double)btw[c] - mean * A);
  }
}

// ---------------- K2: knnA (blocks 0..1023)  ||  conv1+stats (blocks 1024..1663) ----------------
__global__ __launch_bounds__(256) void k2_k(const float* __restrict__ xyz_hr,
    const float* __restrict__ xyzT, float* __restrict__ theta,
    const float* __restrict__ feat_hr, const float* __restrict__ feat_lr,
    const float* __restrict__ w1, const float* __restrict__ b1,
    double* __restrict__ sums, int* __restrict__ ctr,
    const float* __restrict__ gw, const float* __restrict__ btw,
    float* __restrict__ t1h, float* __restrict__ t1l,
    float* __restrict__ AB1h, float* __restrict__ AB1l)
{
  __shared__ __align__(16) float smem[16 * 257 + 256];
  __shared__ int lastf;
  if (blockIdx.x < 1024) {
    knnA_body(blockIdx.x * 256 + threadIdx.x, xyz_hr, xyzT, theta);
  } else {
    convstats_hl<GEOC>(blockIdx.x - 1024, feat_hr, feat_lr, w1, b1, nullptr, nullptr,
                       t1h, t1l, sums, ctr, gw, btw, AB1h, AB1l, smem, &lastf);
  }
}

// ---- knnC body: 8 queries/wave, 32/block; collect idx (d<th; ties==th by asc idx) + moments ----
__device__ __forceinline__ void knnC_body(int cbid, const float* __restrict__ xyz_hr,
    const float* __restrict__ xyzT, const float* __restrict__ theta,
    int* __restrict__ idx_out, double* __restrict__ mompart, float* smemf)
{
#pragma clang fp contract(off)
  int* s_clt = (int*)smemf;            // 32
  int* s_ceq = s_clt + 32;             // 32
  int* s_lt  = s_ceq + 32;             // 32*16
  int* s_eq  = s_lt + 512;             // 32*64
  int* s_sel = s_eq + 2048;            // 32*16
  float* s_mom = (float*)(s_sel + 512);// 4*9
  int w = threadIdx.x >> 6, l = threadIdx.x & 63;
  int qblk = cbid * 32;
  int b = qblk / NN;
  int n0 = qblk % NN + w * 8;
  if (threadIdx.x < 32) { s_clt[threadIdx.x] = 0; s_ceq[threadIdx.x] = 0; }
  __syncthreads();
  float qx[8], qy[8], qz[8], qs[8], th[8];
#pragma unroll
  for (int q = 0; q < 8; q++) {
    qx[q] = xyz_hr[(b * 3 + 0) * NN + n0 + q];
    qy[q] = xyz_hr[(b * 3 + 1) * NN + n0 + q];
    qz[q] = xyz_hr[(b * 3 + 2) * NN + n0 + q];
    qs[q] = (qx[q] * qx[q] + qy[q] * qy[q]) + qz[q] * qz[q];
    th[q] = theta[(size_t)b * NN + n0 + q];
  }
  const float4* __restrict__ P = ((const float4*)xyzT) + (size_t)b * MM;
  for (int j = 0; j < MM / 64; j++) {
    int m = j * 64 + l;
    float4 p = P[m];
#pragma unroll
    for (int q = 0; q < 8; q++) {
      float d = (qs[q] + p.w) - 2.0f * ((qx[q] * p.x + qy[q] * p.y) + qz[q] * p.z);
      int qq = w * 8 + q;
      if (d < th[q]) {
        int pos = atomicAdd(&s_clt[qq], 1);
        if (pos < 16) s_lt[qq * 16 + pos] = m;
      } else if (d == th[q]) {
        int pos = atomicAdd(&s_ceq[qq], 1);
        if (pos < 64) s_eq[qq * 64 + pos] = m;
      }
    }
  }
  __syncthreads();
  if (threadIdx.x < 32) {
    int qq = threadIdx.x;
    int clt = s_clt[qq]; if (clt > 16) clt = 16;
    int ceq = s_ceq[qq]; if (ceq > 64) ceq = 64;
    for (int j = 0; j < clt; j++) s_sel[qq * 16 + j] = s_lt[qq * 16 + j];
    int need = KK - clt;
    for (int t = 0; t < need; t++) {
      int best = 0x7fffffff, bp = 0;
      for (int j = 0; j < ceq; j++) { int v = s_eq[qq * 64 + j]; if (v < best) { best = v; bp = j; } }
      s_sel[qq * 16 + clt + t] = best;
      s_eq[qq * 64 + bp] = 0x7fffffff;
    }
    size_t base = ((size_t)qblk + qq) * KK;
    for (int j = 0; j < KK; j++) idx_out[base + j] = s_sel[qq * 16 + j];
  }
  __syncthreads();
  float t9[9];
#pragma unroll
  for (int j = 0; j < 9; j++) t9[j] = 0.f;
  for (int slot = threadIdx.x; slot < 512; slot += 256) {
    int qq = slot >> 4, jj = slot & 15;
    int nn_ = qblk % NN + qq;
    float ax = xyz_hr[(b * 3 + 0) * NN + nn_];
    float ay = xyz_hr[(b * 3 + 1) * NN + nn_];
    float az = xyz_hr[(b * 3 + 2) * NN + nn_];
    float4 p = P[s_sel[qq * 16 + jj]];
    float rx = ax - p.x, ry = ay - p.y, rz = az - p.z;
    t9[0] += rx; t9[1] += ry; t9[2] += rz;
    t9[3] += rx * rx; t9[4] += ry * ry; t9[5] += rz * rz;
    t9[6] += rx * ry; t9[7] += rx * rz; t9[8] += ry * rz;
  }
#pragma unroll
  for (int j = 0; j < 9; j++)
    for (int o = 32; o >= 1; o >>= 1) t9[j] += __shfl_down(t9[j], o);
  if (l == 0) { for (int j = 0; j < 9; j++) s_mom[w * 9 + j] = t9[j]; }
  __syncthreads();
  if (threadIdx.x == 0) {
    double* op = mompart + (size_t)cbid * 9;
    for (int j = 0; j < 9; j++)
      op[j] = (double)s_mom[j] + (double)s_mom[9 + j] + (double)s_mom[18 + j] + (double)s_mom[27 + j];
  }
}

// ---------------- K3: knnC (blocks 0..1023)  ||  conv2+stats (blocks 1024..1663) ----------------
__global__ __launch_bounds__(256) void k3_k(const float* __restrict__ xyz_hr,
    const float* __restrict__ xyzT, const float* __restrict__ theta,
    int* __restrict__ idxb, double* __restrict__ mompart,
    const float* __restrict__ t1h, const float* __restrict__ t1l,
    const float* __restrict__ w2, const float* __restrict__ b2,
    const float* __restrict__ AB1h, const float* __restrict__ AB1l,
    double* __restrict__ sums, int* __restrict__ ctr,
    const float* __restrict__ gw, const float* __restrict__ btw,
    float* __restrict__ t2h, float* __restrict__ t2l,
    float* __restrict__ AB2h, float* __restrict__ AB2l)
{
  __shared__ __align__(16) float smem[16 * 257 + 256];
  __shared__ int lastf;
  if (blockIdx.x < 1024) {
    knnC_body(blockIdx.x, xyz_hr, xyzT, theta, idxb, mompart, smem);
  } else {
    convstats_hl<CQ>(blockIdx.x - 1024, t1h, t1l, w2, b2, AB1h, AB1l,
                     t2h, t2l, sums, ctr, gw, btw, AB2h, AB2l, smem, &lastf);
  }
}

// ---- mom2 body: reduce 1024 partials, finalize AB2d ----
__device__ __forceinline__ void mom2_body(const double* __restrict__ part, int nblk,
    const float* __restrict__ w1, const float* __restrict__ b1,
    const float* __restrict__ g, const float* __restrict__ bt, float* __restrict__ AB,
    float* smemf)
{
  double* sh = (double*)smemf;        // 4*9
  double* mo = sh + 36;               // 9
  double acc[9];
#pragma unroll
  for (int j = 0; j < 9; j++) acc[j] = 0.0;
  for (int blk = threadIdx.x; blk < nblk; blk += 256) {
    const double* p = part + (size_t)blk * 9;
#pragma unroll
    for (int j = 0; j < 9; j++) acc[j] += p[j];
  }
#pragma unroll
  for (int j = 0; j < 9; j++)
    for (int o = 32; o >= 1; o >>= 1) acc[j] += __shfl_down(acc[j], o);
  int w = threadIdx.x >> 6, l = threadIdx.x & 63;
  if (l == 0) { for (int j = 0; j < 9; j++) sh[w * 9 + j] = acc[j]; }
  __syncthreads();
  if (threadIdx.x == 0) {
    for (int j = 0; j < 9; j++) mo[j] = sh[j] + sh[9 + j] + sh[18 + j] + sh[27 + j];
  }
  __syncthreads();
  if (threadIdx.x < CQ) {
    int c = threadIdx.x;
    double cnt = (double)BB * NN * KK;
    double mx = mo[0]/cnt, my = mo[1]/cnt, mz = mo[2]/cnt;
    double cxx = mo[3]/cnt - mx*mx, cyy = mo[4]/cnt - my*my, czz = mo[5]/cnt - mz*mz;
    double cxy = mo[6]/cnt - mx*my, cxz = mo[7]/cnt - mx*mz, cyz = mo[8]/cnt - my*mz;
    double wx = w1[c*3], wy = w1[c*3+1], wz = w1[c*3+2];
    double mean = wx*mx + wy*my + wz*mz + (double)b1[c];
    double var = wx*wx*cxx + wy*wy*cyy + wz*wz*czz + 2.0*(wx*wy*cxy + wx*wz*cxz + wy*wz*cyz);
    double A = (double)g[c] / sqrt(var + EPSV);
    AB[c] = (float)A;
    AB[CQ + c] = (float)((double)bt[c] - mean * A);
  }
}

// ---- fk body: fused FiLM + K-conv (4 groups x 16 outputs) ----
__device__ __forceinline__ void fk_body(int fb, const float* __restrict__ t2l,
    const float* __restrict__ ABl, const float* __restrict__ val,
    const float* __restrict__ scw, const float* __restrict__ scb,
    const float* __restrict__ shw, const float* __restrict__ shb,
    const float* __restrict__ kw, const float* __restrict__ kb,
    float* __restrict__ KfT)
{
  int tid = fb * 256 + threadIdx.x;  // B*M*4
  int g = tid & 3;
  int i = tid >> 2;                  // b*M + m
  int b = i / MM, m = i % MM;
  float v6[6];
#pragma unroll
  for (int j = 0; j < 6; j++) v6[j] = val[((size_t)b * 6 + j) * MM + m];
  float xr[CQ];
#pragma unroll
  for (int c = 0; c < CQ; c++) {
    float gv = fmaxf(fmaf(t2l[((size_t)b * CQ + c) * MM + m], ABl[c], ABl[CQ + c]), 0.f);
    float sc = scb[c], sh = shb[c];
#pragma unroll
    for (int j = 0; j < 6; j++) {
      sc = fmaf(scw[c * 6 + j], v6[j], sc);
      sh = fmaf(shw[c * 6 + j], v6[j], sh);
    }
    xr[c] = fmaf(gv, 1.f + sc, sh);
  }
#pragma unroll
  for (int oo = 0; oo < 16; oo++) {
    int o = g * 16 + oo;
    float acc = kb[o];
#pragma unroll
    for (int c = 0; c < CQ; c++) acc = fmaf(kw[o * CQ + c], xr[c], acc);
    KfT[(size_t)i * CQ + o] = acc;
  }
}

// ---- convbqq body + stats on tb channels (g<2), counter target 256 ----
__device__ __forceinline__ void convbqq_body(int cb, const float* __restrict__ x,
    const float* __restrict__ bw, const float* __restrict__ bb,
    const float* __restrict__ Wq, const float* __restrict__ bq,
    const float* __restrict__ R, const float* __restrict__ rb,
    const float* __restrict__ AB, float* __restrict__ tb,
    float* __restrict__ Q, float* __restrict__ Qp,
    double* __restrict__ sums, int* __restrict__ ctr,
    const float* __restrict__ gw, const float* __restrict__ btw,
    float* __restrict__ ABb, float* red, int* plastf)
{
  int tid = cb * 256 + threadIdx.x;  // 10 * B*NN
  int g = tid / (BB * NN);           // uniform per block
  int i = tid % (BB * NN);
  int b = i / NN, n = i % NN;
  const float* xp = x + (size_t)b * CQ * NN + n;
  float xr[CQ];
#pragma unroll
  for (int c = 0; c < CQ; c++)
    xr[c] = fmaxf(fmaf(xp[(size_t)c * NN], AB[c], AB[CQ + c]), 0.f);
  const float* W; const float* bias; float* y; int o0; int COUTL;
  if (g < 2)      { W = bw; bias = bb; y = tb; o0 = g * 16;       COUTL = 32; }
  else if (g < 6) { W = Wq; bias = bq; y = Q;  o0 = (g - 2) * 16; COUTL = CQ; }
  else            { W = R;  bias = rb; y = Qp; o0 = (g - 6) * 16; COUTL = CQ; }
  float acc[16];
#pragma unroll
  for (int oo = 0; oo < 16; oo++) {
    int o = o0 + oo;
    float a = bias[o];
#pragma unroll
    for (int c = 0; c < CQ; c++) a = fmaf(W[o * CQ + c], xr[c], a);
    acc[oo] = a;
    y[((size_t)b * COUTL + o) * NN + n] = a;
  }
  if (g >= 2) return;
  // stats on boundary-head pre-activations
#pragma unroll
  for (int oo = 0; oo < 16; oo++) red[oo * 257 + threadIdx.x] = acc[oo];
  __syncthreads();
  float* r2 = red + 16 * 257;
  int t = threadIdx.x;
  if (t < 128) {
    int oo = t >> 3, seg = t & 7;
    float s = 0.f, ss = 0.f;
    for (int j = seg * 32; j < seg * 32 + 32; j++) {
      float v = red[oo * 257 + j]; s += v; ss += v * v;
    }
    r2[(oo * 8 + seg) * 2] = s; r2[(oo * 8 + seg) * 2 + 1] = ss;
  }
  __syncthreads();
  if (t < 16) {
    double s = 0.0, ss = 0.0;
    for (int j = 0; j < 8; j++) { s += r2[(t * 8 + j) * 2]; ss += r2[(t * 8 + j) * 2 + 1]; }
    int c = g * 16 + t;
    atomicAdd(&sums[c], s);
    atomicAdd(&sums[32 + c], ss);
  }
  __syncthreads();
  if (t == 0) {
    __threadfence();
    int old = atomicAdd(ctr, 1);
    *plastf = (old == 256 - 1) ? 1 : 0;
  }
  __syncthreads();
  if (*plastf && t < 32) {
    int c = t;
    double S  = atomicAdd(&sums[c], 0.0);
    double SS = atomicAdd(&sums[32 + c], 0.0);
    double nn2 = (double)BB * NN;
    double mean = S / nn2, var = SS / nn2 - mean * mean;
    double A = (double)gw[c] / sqrt(var + EPSV);
    ABb[c] = (float)A;
    ABb[32 + c] = (float)((double)btw[c] - mean * A);
  }
}

// ---------------- K4: mom2 (block 0) || fk (1..128) || convbqq+stats (129..1408) ----------------
__global__ __launch_bounds__(256) void k4_k(
    const double* __restrict__ mompart,
    const float* __restrict__ rp_w1, const float* __restrict__ rp_b1,
    const float* __restrict__ rp_g, const float* __restrict__ rp_bt, float* __restrict__ AB2d,
    const float* __restrict__ t2l, const float* __restrict__ AB2l, const float* __restrict__ val,
    const float* __restrict__ scw, const float* __restrict__ scb,
    const float* __restrict__ shw, const float* __restrict__ shb,
    const float* __restrict__ kw, const float* __restrict__ kb, float* __restrict__ KfT,
    const float* __restrict__ t2h, const float* __restrict__ bw, const float* __restrict__ bb,
    const float* __restrict__ Wq, const float* __restrict__ bq,
    const float* __restrict__ R, const float* __restrict__ rb,
    const float* __restrict__ AB2h, float* __restrict__ tb,
    float* __restrict__ Q, float* __restrict__ Qp,
    double* __restrict__ sums3, int* __restrict__ ctr3,
    const float* __restrict__ bh_g, const float* __restrict__ bh_bt, float* __restrict__ ABb)
{
  __shared__ __align__(16) float smem[16 * 257 + 256];
  __shared__ int lastf;
  if (blockIdx.x == 0) {
    mom2_body(mompart, 1024, rp_w1, rp_b1, rp_g, rp_bt, AB2d, smem);
  } else if (blockIdx.x <= 128) {
    fk_body(blockIdx.x - 1, t2l, AB2l, val, scw, scb, shw, shb, kw, kb, KfT);
  } else {
    convbqq_body(blockIdx.x - 129, t2h, bw, bb, Wq, bq, R, rb, AB2h, tb, Q, Qp,
                 sums3, ctr3, bh_g, bh_bt, ABb, smem, &lastf);
  }
}

// ---------------- K5: fused pos-enc + attention + output (+ boundary head blocks) ----------------
__global__ __launch_bounds__(256) void attn_k(
    const float* __restrict__ Q, const float* __restrict__ Qp,
    const float* __restrict__ KfT, const int* __restrict__ idxb,
    const float* __restrict__ xyzT, const float* __restrict__ valT,
    const float* __restrict__ xyz_hr, const float* __restrict__ AB,
    const float* __restrict__ w1, const float* __restrict__ b1,
    const float* __restrict__ b2, float* __restrict__ out,
    const float* __restrict__ tb, const float* __restrict__ ABb,
    const float* __restrict__ bhw2, const float* __restrict__ bhb2)
{
  __shared__ float q_s[CQ * 16], qp_s[CQ * 16];
  if (blockIdx.x >= 2048) {
    int i = (blockIdx.x - 2048) * 256 + threadIdx.x;  // B*N
    int b = i / NN, n = i % NN;
    float acc = bhb2[0];
#pragma unroll
    for (int c = 0; c < 32; c++) {
      float v = tb[((size_t)b * 32 + c) * NN + n];
      v = fmaxf(fmaf(v, ABb[c], ABb[32 + c]), 0.f);
      acc = fmaf(bhw2[c], v, acc);
    }
    out[(size_t)BB * 6 * NN + i] = 1.f / (1.f + expf(-acc));
    return;
  }
  const int ngrp = NN / 16;
  int b = blockIdx.x / ngrp;
  int n0 = (blockIdx.x % ngrp) * 16;
  for (int t = threadIdx.x; t < CQ * 16; t += 256) {
    int c = t >> 4, j = t & 15;
    q_s[t]  = Q [((size_t)b * CQ + c) * NN + n0 + j];
    qp_s[t] = Qp[((size_t)b * CQ + c) * NN + n0 + j];
  }
  __syncthreads();
  int q = threadIdx.x >> 4, k = threadIdx.x & 15;
  int n = n0 + q;
  int id = idxb[((size_t)b * NN + n) * KK + k];
  float ax = xyz_hr[(b * 3 + 0) * NN + n];
  float ay = xyz_hr[(b * 3 + 1) * NN + n];
  float az = xyz_hr[(b * 3 + 2) * NN + n];
  float4 pl = ((const float4*)xyzT)[(size_t)b * MM + id];
  float rx = ax - pl.x, ry = ay - pl.y, rz = az - pl.z;
  const float4* kg = (const float4*)(KfT + ((size_t)b * MM + id) * CQ);
  float s = 0.f;
#pragma unroll
  for (int c4 = 0; c4 < CQ / 4; c4++) {
    float4 g4 = kg[c4];
    float ga[4] = {g4.x, g4.y, g4.z, g4.w};
#pragma unroll
    for (int u = 0; u < 4; u++) {
      int c = 4 * c4 + u;
      float t0 = fmaf(w1[c * 3 + 0], rx, fmaf(w1[c * 3 + 1], ry, w1[c * 3 + 2] * rz)) + b1[c];
      float pe = fmaxf(fmaf(t0, AB[c], AB[CQ + c]), 0.f);
      s = fmaf(q_s[c * 16 + q], ga[u] + b2[c], s);
      s = fmaf(qp_s[c * 16 + q], pe, s);
    }
  }
  s *= 0.125f;
  float mx = s;
#pragma unroll
  for (int o = 8; o >= 1; o >>= 1) mx = fmaxf(mx, __shfl_xor(mx, o, 16));
  float p = expf(s - mx);
  float sum = p;
#pragma unroll
  for (int o = 8; o >= 1; o >>= 1) sum += __shfl_xor(sum, o, 16);
  float attn = p / sum;
  const float4* vt = (const float4*)(valT + ((size_t)b * MM + id) * 8);
  float4 va = vt[0], vb = vt[1];
  float oc[6] = {attn*va.x, attn*va.y, attn*va.z, attn*va.w, attn*vb.x, attn*vb.y};
#pragma unroll
  for (int c = 0; c < 6; c++) {
    float a = oc[c];
#pragma unroll
    for (int o = 8; o >= 1; o >>= 1) a += __shfl_xor(a, o, 16);
    oc[c] = a;
  }
  if (k == 0) {
#pragma unroll
    for (int c = 0; c < 6; c++) out[((size_t)b * 6 + c) * NN + n] = oc[c];
  }
}

extern "C" void kernel_launch(void* const* d_in, const int* in_sizes, int n_in,
                              void* d_out, int out_size, void* d_ws, size_t ws_size,
                              hipStream_t stream)
{
  const float* xyz_hr = (const float*)d_in[0];
  const float* xyz_lr = (const float*)d_in[1];
  const float* val_lr = (const float*)d_in[2];
  const float* feat_hr= (const float*)d_in[3];
  const float* feat_lr= (const float*)d_in[4];
  const float* ge_w1 = (const float*)d_in[5];
  const float* ge_b1 = (const float*)d_in[6];
  const float* ge_g1 = (const float*)d_in[7];
  const float* ge_bt1= (const float*)d_in[8];
  const float* ge_w2 = (const float*)d_in[9];
  const float* ge_b2 = (const float*)d_in[10];
  const float* ge_g2 = (const float*)d_in[11];
  const float* ge_bt2= (const float*)d_in[12];
  const float* sc_w = (const float*)d_in[13];
  const float* sc_b = (const float*)d_in[14];
  const float* sh_w = (const float*)d_in[15];
  const float* sh_b = (const float*)d_in[16];
  const float* q_w  = (const float*)d_in[17];
  const float* q_b  = (const float*)d_in[18];
  const float* k_w  = (const float*)d_in[19];
  const float* k_b  = (const float*)d_in[20];
  const float* bh_w1= (const float*)d_in[21];
  const float* bh_b1= (const float*)d_in[22];
  const float* bh_g = (const float*)d_in[23];
  const float* bh_bt= (const float*)d_in[24];
  const float* bh_w2= (const float*)d_in[25];
  const float* bh_b2= (const float*)d_in[26];
  const float* rp_w1= (const float*)d_in[27];
  const float* rp_b1= (const float*)d_in[28];
  const float* rp_g = (const float*)d_in[29];
  const float* rp_bt= (const float*)d_in[30];
  const float* rp_w2= (const float*)d_in[31];
  const float* rp_b2= (const float*)d_in[32];
  float* out = (float*)d_out;

  // header (zeroed by init_k): [0,96) pad | ctrs 8 ints | sums 576 dbl
  int*    hdr  = (int*)d_ws;
  int*    ctrs = (int*)((char*)d_ws + 96);
  double* sums = (double*)((char*)d_ws + 128);      // sums1[256] | sums2[256] | sums3[64]
  float*  base = (float*)((char*)d_ws + 5504);
  float* AB1h = base;          // 128
  float* AB2h = base + 128;    // 128
  float* AB1l = base + 256;    // 128
  float* AB2l = base + 384;    // 128
  float* ABb  = base + 512;    // 64
  float* AB2d = base + 576;    // 128
  float* big  = base + 768;
  float* t1_hr = big;                      // 2*64*16384
  float* t2_hr = t1_hr + 2097152;
  float* Qb    = t2_hr + 2097152;
  float* Qp    = Qb    + 2097152;
  float* t1_lr = Qp    + 2097152;          // 2*64*4096
  float* t2_lr = t1_lr + 524288;
  float* Rbuf  = t2_lr + 524288;
  float* KfT   = Rbuf  + 524288;           // [B,M,64]
  float* tb    = KfT   + 524288;           // 2*32*16384
  float* xyzT  = tb    + 1048576;          // [B,M,4]
  float* valT  = xyzT  + 32768;            // [B,M,8]
  int*   idxb  = (int*)(valT + 65536);     // 2*16384*16 ints
  double* mompart = (double*)(idxb + BB * NN * KK);  // 1024*9 dbl (dedicated)
  float* theta = Qb;                       // overlay: consumed in K3, Qb written in K4
  float* Rw    = Rbuf;
  float* rbv   = Rbuf + 4096;

  init_k<<<33, 256, 0, stream>>>(xyz_lr, val_lr, xyzT, valT, q_w, q_b, rp_w2, Rw, rbv, hdr);

  k2_k<<<1664, 256, 0, stream>>>(xyz_hr, xyzT, theta, feat_hr, feat_lr, ge_w1, ge_b1,
                                 sums, ctrs + 0, ge_g1, ge_bt1, t1_hr, t1_lr, AB1h, AB1l);

  k3_k<<<1664, 256, 0, stream>>>(xyz_hr, xyzT, theta, idxb, mompart, t1_hr, t1_lr,
                                 ge_w2, ge_b2, AB1h, AB1l, sums + 256, ctrs + 1,
                                 ge_g2, ge_bt2, t2_hr, t2_lr, AB2h, AB2l);

  k4_k<<<1409, 256, 0, stream>>>(mompart, rp_w1, rp_b1, rp_g, rp_bt, AB2d,
                                 t2_lr, AB2l, val_lr, sc_w, sc_b, sh_w, sh_b, k_w, k_b, KfT,
                                 t2_hr, bh_w1, bh_b1, q_w, q_b, Rw, rbv, AB2h, tb, Qb, Qp,
                                 sums + 512, ctrs + 2, bh_g, bh_bt, ABb);

  attn_k<<<2048 + 128, 256, 0, stream>>>(Qb, Qp, KfT, idxb, xyzT, valT, xyz_hr, AB2d,
                                         rp_w1, rp_b1, rp_b2, out, tb, ABb, bh_w2, bh_b2);
}